// Round 1
// baseline (793.296 us; speedup 1.0000x reference)
//
#include <hip/hip_runtime.h>
#include <math.h>

#define HH 28
#define WW 28
#define HWP 784      // 28*28
#define NB 256       // batch

// ---------------- workspace layout (floats) ----------------
// h1    : 256*32*784  = 6,422,528
// off   : 256*18*784  = 3,612,672
// h2    : 256*32*784  = 6,422,528
// pooled: 256*64      = 16,384
#define H1_OFF   0
#define OFF_OFF  6422528
#define H2_OFF   (6422528 + 3612672)
#define POOL_OFF (6422528 + 3612672 + 6422528)

// ---------------- conv1: 3->32, pad 1, relu then bn ----------------
__global__ __launch_bounds__(256) void conv1_kernel(
    const float* __restrict__ x, const float* __restrict__ w1,
    const float* __restrict__ g, const float* __restrict__ bb,
    const float* __restrict__ m, const float* __restrict__ v,
    float* __restrict__ h1)
{
    __shared__ float wlds[9 * 3 * 32];   // [n][ic][oc]
    __shared__ float sc[32], sh[32];
    int tid = threadIdx.x;
    for (int i = tid; i < 864; i += 256) {
        int oc = i & 31;
        int r = i >> 5;           // r = n*3 + ic, r < 27
        int n = r / 3, ic = r % 3;
        wlds[n * 96 + ic * 32 + oc] = w1[oc * 27 + ic * 9 + n];
    }
    if (tid < 32) {
        float inv = g[tid] * rsqrtf(v[tid] + 1e-5f);
        sc[tid] = inv;
        sh[tid] = bb[tid] - m[tid] * inv;
    }
    __syncthreads();

    int gp = blockIdx.x * 256 + tid;       // < 200704
    int b = gp / HWP;
    int p = gp % HWP;
    int y = p / WW, xx = p % WW;

    float acc[32];
#pragma unroll
    for (int i = 0; i < 32; i++) acc[i] = 0.f;

    const float* xb = x + (size_t)b * 3 * HWP;
    for (int n = 0; n < 9; n++) {
        int yy = y + n / 3 - 1;
        int xc = xx + n % 3 - 1;
        bool ok = (yy >= 0 && yy < HH && xc >= 0 && xc < WW);
        for (int ic = 0; ic < 3; ic++) {
            float val = ok ? xb[ic * HWP + yy * WW + xc] : 0.f;
            const float4* wl4 = (const float4*)&wlds[n * 96 + ic * 32];
#pragma unroll
            for (int q = 0; q < 8; q++) {
                float4 wv = wl4[q];
                acc[4 * q + 0] += val * wv.x;
                acc[4 * q + 1] += val * wv.y;
                acc[4 * q + 2] += val * wv.z;
                acc[4 * q + 3] += val * wv.w;
            }
        }
    }
    float* outp = h1 + (size_t)b * 32 * HWP + p;
#pragma unroll
    for (int oc = 0; oc < 32; oc++) {
        float r = fmaxf(acc[oc], 0.f);
        outp[oc * HWP] = r * sc[oc] + sh[oc];
    }
}

// ---------------- p_conv: 32->18, pad 1, + bias ----------------
__global__ __launch_bounds__(256) void pconv_kernel(
    const float* __restrict__ h1, const float* __restrict__ wp,
    const float* __restrict__ bp, float* __restrict__ off)
{
    __shared__ float wlds[32 * 9 * 18];   // [c][n][oc]
    __shared__ float bl[18];
    int tid = threadIdx.x;
    for (int i = tid; i < 5184; i += 256) {
        int oc = i % 18;
        int r = i / 18;        // r = c*9 + n
        int c = r / 9, n = r % 9;
        wlds[i] = wp[oc * 288 + c * 9 + n];
    }
    if (tid < 18) bl[tid] = bp[tid];
    __syncthreads();

    int gp = blockIdx.x * 256 + tid;
    int b = gp / HWP;
    int p = gp % HWP;
    int y = p / WW, xx = p % WW;

    float acc[18];
#pragma unroll
    for (int i = 0; i < 18; i++) acc[i] = 0.f;

    const float* hb = h1 + (size_t)b * 32 * HWP;
    for (int c = 0; c < 32; c++) {
        float vv[9];
#pragma unroll
        for (int n = 0; n < 9; n++) {
            int yy = y + n / 3 - 1;
            int xc = xx + n % 3 - 1;
            vv[n] = (yy >= 0 && yy < HH && xc >= 0 && xc < WW) ? hb[c * HWP + yy * WW + xc] : 0.f;
        }
        const float* wl = &wlds[c * 162];
#pragma unroll
        for (int n = 0; n < 9; n++) {
            float vn = vv[n];
#pragma unroll
            for (int oc = 0; oc < 18; oc++)
                acc[oc] += vn * wl[n * 18 + oc];
        }
    }
    float* ob = off + (size_t)b * 18 * HWP + p;
#pragma unroll
    for (int oc = 0; oc < 18; oc++) ob[oc * HWP] = acc[oc] + bl[oc];
}

// ------- deform sample + 3x3 "conv2" (einsum) + relu + bn2 -------
__global__ __launch_bounds__(256) void deform_kernel(
    const float* __restrict__ h1, const float* __restrict__ off,
    const float* __restrict__ w2,
    const float* __restrict__ g, const float* __restrict__ bb,
    const float* __restrict__ m, const float* __restrict__ v,
    float* __restrict__ h2)
{
    __shared__ float wlds[9 * 32 * 32];  // [n][c][oc]
    __shared__ float sc[32], sh[32];
    int tid = threadIdx.x;
    for (int i = tid; i < 9216; i += 256) {
        int oc = i & 31;
        int r = i >> 5;           // r = n*32 + c
        int c = r & 31, n = r >> 5;
        wlds[i] = w2[oc * 288 + c * 9 + n];
    }
    if (tid < 32) {
        float inv = g[tid] * rsqrtf(v[tid] + 1e-5f);
        sc[tid] = inv;
        sh[tid] = bb[tid] - m[tid] * inv;
    }
    __syncthreads();

    int gp = blockIdx.x * 256 + tid;
    int b = gp / HWP;
    int p = gp % HWP;
    int y = p / WW, xx = p % WW;

    float acc[32];
#pragma unroll
    for (int i = 0; i < 32; i++) acc[i] = 0.f;

    const float* hb = h1 + (size_t)b * 32 * HWP;
    const float* ob = off + (size_t)b * 18 * HWP + p;

    for (int n = 0; n < 9; n++) {
        float offy = ob[n * HWP];
        float offx = ob[(9 + n) * HWP];
        // padded coords: base (y+1, x+1), tap (n/3-1, n%3-1)
        float py = (float)(y + n / 3) + offy;
        float px = (float)(xx + n % 3) + offx;
        float fy = floorf(py), fx = floorf(px);
        float qy0 = fminf(fmaxf(fy, 0.f), 29.f);
        float qy1 = fminf(fmaxf(fy + 1.f, 0.f), 29.f);
        float qx0 = fminf(fmaxf(fx, 0.f), 29.f);
        float qx1 = fminf(fmaxf(fx + 1.f, 0.f), 29.f);
        float pyc = fminf(fmaxf(py, 0.f), 29.f);
        float pxc = fminf(fmaxf(px, 0.f), 29.f);
        float glt = (1.f + (qy0 - pyc)) * (1.f + (qx0 - pxc));
        float grb = (1.f - (qy1 - pyc)) * (1.f - (qx1 - pxc));
        float glb = (1.f + (qy0 - pyc)) * (1.f - (qx1 - pxc));
        float grt = (1.f - (qy1 - pyc)) * (1.f + (qx0 - pxc));
        int iy0 = (int)qy0, iy1 = (int)qy1, ix0 = (int)qx0, ix1 = (int)qx1;
        // padded (qy,qx) -> unpadded (qy-1, qx-1); outside -> 0
        bool vy0 = (iy0 >= 1 && iy0 <= 28), vy1 = (iy1 >= 1 && iy1 <= 28);
        bool vx0 = (ix0 >= 1 && ix0 <= 28), vx1 = (ix1 >= 1 && ix1 <= 28);
        bool b00 = vy0 && vx0, b11 = vy1 && vx1, b01 = vy0 && vx1, b10 = vy1 && vx0;
        int o00 = (iy0 - 1) * WW + (ix0 - 1);
        int o11 = (iy1 - 1) * WW + (ix1 - 1);
        int o01 = (iy0 - 1) * WW + (ix1 - 1);
        int o10 = (iy1 - 1) * WW + (ix0 - 1);

        const float* wbase = &wlds[n * 1024];
        for (int c = 0; c < 32; c++) {
            const float* hc = hb + c * HWP;
            float v00 = b00 ? hc[o00] : 0.f;
            float v11 = b11 ? hc[o11] : 0.f;
            float v01 = b01 ? hc[o01] : 0.f;
            float v10 = b10 ? hc[o10] : 0.f;
            float xo = glt * v00 + grb * v11 + glb * v01 + grt * v10;
            const float4* wl4 = (const float4*)&wbase[c * 32];
#pragma unroll
            for (int q = 0; q < 8; q++) {
                float4 wv = wl4[q];
                acc[4 * q + 0] += xo * wv.x;
                acc[4 * q + 1] += xo * wv.y;
                acc[4 * q + 2] += xo * wv.z;
                acc[4 * q + 3] += xo * wv.w;
            }
        }
    }
    float* outp = h2 + (size_t)b * 32 * HWP + p;
#pragma unroll
    for (int oc = 0; oc < 32; oc++) {
        float r = fmaxf(acc[oc], 0.f);
        outp[oc * HWP] = r * sc[oc] + sh[oc];
    }
}

// -------- zero the pooled accumulator --------
__global__ void zero_kernel(float* __restrict__ p, int n)
{
    int i = blockIdx.x * 256 + threadIdx.x;
    if (i < n) p[i] = 0.f;
}

// -------- conv3: 32->64 pad1 + relu + bn3 + global mean (sum via atomics) --------
__global__ __launch_bounds__(256) void conv3_pool_kernel(
    const float* __restrict__ h2, const float* __restrict__ w3,
    const float* __restrict__ g, const float* __restrict__ bb,
    const float* __restrict__ m, const float* __restrict__ vv,
    float* __restrict__ pooled)
{
    __shared__ float wlds[9 * 32 * 32];  // one 32-oc half at a time
    __shared__ float sc[64], sh[64];
    int tid = threadIdx.x;
    int b = blockIdx.y;
    int p = blockIdx.x * 256 + tid;      // < 1024; valid if < 784
    bool valid = p < HWP;
    int y = p / WW, xx = p % WW;

    if (tid < 64) {
        float inv = g[tid] * rsqrtf(vv[tid] + 1e-5f);
        sc[tid] = inv;
        sh[tid] = bb[tid] - m[tid] * inv;
    }

    const float* hb = h2 + (size_t)b * 32 * HWP;
    float val[64];

    for (int half = 0; half < 2; half++) {
        __syncthreads();
        for (int i = tid; i < 9216; i += 256) {
            int oc = i & 31;
            int r = i >> 5;
            int c = r & 31, n = r >> 5;
            wlds[i] = w3[(size_t)(half * 32 + oc) * 288 + c * 9 + n];
        }
        __syncthreads();

        float acc[32];
#pragma unroll
        for (int i = 0; i < 32; i++) acc[i] = 0.f;

        if (valid) {
            for (int c = 0; c < 32; c++) {
                const float* hc = hb + c * HWP;
                float vtap[9];
#pragma unroll
                for (int n = 0; n < 9; n++) {
                    int yy = y + n / 3 - 1;
                    int xc = xx + n % 3 - 1;
                    vtap[n] = (yy >= 0 && yy < HH && xc >= 0 && xc < WW) ? hc[yy * WW + xc] : 0.f;
                }
#pragma unroll
                for (int n = 0; n < 9; n++) {
                    float vn = vtap[n];
                    const float4* wl4 = (const float4*)&wlds[n * 1024 + c * 32];
#pragma unroll
                    for (int q = 0; q < 8; q++) {
                        float4 wv = wl4[q];
                        acc[4 * q + 0] += vn * wv.x;
                        acc[4 * q + 1] += vn * wv.y;
                        acc[4 * q + 2] += vn * wv.z;
                        acc[4 * q + 3] += vn * wv.w;
                    }
                }
            }
        }
#pragma unroll
        for (int i = 0; i < 32; i++) val[half * 32 + i] = acc[i];
    }

#pragma unroll
    for (int oc = 0; oc < 64; oc++) {
        float r = valid ? (fmaxf(val[oc], 0.f) * sc[oc] + sh[oc]) : 0.f;
#pragma unroll
        for (int s = 1; s < 64; s <<= 1) r += __shfl_xor(r, s, 64);
        if ((tid & 63) == 0) atomicAdd(&pooled[b * 64 + oc], r);
    }
}

// -------- classifier: mean/784, linear 64->10, log_softmax --------
__global__ __launch_bounds__(256) void cls_kernel(
    const float* __restrict__ pooled, const float* __restrict__ wc,
    const float* __restrict__ bc, float* __restrict__ outp)
{
    int b = threadIdx.x;   // 256 threads, one block
    float feat[64];
#pragma unroll
    for (int k = 0; k < 64; k++) feat[k] = pooled[b * 64 + k] * (1.f / 784.f);
    float l[10];
    float mx = -1e30f;
#pragma unroll
    for (int j = 0; j < 10; j++) {
        float s = bc[j];
#pragma unroll
        for (int k = 0; k < 64; k++) s += feat[k] * wc[j * 64 + k];
        l[j] = s;
        mx = fmaxf(mx, s);
    }
    float se = 0.f;
#pragma unroll
    for (int j = 0; j < 10; j++) se += expf(l[j] - mx);
    float lse = logf(se);
#pragma unroll
    for (int j = 0; j < 10; j++) outp[b * 10 + j] = l[j] - mx - lse;
}

extern "C" void kernel_launch(void* const* d_in, const int* in_sizes, int n_in,
                              void* d_out, int out_size, void* d_ws, size_t ws_size,
                              hipStream_t stream)
{
    const float* x  = (const float*)d_in[0];
    const float* w1 = (const float*)d_in[1];
    const float* g1 = (const float*)d_in[2];
    const float* b1 = (const float*)d_in[3];
    const float* m1 = (const float*)d_in[4];
    const float* v1 = (const float*)d_in[5];
    const float* wp = (const float*)d_in[6];
    const float* bp = (const float*)d_in[7];
    const float* w2 = (const float*)d_in[8];
    const float* g2 = (const float*)d_in[9];
    const float* b2 = (const float*)d_in[10];
    const float* m2 = (const float*)d_in[11];
    const float* v2 = (const float*)d_in[12];
    const float* w3 = (const float*)d_in[13];
    const float* g3 = (const float*)d_in[14];
    const float* b3 = (const float*)d_in[15];
    const float* m3 = (const float*)d_in[16];
    const float* v3 = (const float*)d_in[17];
    const float* wc = (const float*)d_in[18];
    const float* bc = (const float*)d_in[19];
    float* outp = (float*)d_out;

    float* wsf    = (float*)d_ws;
    float* h1     = wsf + H1_OFF;
    float* off    = wsf + OFF_OFF;
    float* h2     = wsf + H2_OFF;
    float* pooled = wsf + POOL_OFF;

    // 200704 pixels total / 256 threads = 784 blocks
    conv1_kernel<<<784, 256, 0, stream>>>(x, w1, g1, b1, m1, v1, h1);
    pconv_kernel<<<784, 256, 0, stream>>>(h1, wp, bp, off);
    deform_kernel<<<784, 256, 0, stream>>>(h1, off, w2, g2, b2, m2, v2, h2);
    zero_kernel<<<64, 256, 0, stream>>>(pooled, NB * 64);
    conv3_pool_kernel<<<dim3(4, NB), 256, 0, stream>>>(h2, w3, g3, b3, m3, v3, pooled);
    cls_kernel<<<1, 256, 0, stream>>>(pooled, wc, bc, outp);
}

// Round 2
// 367.430 us; speedup vs baseline: 2.1590x; 2.1590x over previous
//
#include <hip/hip_runtime.h>
#include <math.h>

typedef __attribute__((ext_vector_type(8))) short short8;   // 8 bf16 = 4 VGPRs (MFMA A/B frag)
typedef __attribute__((ext_vector_type(4))) float floatx4;  // MFMA C/D frag

#define NB  256
#define HH  28
#define WW  28
#define HWP 784

// ---------------- workspace layout (bytes) ----------------
// h1p : 256*900*32 bf16 = 14,745,600   (padded 30x30 image, [b][p30][c], borders zero)
// h2p : same              14,745,600
// offs: 256*784*18 f32  = 14,450,688   ([b][p][ch])
// wpbf: 32*288 bf16 (rows>=18 zero), w2bf: 32*288, w3bf: 64*288  ([oc][k=n*32+ic])
// pooled: 256*64 f32
#define H1P_OFF   0u
#define H2P_OFF   14745600u
#define OFFS_OFF  29491200u
#define WPBF_OFF  43941888u
#define W2BF_OFF  43960320u
#define W3BF_OFF  43978752u
#define POOL_OFF  44015616u

static __device__ __forceinline__ unsigned short f2bf(float f) {
    unsigned u = __float_as_uint(f);
    u = (u + 0x7fffu + ((u >> 16) & 1u)) >> 16;   // RNE
    return (unsigned short)u;
}

// ---------------- zero h1p + h2p (contiguous) ----------------
__global__ void zero_ws(uint4* __restrict__ p, int n)
{
    int idx = blockIdx.x * 256 + threadIdx.x;
    uint4 z = make_uint4(0u, 0u, 0u, 0u);
    for (int i = idx; i < n; i += gridDim.x * 256) p[i] = z;
}

// ---------------- convert weights to bf16 [oc][k = n*32+ic] ----------------
__global__ void wcvt(const float* __restrict__ wp, const float* __restrict__ w2,
                     const float* __restrict__ w3,
                     unsigned short* __restrict__ wpbf, unsigned short* __restrict__ w2bf,
                     unsigned short* __restrict__ w3bf)
{
    int t = blockIdx.x * 256 + threadIdx.x;
    if (t < 9216) {
        int oc = t / 288, k = t % 288;
        int n = k >> 5, ic = k & 31;
        wpbf[t] = (oc < 18) ? f2bf(wp[oc * 288 + ic * 9 + n]) : (unsigned short)0;
    } else if (t < 18432) {
        int i = t - 9216;
        int oc = i / 288, k = i % 288;
        int n = k >> 5, ic = k & 31;
        w2bf[i] = f2bf(w2[oc * 288 + ic * 9 + n]);
    } else if (t < 36864) {
        int i = t - 18432;
        int oc = i / 288, k = i % 288;
        int n = k >> 5, ic = k & 31;
        w3bf[i] = f2bf(w3[oc * 288 + ic * 9 + n]);
    }
}

// ---------------- conv1: 3->32 pad1, relu, bn -> h1p (bf16 padded) ----------------
__global__ __launch_bounds__(256) void conv1_kernel(
    const float* __restrict__ x, const float* __restrict__ w1,
    const float* __restrict__ g, const float* __restrict__ bb,
    const float* __restrict__ m, const float* __restrict__ v,
    unsigned short* __restrict__ h1p)
{
    __shared__ float wlds[9 * 3 * 32];   // [n][ic][oc]
    __shared__ float sc[32], sh[32];
    int tid = threadIdx.x;
    for (int i = tid; i < 864; i += 256) {
        int oc = i & 31;
        int r = i >> 5;
        int n = r / 3, ic = r % 3;
        wlds[n * 96 + ic * 32 + oc] = w1[oc * 27 + ic * 9 + n];
    }
    if (tid < 32) {
        float inv = g[tid] * rsqrtf(v[tid] + 1e-5f);
        sc[tid] = inv;
        sh[tid] = bb[tid] - m[tid] * inv;
    }
    __syncthreads();

    int gp = blockIdx.x * 256 + tid;
    int b = gp / HWP;
    int p = gp % HWP;
    int y = p / WW, xx = p % WW;

    float acc[32];
#pragma unroll
    for (int i = 0; i < 32; i++) acc[i] = 0.f;

    const float* xb = x + (size_t)b * 3 * HWP;
    for (int n = 0; n < 9; n++) {
        int yy = y + n / 3 - 1;
        int xc = xx + n % 3 - 1;
        bool ok = (yy >= 0 && yy < HH && xc >= 0 && xc < WW);
        for (int ic = 0; ic < 3; ic++) {
            float val = ok ? xb[ic * HWP + yy * WW + xc] : 0.f;
            const float4* wl4 = (const float4*)&wlds[n * 96 + ic * 32];
#pragma unroll
            for (int qq = 0; qq < 8; qq++) {
                float4 wv = wl4[qq];
                acc[4 * qq + 0] += val * wv.x;
                acc[4 * qq + 1] += val * wv.y;
                acc[4 * qq + 2] += val * wv.z;
                acc[4 * qq + 3] += val * wv.w;
            }
        }
    }
    // write 32 bf16 at padded location (coalesced 64B per thread)
    unsigned short* outp = h1p + ((size_t)b * 900 + (size_t)(y + 1) * 30 + (xx + 1)) * 32;
    unsigned wbuf[16];
#pragma unroll
    for (int i2 = 0; i2 < 16; i2++) {
        float r0 = fmaxf(acc[2 * i2], 0.f) * sc[2 * i2] + sh[2 * i2];
        float r1 = fmaxf(acc[2 * i2 + 1], 0.f) * sc[2 * i2 + 1] + sh[2 * i2 + 1];
        wbuf[i2] = (unsigned)f2bf(r0) | ((unsigned)f2bf(r1) << 16);
    }
    uint4* o4 = (uint4*)outp;
#pragma unroll
    for (int j = 0; j < 4; j++)
        o4[j] = make_uint4(wbuf[4 * j], wbuf[4 * j + 1], wbuf[4 * j + 2], wbuf[4 * j + 3]);
}

// byte offsets of the 9 taps in the padded [p30][32ch] bf16 image (stride 64 B/pixel)
__device__ __constant__ int OFFN_C[9] = {-1984, -1920, -1856, -64, 0, 64, 1856, 1920, 1984};

// ---------------- p_conv as MFMA: h1p -> offs[b][p][18] ----------------
__global__ __launch_bounds__(512) void pconv_mfma(
    const unsigned short* __restrict__ h1p, const unsigned short* __restrict__ wpbf,
    const float* __restrict__ bp, float* __restrict__ offs)
{
    __shared__ __align__(16) unsigned short img[28800];   // 57.6 KB
    int t = threadIdx.x, b = blockIdx.x;
    {
        const uint4* src = (const uint4*)(h1p + (size_t)b * 28800);
        uint4* dst = (uint4*)img;
        for (int i = t; i < 3600; i += 512) dst[i] = src[i];
    }
    __syncthreads();
    int w = t >> 6, l = t & 63, col = l & 15, q = l >> 4;
    const char* imgb = (const char*)img;

    for (int wu = w; wu < 98; wu += 8) {
        int mt = wu >> 1, tile = wu & 1;
        int oc = tile * 16 + col;
        short8 bfr[9];
#pragma unroll
        for (int n = 0; n < 9; n++)
            bfr[n] = *(const short8*)(wpbf + oc * 288 + n * 32 + q * 8);

        unsigned p = (unsigned)(mt * 16 + col);     // A row m = lane&15
        unsigned y = p / 28u, xx = p % 28u;
        int ab = (int)(((y + 1) * 30 + xx + 1) * 64 + q * 16);
        floatx4 acc = {0.f, 0.f, 0.f, 0.f};
#pragma unroll
        for (int n = 0; n < 9; n++) {
            short8 a = *(const short8*)(imgb + ab + OFFN_C[n]);
            acc = __builtin_amdgcn_mfma_f32_16x16x32_bf16(a, bfr[n], acc, 0, 0, 0);
        }
        if (oc < 18) {
            float bias = bp[oc];
            float* obp = offs + (size_t)b * 784 * 18 + oc;
#pragma unroll
            for (int r = 0; r < 4; r++) {
                int pout = mt * 16 + q * 4 + r;     // D row = quad*4 + reg
                obp[pout * 18] = acc[r] + bias;
            }
        }
    }
}

static __device__ __forceinline__ unsigned bilerp2(unsigned e00, unsigned e11, unsigned e01, unsigned e10,
                                                   float glt, float grb, float glb, float grt)
{
    float f0 = glt * __uint_as_float(e00 << 16) + grb * __uint_as_float(e11 << 16)
             + glb * __uint_as_float(e01 << 16) + grt * __uint_as_float(e10 << 16);
    float f1 = glt * __uint_as_float(e00 & 0xffff0000u) + grb * __uint_as_float(e11 & 0xffff0000u)
             + glb * __uint_as_float(e01 & 0xffff0000u) + grt * __uint_as_float(e10 & 0xffff0000u);
    return (unsigned)f2bf(f0) | ((unsigned)f2bf(f1) << 16);
}

// ------- deform sample (A-panel in LDS) + MFMA conv2 + relu + bn2 -> h2p -------
__global__ __launch_bounds__(512) void deform_mfma(
    const unsigned short* __restrict__ h1p, const float* __restrict__ offs,
    const unsigned short* __restrict__ w2bf,
    const float* __restrict__ g, const float* __restrict__ bb,
    const float* __restrict__ m_, const float* __restrict__ v_,
    unsigned short* __restrict__ h2p)
{
    __shared__ __align__(16) unsigned short panel[64 * 296];  // 4 M-tiles x 288k, +8 pad
    int t = threadIdx.x, b = blockIdx.x;
    int w = t >> 6, l = t & 63, col = l & 15, q = l >> 4;
    int ocl = (w & 1) * 16 + col;
    float inv = g[ocl] * rsqrtf(v_[ocl] + 1e-5f);
    float sc = inv, sh = bb[ocl] - m_[ocl] * inv;
    short8 bfr[9];
#pragma unroll
    for (int n = 0; n < 9; n++)
        bfr[n] = *(const short8*)(w2bf + ocl * 288 + n * 32 + q * 8);

    const unsigned short* gimg = h1p + (size_t)b * 28800;
    const float* ob = offs + (size_t)b * 784 * 18;

    for (int ph = 0; ph < 13; ph++) {
        int ntl = (ph == 12) ? 1 : 4;
        __syncthreads();
        for (int u = t; u < ntl * 144; u += 512) {
            int tl = u / 144, r2 = u % 144;
            int pxl = r2 / 9, n = r2 % 9;
            unsigned p = (unsigned)((ph * 4 + tl) * 16 + pxl);
            unsigned y = p / 28u, xx = p % 28u;
            float offy = ob[p * 18 + n];
            float offx = ob[p * 18 + 9 + n];
            float py = (float)(y + n / 3) + offy;       // padded coords
            float px = (float)(xx + n % 3) + offx;
            float fy = floorf(py), fx = floorf(px);
            float qy0 = fminf(fmaxf(fy, 0.f), 29.f);
            float qy1 = fminf(fmaxf(fy + 1.f, 0.f), 29.f);
            float qx0 = fminf(fmaxf(fx, 0.f), 29.f);
            float qx1 = fminf(fmaxf(fx + 1.f, 0.f), 29.f);
            float pyc = fminf(fmaxf(py, 0.f), 29.f);
            float pxc = fminf(fmaxf(px, 0.f), 29.f);
            float glt = (1.f + (qy0 - pyc)) * (1.f + (qx0 - pxc));
            float grb = (1.f - (qy1 - pyc)) * (1.f - (qx1 - pxc));
            float glb = (1.f + (qy0 - pyc)) * (1.f - (qx1 - pxc));
            float grt = (1.f - (qy1 - pyc)) * (1.f + (qx0 - pxc));
            int iy0 = (int)qy0, iy1 = (int)qy1, ix0 = (int)qx0, ix1 = (int)qx1;
            const uint4* c00 = (const uint4*)(gimg + (iy0 * 30 + ix0) * 32);
            const uint4* c11 = (const uint4*)(gimg + (iy1 * 30 + ix1) * 32);
            const uint4* c01 = (const uint4*)(gimg + (iy0 * 30 + ix1) * 32);
            const uint4* c10 = (const uint4*)(gimg + (iy1 * 30 + ix0) * 32);
            unsigned short* prow = panel + (tl * 16 + pxl) * 296 + n * 32;
#pragma unroll
            for (int cg = 0; cg < 4; cg++) {
                uint4 u00 = c00[cg], u11 = c11[cg], u01 = c01[cg], u10 = c10[cg];
                unsigned o0 = bilerp2(u00.x, u11.x, u01.x, u10.x, glt, grb, glb, grt);
                unsigned o1 = bilerp2(u00.y, u11.y, u01.y, u10.y, glt, grb, glb, grt);
                unsigned o2 = bilerp2(u00.z, u11.z, u01.z, u10.z, glt, grb, glb, grt);
                unsigned o3 = bilerp2(u00.w, u11.w, u01.w, u10.w, glt, grb, glb, grt);
                *(uint4*)(prow + cg * 8) = make_uint4(o0, o1, o2, o3);
            }
        }
        __syncthreads();
        int mt2 = ph * 4 + (w >> 1);
        if (mt2 < 49) {
            floatx4 acc = {0.f, 0.f, 0.f, 0.f};
            const char* pb = (const char*)panel;
            int abase = ((w >> 1) * 16 + col) * 592 + q * 16;
#pragma unroll
            for (int n = 0; n < 9; n++) {
                short8 a = *(const short8*)(pb + abase + n * 64);
                acc = __builtin_amdgcn_mfma_f32_16x16x32_bf16(a, bfr[n], acc, 0, 0, 0);
            }
            unsigned short* h2b = h2p + (size_t)b * 28800;
#pragma unroll
            for (int r = 0; r < 4; r++) {
                int pout = mt2 * 16 + q * 4 + r;
                unsigned yo = (unsigned)pout / 28u, xo = (unsigned)pout % 28u;
                float val = fmaxf(acc[r], 0.f) * sc + sh;
                h2b[((yo + 1) * 30 + xo + 1) * 32 + ocl] = f2bf(val);
            }
        }
    }
}

// ------- conv3 MFMA + relu + bn3 + global mean -> pooled[b][64] -------
__global__ __launch_bounds__(512) void conv3_mfma(
    const unsigned short* __restrict__ h2p, const unsigned short* __restrict__ w3bf,
    const float* __restrict__ g, const float* __restrict__ bb,
    const float* __restrict__ m_, const float* __restrict__ v_,
    float* __restrict__ pooled)
{
    __shared__ __align__(16) unsigned short img[28800];
    __shared__ float part[2][64];
    int t = threadIdx.x, b = blockIdx.x;
    {
        const uint4* src = (const uint4*)(h2p + (size_t)b * 28800);
        uint4* dst = (uint4*)img;
        for (int i = t; i < 3600; i += 512) dst[i] = src[i];
    }
    int w = t >> 6, l = t & 63, col = l & 15, q = l >> 4;
    int ocl = (w & 3) * 16 + col;
    short8 bfr[9];
#pragma unroll
    for (int n = 0; n < 9; n++)
        bfr[n] = *(const short8*)(w3bf + ocl * 288 + n * 32 + q * 8);
    __syncthreads();

    const char* imgb = (const char*)img;
    float psum = 0.f;
    for (int mt = (w >> 2); mt < 49; mt += 2) {
        unsigned p = (unsigned)(mt * 16 + col);
        unsigned y = p / 28u, xx = p % 28u;
        int ab = (int)(((y + 1) * 30 + xx + 1) * 64 + q * 16);
        floatx4 acc = {0.f, 0.f, 0.f, 0.f};
#pragma unroll
        for (int n = 0; n < 9; n++) {
            short8 a = *(const short8*)(imgb + ab + OFFN_C[n]);
            acc = __builtin_amdgcn_mfma_f32_16x16x32_bf16(a, bfr[n], acc, 0, 0, 0);
        }
        psum += fmaxf(acc[0], 0.f) + fmaxf(acc[1], 0.f) + fmaxf(acc[2], 0.f) + fmaxf(acc[3], 0.f);
    }
    psum += __shfl_xor(psum, 16, 64);
    psum += __shfl_xor(psum, 32, 64);
    if (l < 16) part[w >> 2][(w & 3) * 16 + l] = psum;
    __syncthreads();
    if (t < 64) {
        float inv = g[t] * rsqrtf(v_[t] + 1e-5f);
        pooled[b * 64 + t] = (part[0][t] + part[1][t]) * inv + 784.f * (bb[t] - m_[t] * inv);
    }
}

// -------- classifier: mean/784, linear 64->10, log_softmax --------
__global__ __launch_bounds__(256) void cls_kernel(
    const float* __restrict__ pooled, const float* __restrict__ wc,
    const float* __restrict__ bc, float* __restrict__ outp)
{
    int b = threadIdx.x;
    float feat[64];
#pragma unroll
    for (int k = 0; k < 64; k++) feat[k] = pooled[b * 64 + k] * (1.f / 784.f);
    float lg[10];
    float mx = -1e30f;
#pragma unroll
    for (int j = 0; j < 10; j++) {
        float s = bc[j];
#pragma unroll
        for (int k = 0; k < 64; k++) s += feat[k] * wc[j * 64 + k];
        lg[j] = s;
        mx = fmaxf(mx, s);
    }
    float se = 0.f;
#pragma unroll
    for (int j = 0; j < 10; j++) se += expf(lg[j] - mx);
    float lse = logf(se);
#pragma unroll
    for (int j = 0; j < 10; j++) outp[b * 10 + j] = lg[j] - mx - lse;
}

extern "C" void kernel_launch(void* const* d_in, const int* in_sizes, int n_in,
                              void* d_out, int out_size, void* d_ws, size_t ws_size,
                              hipStream_t stream)
{
    (void)in_sizes; (void)n_in; (void)out_size; (void)ws_size;
    const float* x  = (const float*)d_in[0];
    const float* w1 = (const float*)d_in[1];
    const float* g1 = (const float*)d_in[2];
    const float* b1 = (const float*)d_in[3];
    const float* m1 = (const float*)d_in[4];
    const float* v1 = (const float*)d_in[5];
    const float* wp = (const float*)d_in[6];
    const float* bp = (const float*)d_in[7];
    const float* w2 = (const float*)d_in[8];
    const float* g2 = (const float*)d_in[9];
    const float* b2 = (const float*)d_in[10];
    const float* m2 = (const float*)d_in[11];
    const float* v2 = (const float*)d_in[12];
    const float* w3 = (const float*)d_in[13];
    const float* g3 = (const float*)d_in[14];
    const float* b3 = (const float*)d_in[15];
    const float* m3 = (const float*)d_in[16];
    const float* v3 = (const float*)d_in[17];
    const float* wc = (const float*)d_in[18];
    const float* bc = (const float*)d_in[19];
    float* outp = (float*)d_out;

    unsigned char* ws = (unsigned char*)d_ws;
    unsigned short* h1p  = (unsigned short*)(ws + H1P_OFF);
    unsigned short* h2p  = (unsigned short*)(ws + H2P_OFF);
    float*          offs = (float*)(ws + OFFS_OFF);
    unsigned short* wpbf = (unsigned short*)(ws + WPBF_OFF);
    unsigned short* w2bf = (unsigned short*)(ws + W2BF_OFF);
    unsigned short* w3bf = (unsigned short*)(ws + W3BF_OFF);
    float*          pooled = (float*)(ws + POOL_OFF);

    zero_ws<<<1800, 256, 0, stream>>>((uint4*)ws, 1843200);   // h1p + h2p
    wcvt<<<144, 256, 0, stream>>>(wp, w2, w3, wpbf, w2bf, w3bf);
    conv1_kernel<<<784, 256, 0, stream>>>(x, w1, g1, b1, m1, v1, h1p);
    pconv_mfma<<<NB, 512, 0, stream>>>(h1p, wpbf, bp, offs);
    deform_mfma<<<NB, 512, 0, stream>>>(h1p, offs, w2bf, g2, b2, m2, v2, h2p);
    conv3_mfma<<<NB, 512, 0, stream>>>(h2p, w3bf, g3, b3, m3, v3, pooled);
    cls_kernel<<<1, 256, 0, stream>>>(pooled, wc, bc, outp);
}

// Round 3
// 235.121 us; speedup vs baseline: 3.3740x; 1.5627x over previous
//
#include <hip/hip_runtime.h>
#include <math.h>

typedef __attribute__((ext_vector_type(8))) short short8;   // 8 bf16 = 4 VGPRs (MFMA A/B frag)
typedef __attribute__((ext_vector_type(4))) float floatx4;  // MFMA C/D frag

#define NB  256
#define HH  28
#define WW  28
#define HWP 784

// ---------------- workspace layout (bytes) ----------------
// h1p : 256*900*32 bf16 = 14,745,600   (padded 30x30 image, [b][p30][c], borders zero)
// h2p : same              14,745,600
// offs: 256*784*18 f32  = 14,450,688   ([b][p][ch])
// wpbf: 32*288 bf16 (rows>=18 zero), w2bf: 32*288, w3bf: 64*288  ([oc][k=n*32+ic])
// pooled: 256*64 f32
// w1t : 27*32 f32 ([k=n*3+ic][oc]);  c1p: 64 f32 (scale[32], shift[32])
#define H1P_OFF   0u
#define H2P_OFF   14745600u
#define OFFS_OFF  29491200u
#define WPBF_OFF  43941888u
#define W2BF_OFF  43960320u
#define W3BF_OFF  43978752u
#define POOL_OFF  44015616u
#define W1T_OFF   44081152u
#define C1P_OFF   44084608u

static __device__ __forceinline__ unsigned short f2bf(float f) {
    unsigned u = __float_as_uint(f);
    u = (u + 0x7fffu + ((u >> 16) & 1u)) >> 16;   // RNE
    return (unsigned short)u;
}

// ---------------- zero only the padded borders of h1p/h2p ----------------
__global__ __launch_bounds__(256) void border_zero(unsigned short* __restrict__ h1p,
                                                   unsigned short* __restrict__ h2p)
{
    int b = blockIdx.x, t = threadIdx.x;
    unsigned short* base = (t < 128) ? h1p : h2p;
    int tt = t & 127;
    if (tt < 116) {
        int y, xx;
        if (tt < 30)      { y = 0;       xx = tt; }
        else if (tt < 60) { y = 29;      xx = tt - 30; }
        else if (tt < 88) { y = tt - 59; xx = 0; }
        else              { y = tt - 87; xx = 29; }
        uint4* p4 = (uint4*)(base + ((size_t)b * 900 + y * 30 + xx) * 32);
        uint4 z = make_uint4(0u, 0u, 0u, 0u);
        p4[0] = z; p4[1] = z; p4[2] = z; p4[3] = z;
    }
}

// ------- weight prep: bf16 [oc][k=n*32+ic] for MFMA convs; f32 [k][oc] + BN for conv1 -------
__global__ void wcvt(const float* __restrict__ wp, const float* __restrict__ w2,
                     const float* __restrict__ w3, const float* __restrict__ w1,
                     const float* __restrict__ g1, const float* __restrict__ b1,
                     const float* __restrict__ m1, const float* __restrict__ v1,
                     unsigned short* __restrict__ wpbf, unsigned short* __restrict__ w2bf,
                     unsigned short* __restrict__ w3bf, float* __restrict__ w1t,
                     float* __restrict__ c1p)
{
    int t = blockIdx.x * 256 + threadIdx.x;
    if (t < 9216) {
        int oc = t / 288, k = t % 288;
        int n = k >> 5, ic = k & 31;
        wpbf[t] = (oc < 18) ? f2bf(wp[oc * 288 + ic * 9 + n]) : (unsigned short)0;
    } else if (t < 18432) {
        int i = t - 9216;
        int oc = i / 288, k = i % 288;
        int n = k >> 5, ic = k & 31;
        w2bf[i] = f2bf(w2[oc * 288 + ic * 9 + n]);
    } else if (t < 36864) {
        int i = t - 18432;
        int oc = i / 288, k = i % 288;
        int n = k >> 5, ic = k & 31;
        w3bf[i] = f2bf(w3[oc * 288 + ic * 9 + n]);
    } else if (t < 37728) {
        int i = t - 36864;        // i = k*32 + oc, k = n*3+ic
        int k = i >> 5, oc = i & 31;
        int n = k / 3, ic = k % 3;
        w1t[i] = w1[oc * 27 + ic * 9 + n];
    } else if (t < 37792) {
        int oc = t - 37728;       // 0..63
        int c = oc & 31;
        float inv = g1[c] * rsqrtf(v1[c] + 1e-5f);
        c1p[oc] = (oc < 32) ? inv : (b1[c] - m1[c] * inv);
    }
}

// ---------------- conv1: 3->32 pad1, relu, bn -> h1p (bf16 padded) ----------------
// One block per image; x staged in LDS; weights read via uniform indices (SGPR/K$).
__global__ __launch_bounds__(256) void conv1_kernel(
    const float* __restrict__ x, const float* __restrict__ w1t,
    const float* __restrict__ c1p, unsigned short* __restrict__ h1p)
{
    __shared__ float xs[2352];
    int tid = threadIdx.x, b = blockIdx.x;
    {
        const float4* xg = (const float4*)(x + (size_t)b * 2352);
        float4* xl = (float4*)xs;
        for (int i = tid; i < 588; i += 256) xl[i] = xg[i];
    }
    __syncthreads();

    for (int p = tid; p < HWP; p += 256) {
        int y = p / WW, xx = p % WW;
        float acc[32];
#pragma unroll
        for (int i = 0; i < 32; i++) acc[i] = 0.f;

#pragma unroll
        for (int n = 0; n < 9; n++) {
            int yy = y + n / 3 - 1, xc = xx + n % 3 - 1;
            bool ok = (yy >= 0 && yy < HH && xc >= 0 && xc < WW);
#pragma unroll
            for (int ic = 0; ic < 3; ic++) {
                float val = ok ? xs[ic * HWP + yy * WW + xc] : 0.f;
                const float* wr = w1t + (n * 3 + ic) * 32;
#pragma unroll
                for (int oc = 0; oc < 32; oc++) acc[oc] += val * wr[oc];
            }
        }

        unsigned short* outp = h1p + ((size_t)b * 900 + (size_t)(y + 1) * 30 + (xx + 1)) * 32;
        uint4* o4 = (uint4*)outp;
#pragma unroll
        for (int j = 0; j < 4; j++) {
            unsigned wv[4];
#pragma unroll
            for (int h = 0; h < 4; h++) {
                int oc = j * 8 + h * 2;
                float r0 = fmaxf(acc[oc], 0.f) * c1p[oc] + c1p[32 + oc];
                float r1 = fmaxf(acc[oc + 1], 0.f) * c1p[oc + 1] + c1p[32 + oc + 1];
                wv[h] = (unsigned)f2bf(r0) | ((unsigned)f2bf(r1) << 16);
            }
            o4[j] = make_uint4(wv[0], wv[1], wv[2], wv[3]);
        }
    }
}

// byte offsets of the 9 taps in the padded [p30][32ch] bf16 image (stride 64 B/pixel)
__device__ __constant__ int OFFN_C[9] = {-1984, -1920, -1856, -64, 0, 64, 1856, 1920, 1984};

// ---------------- p_conv as MFMA: h1p -> offs[b][p][18] ----------------
__global__ __launch_bounds__(512) void pconv_mfma(
    const unsigned short* __restrict__ h1p, const unsigned short* __restrict__ wpbf,
    const float* __restrict__ bp, float* __restrict__ offs)
{
    __shared__ __align__(16) unsigned short img[28800];   // 57.6 KB
    int t = threadIdx.x, b = blockIdx.x;
    {
        const uint4* src = (const uint4*)(h1p + (size_t)b * 28800);
        uint4* dst = (uint4*)img;
        for (int i = t; i < 3600; i += 512) dst[i] = src[i];
    }
    __syncthreads();
    int w = t >> 6, l = t & 63, col = l & 15, q = l >> 4;
    const char* imgb = (const char*)img;

    for (int wu = w; wu < 98; wu += 8) {
        int mt = wu >> 1, tile = wu & 1;
        int oc = tile * 16 + col;
        short8 bfr[9];
#pragma unroll
        for (int n = 0; n < 9; n++)
            bfr[n] = *(const short8*)(wpbf + oc * 288 + n * 32 + q * 8);

        unsigned p = (unsigned)(mt * 16 + col);     // A row m = lane&15
        unsigned y = p / 28u, xx = p % 28u;
        int ab = (int)(((y + 1) * 30 + xx + 1) * 64 + q * 16);
        floatx4 acc = {0.f, 0.f, 0.f, 0.f};
#pragma unroll
        for (int n = 0; n < 9; n++) {
            short8 a = *(const short8*)(imgb + ab + OFFN_C[n]);
            acc = __builtin_amdgcn_mfma_f32_16x16x32_bf16(a, bfr[n], acc, 0, 0, 0);
        }
        if (oc < 18) {
            float bias = bp[oc];
            float* obp = offs + (size_t)b * 784 * 18 + oc;
#pragma unroll
            for (int r = 0; r < 4; r++) {
                int pout = mt * 16 + q * 4 + r;     // D row = quad*4 + reg
                obp[pout * 18] = acc[r] + bias;
            }
        }
    }
}

static __device__ __forceinline__ unsigned bilerp2(unsigned e00, unsigned e11, unsigned e01, unsigned e10,
                                                   float glt, float grb, float glb, float grt)
{
    float f0 = glt * __uint_as_float(e00 << 16) + grb * __uint_as_float(e11 << 16)
             + glb * __uint_as_float(e01 << 16) + grt * __uint_as_float(e10 << 16);
    float f1 = glt * __uint_as_float(e00 & 0xffff0000u) + grb * __uint_as_float(e11 & 0xffff0000u)
             + glb * __uint_as_float(e01 & 0xffff0000u) + grt * __uint_as_float(e10 & 0xffff0000u);
    return (unsigned)f2bf(f0) | ((unsigned)f2bf(f1) << 16);
}

// ------- deform sample (A-panel in LDS) + MFMA conv2 + relu + bn2 -> h2p -------
__global__ __launch_bounds__(512) void deform_mfma(
    const unsigned short* __restrict__ h1p, const float* __restrict__ offs,
    const unsigned short* __restrict__ w2bf,
    const float* __restrict__ g, const float* __restrict__ bb,
    const float* __restrict__ m_, const float* __restrict__ v_,
    unsigned short* __restrict__ h2p)
{
    __shared__ __align__(16) unsigned short panel[64 * 296];  // 4 M-tiles x 288k, +8 pad
    int t = threadIdx.x, b = blockIdx.x;
    int w = t >> 6, l = t & 63, col = l & 15, q = l >> 4;
    int ocl = (w & 1) * 16 + col;
    float inv = g[ocl] * rsqrtf(v_[ocl] + 1e-5f);
    float sc = inv, sh = bb[ocl] - m_[ocl] * inv;
    short8 bfr[9];
#pragma unroll
    for (int n = 0; n < 9; n++)
        bfr[n] = *(const short8*)(w2bf + ocl * 288 + n * 32 + q * 8);

    const unsigned short* gimg = h1p + (size_t)b * 28800;
    const float* ob = offs + (size_t)b * 784 * 18;

    for (int ph = 0; ph < 13; ph++) {
        int ntl = (ph == 12) ? 1 : 4;
        __syncthreads();
        for (int u = t; u < ntl * 144; u += 512) {
            int tl = u / 144, r2 = u % 144;
            int pxl = r2 / 9, n = r2 % 9;
            unsigned p = (unsigned)((ph * 4 + tl) * 16 + pxl);
            unsigned y = p / 28u, xx = p % 28u;
            float offy = ob[p * 18 + n];
            float offx = ob[p * 18 + 9 + n];
            float py = (float)(y + n / 3) + offy;       // padded coords
            float px = (float)(xx + n % 3) + offx;
            float fy = floorf(py), fx = floorf(px);
            float qy0 = fminf(fmaxf(fy, 0.f), 29.f);
            float qy1 = fminf(fmaxf(fy + 1.f, 0.f), 29.f);
            float qx0 = fminf(fmaxf(fx, 0.f), 29.f);
            float qx1 = fminf(fmaxf(fx + 1.f, 0.f), 29.f);
            float pyc = fminf(fmaxf(py, 0.f), 29.f);
            float pxc = fminf(fmaxf(px, 0.f), 29.f);
            float glt = (1.f + (qy0 - pyc)) * (1.f + (qx0 - pxc));
            float grb = (1.f - (qy1 - pyc)) * (1.f - (qx1 - pxc));
            float glb = (1.f + (qy0 - pyc)) * (1.f - (qx1 - pxc));
            float grt = (1.f - (qy1 - pyc)) * (1.f + (qx0 - pxc));
            int iy0 = (int)qy0, iy1 = (int)qy1, ix0 = (int)qx0, ix1 = (int)qx1;
            const uint4* c00 = (const uint4*)(gimg + (iy0 * 30 + ix0) * 32);
            const uint4* c11 = (const uint4*)(gimg + (iy1 * 30 + ix1) * 32);
            const uint4* c01 = (const uint4*)(gimg + (iy0 * 30 + ix1) * 32);
            const uint4* c10 = (const uint4*)(gimg + (iy1 * 30 + ix0) * 32);
            unsigned short* prow = panel + (tl * 16 + pxl) * 296 + n * 32;
#pragma unroll
            for (int cg = 0; cg < 4; cg++) {
                uint4 u00 = c00[cg], u11 = c11[cg], u01 = c01[cg], u10 = c10[cg];
                unsigned o0 = bilerp2(u00.x, u11.x, u01.x, u10.x, glt, grb, glb, grt);
                unsigned o1 = bilerp2(u00.y, u11.y, u01.y, u10.y, glt, grb, glb, grt);
                unsigned o2 = bilerp2(u00.z, u11.z, u01.z, u10.z, glt, grb, glb, grt);
                unsigned o3 = bilerp2(u00.w, u11.w, u01.w, u10.w, glt, grb, glb, grt);
                *(uint4*)(prow + cg * 8) = make_uint4(o0, o1, o2, o3);
            }
        }
        __syncthreads();
        int mt2 = ph * 4 + (w >> 1);
        if (mt2 < 49) {
            floatx4 acc = {0.f, 0.f, 0.f, 0.f};
            const char* pb = (const char*)panel;
            int abase = ((w >> 1) * 16 + col) * 592 + q * 16;
#pragma unroll
            for (int n = 0; n < 9; n++) {
                short8 a = *(const short8*)(pb + abase + n * 64);
                acc = __builtin_amdgcn_mfma_f32_16x16x32_bf16(a, bfr[n], acc, 0, 0, 0);
            }
            unsigned short* h2b = h2p + (size_t)b * 28800;
#pragma unroll
            for (int r = 0; r < 4; r++) {
                int pout = mt2 * 16 + q * 4 + r;
                unsigned yo = (unsigned)pout / 28u, xo = (unsigned)pout % 28u;
                float val = fmaxf(acc[r], 0.f) * sc + sh;
                h2b[((yo + 1) * 30 + xo + 1) * 32 + ocl] = f2bf(val);
            }
        }
    }
}

// ------- conv3 MFMA + relu + bn3 + global mean -> pooled[b][64] -------
__global__ __launch_bounds__(512) void conv3_mfma(
    const unsigned short* __restrict__ h2p, const unsigned short* __restrict__ w3bf,
    const float* __restrict__ g, const float* __restrict__ bb,
    const float* __restrict__ m_, const float* __restrict__ v_,
    float* __restrict__ pooled)
{
    __shared__ __align__(16) unsigned short img[28800];
    __shared__ float part[2][64];
    int t = threadIdx.x, b = blockIdx.x;
    {
        const uint4* src = (const uint4*)(h2p + (size_t)b * 28800);
        uint4* dst = (uint4*)img;
        for (int i = t; i < 3600; i += 512) dst[i] = src[i];
    }
    int w = t >> 6, l = t & 63, col = l & 15, q = l >> 4;
    int ocl = (w & 3) * 16 + col;
    short8 bfr[9];
#pragma unroll
    for (int n = 0; n < 9; n++)
        bfr[n] = *(const short8*)(w3bf + ocl * 288 + n * 32 + q * 8);
    __syncthreads();

    const char* imgb = (const char*)img;
    float psum = 0.f;
    for (int mt = (w >> 2); mt < 49; mt += 2) {
        unsigned p = (unsigned)(mt * 16 + col);
        unsigned y = p / 28u, xx = p % 28u;
        int ab = (int)(((y + 1) * 30 + xx + 1) * 64 + q * 16);
        floatx4 acc = {0.f, 0.f, 0.f, 0.f};
#pragma unroll
        for (int n = 0; n < 9; n++) {
            short8 a = *(const short8*)(imgb + ab + OFFN_C[n]);
            acc = __builtin_amdgcn_mfma_f32_16x16x32_bf16(a, bfr[n], acc, 0, 0, 0);
        }
        psum += fmaxf(acc[0], 0.f) + fmaxf(acc[1], 0.f) + fmaxf(acc[2], 0.f) + fmaxf(acc[3], 0.f);
    }
    psum += __shfl_xor(psum, 16, 64);
    psum += __shfl_xor(psum, 32, 64);
    if (l < 16) part[w >> 2][(w & 3) * 16 + l] = psum;
    __syncthreads();
    if (t < 64) {
        float inv = g[t] * rsqrtf(v_[t] + 1e-5f);
        pooled[b * 64 + t] = (part[0][t] + part[1][t]) * inv + 784.f * (bb[t] - m_[t] * inv);
    }
}

// -------- classifier: mean/784, linear 64->10, log_softmax --------
__global__ __launch_bounds__(256) void cls_kernel(
    const float* __restrict__ pooled, const float* __restrict__ wc,
    const float* __restrict__ bc, float* __restrict__ outp)
{
    int b = threadIdx.x;
    float feat[64];
#pragma unroll
    for (int k = 0; k < 64; k++) feat[k] = pooled[b * 64 + k] * (1.f / 784.f);
    float lg[10];
    float mx = -1e30f;
#pragma unroll
    for (int j = 0; j < 10; j++) {
        float s = bc[j];
#pragma unroll
        for (int k = 0; k < 64; k++) s += feat[k] * wc[j * 64 + k];
        lg[j] = s;
        mx = fmaxf(mx, s);
    }
    float se = 0.f;
#pragma unroll
    for (int j = 0; j < 10; j++) se += expf(lg[j] - mx);
    float lse = logf(se);
#pragma unroll
    for (int j = 0; j < 10; j++) outp[b * 10 + j] = lg[j] - mx - lse;
}

extern "C" void kernel_launch(void* const* d_in, const int* in_sizes, int n_in,
                              void* d_out, int out_size, void* d_ws, size_t ws_size,
                              hipStream_t stream)
{
    (void)in_sizes; (void)n_in; (void)out_size; (void)ws_size;
    const float* x  = (const float*)d_in[0];
    const float* w1 = (const float*)d_in[1];
    const float* g1 = (const float*)d_in[2];
    const float* b1 = (const float*)d_in[3];
    const float* m1 = (const float*)d_in[4];
    const float* v1 = (const float*)d_in[5];
    const float* wp = (const float*)d_in[6];
    const float* bp = (const float*)d_in[7];
    const float* w2 = (const float*)d_in[8];
    const float* g2 = (const float*)d_in[9];
    const float* b2 = (const float*)d_in[10];
    const float* m2 = (const float*)d_in[11];
    const float* v2 = (const float*)d_in[12];
    const float* w3 = (const float*)d_in[13];
    const float* g3 = (const float*)d_in[14];
    const float* b3 = (const float*)d_in[15];
    const float* m3 = (const float*)d_in[16];
    const float* v3 = (const float*)d_in[17];
    const float* wc = (const float*)d_in[18];
    const float* bc = (const float*)d_in[19];
    float* outp = (float*)d_out;

    unsigned char* ws = (unsigned char*)d_ws;
    unsigned short* h1p  = (unsigned short*)(ws + H1P_OFF);
    unsigned short* h2p  = (unsigned short*)(ws + H2P_OFF);
    float*          offs = (float*)(ws + OFFS_OFF);
    unsigned short* wpbf = (unsigned short*)(ws + WPBF_OFF);
    unsigned short* w2bf = (unsigned short*)(ws + W2BF_OFF);
    unsigned short* w3bf = (unsigned short*)(ws + W3BF_OFF);
    float*          pooled = (float*)(ws + POOL_OFF);
    float*          w1t  = (float*)(ws + W1T_OFF);
    float*          c1p  = (float*)(ws + C1P_OFF);

    border_zero<<<NB, 256, 0, stream>>>(h1p, h2p);
    wcvt<<<148, 256, 0, stream>>>(wp, w2, w3, w1, g1, b1, m1, v1,
                                  wpbf, w2bf, w3bf, w1t, c1p);
    conv1_kernel<<<NB, 256, 0, stream>>>(x, w1t, c1p, h1p);
    pconv_mfma<<<NB, 512, 0, stream>>>(h1p, wpbf, bp, offs);
    deform_mfma<<<NB, 512, 0, stream>>>(h1p, offs, w2bf, g2, b2, m2, v2, h2p);
    conv3_mfma<<<NB, 512, 0, stream>>>(h2p, w3bf, g3, b3, m3, v3, pooled);
    cls_kernel<<<1, 256, 0, stream>>>(pooled, wc, bc, outp);
}

// Round 4
// 204.165 us; speedup vs baseline: 3.8856x; 1.1516x over previous
//
#include <hip/hip_runtime.h>
#include <math.h>

typedef __attribute__((ext_vector_type(8))) short short8;   // 8 bf16 = 4 VGPRs (MFMA A/B frag)
typedef __attribute__((ext_vector_type(4))) float floatx4;  // MFMA C/D frag

#define NB  256
#define HH  28
#define WW  28
#define HWP 784

// ---------------- workspace layout (bytes) ----------------
// h1p : 256*900*32 bf16 (padded 30x30, [b][p30][c], borders zero)
// h2p : same
// wpbf: 32*288 bf16 (rows>=18 zero)  w2bf: 32*288  w3bf: 64*288   ([oc][k=n*32+ic])
// pooled2: 512*64 f32 (per half-block partials)
// w1t : 27*32 f32   c1p: 64 f32 (conv1 scale/shift)   c3p: 128 f32 (conv3 inv/shift)
#define H1P_OFF   0u
#define H2P_OFF   14745600u
#define WPBF_OFF  29491200u
#define W2BF_OFF  29509632u
#define W3BF_OFF  29528064u
#define POOL2_OFF 29564928u
#define W1T_OFF   29696000u
#define C1P_OFF   29699456u
#define C3P_OFF   29699712u

static __device__ __forceinline__ unsigned short f2bf(float f) {
    unsigned u = __float_as_uint(f);
    u = (u + 0x7fffu + ((u >> 16) & 1u)) >> 16;   // RNE
    return (unsigned short)u;
}

// ---------------- zero only the padded borders of h1p/h2p ----------------
__global__ __launch_bounds__(256) void border_zero(unsigned short* __restrict__ h1p,
                                                   unsigned short* __restrict__ h2p)
{
    int b = blockIdx.x, t = threadIdx.x;
    unsigned short* base = (t < 128) ? h1p : h2p;
    int tt = t & 127;
    if (tt < 116) {
        int y, xx;
        if (tt < 30)      { y = 0;       xx = tt; }
        else if (tt < 60) { y = 29;      xx = tt - 30; }
        else if (tt < 88) { y = tt - 59; xx = 0; }
        else              { y = tt - 87; xx = 29; }
        uint4* p4 = (uint4*)(base + ((size_t)b * 900 + y * 30 + xx) * 32);
        uint4 z = make_uint4(0u, 0u, 0u, 0u);
        p4[0] = z; p4[1] = z; p4[2] = z; p4[3] = z;
    }
}

// ------- weight prep -------
__global__ void wcvt(const float* __restrict__ wp, const float* __restrict__ w2,
                     const float* __restrict__ w3, const float* __restrict__ w1,
                     const float* __restrict__ g1, const float* __restrict__ b1,
                     const float* __restrict__ m1, const float* __restrict__ v1,
                     const float* __restrict__ g3, const float* __restrict__ b3,
                     const float* __restrict__ m3, const float* __restrict__ v3,
                     unsigned short* __restrict__ wpbf, unsigned short* __restrict__ w2bf,
                     unsigned short* __restrict__ w3bf, float* __restrict__ w1t,
                     float* __restrict__ c1p, float* __restrict__ c3p)
{
    int t = blockIdx.x * 256 + threadIdx.x;
    if (t < 9216) {
        int oc = t / 288, k = t % 288;
        int n = k >> 5, ic = k & 31;
        wpbf[t] = (oc < 18) ? f2bf(wp[oc * 288 + ic * 9 + n]) : (unsigned short)0;
    } else if (t < 18432) {
        int i = t - 9216;
        int oc = i / 288, k = i % 288;
        int n = k >> 5, ic = k & 31;
        w2bf[i] = f2bf(w2[oc * 288 + ic * 9 + n]);
    } else if (t < 36864) {
        int i = t - 18432;
        int oc = i / 288, k = i % 288;
        int n = k >> 5, ic = k & 31;
        w3bf[i] = f2bf(w3[oc * 288 + ic * 9 + n]);
    } else if (t < 37728) {
        int i = t - 36864;        // i = k*32 + oc, k = n*3+ic
        int k = i >> 5, oc = i & 31;
        int n = k / 3, ic = k % 3;
        w1t[i] = w1[oc * 27 + ic * 9 + n];
    } else if (t < 37792) {
        int oc = t - 37728;       // 0..63
        int c = oc & 31;
        float inv = g1[c] * rsqrtf(v1[c] + 1e-5f);
        c1p[oc] = (oc < 32) ? inv : (b1[c] - m1[c] * inv);
    } else if (t < 37920) {
        int i = t - 37792;        // 0..127
        int k = i & 63;
        float inv = g3[k] * rsqrtf(v3[k] + 1e-5f);
        c3p[i] = (i < 64) ? inv : (b3[k] - m3[k] * inv);
    }
}

// ---------------- conv1: 3->32 pad1, relu, bn -> h1p (bf16 padded) ----------------
__global__ __launch_bounds__(256) void conv1_kernel(
    const float* __restrict__ x, const float* __restrict__ w1t,
    const float* __restrict__ c1p, unsigned short* __restrict__ h1p)
{
    __shared__ float xs[2352];
    int tid = threadIdx.x, b = blockIdx.x;
    {
        const float4* xg = (const float4*)(x + (size_t)b * 2352);
        float4* xl = (float4*)xs;
        for (int i = tid; i < 588; i += 256) xl[i] = xg[i];
    }
    __syncthreads();

    for (int p = tid; p < HWP; p += 256) {
        int y = p / WW, xx = p % WW;
        float acc[32];
#pragma unroll
        for (int i = 0; i < 32; i++) acc[i] = 0.f;

#pragma unroll
        for (int n = 0; n < 9; n++) {
            int yy = y + n / 3 - 1, xc = xx + n % 3 - 1;
            bool ok = (yy >= 0 && yy < HH && xc >= 0 && xc < WW);
#pragma unroll
            for (int ic = 0; ic < 3; ic++) {
                float val = ok ? xs[ic * HWP + yy * WW + xc] : 0.f;
                const float* wr = w1t + (n * 3 + ic) * 32;
#pragma unroll
                for (int oc = 0; oc < 32; oc++) acc[oc] += val * wr[oc];
            }
        }

        unsigned short* outp = h1p + ((size_t)b * 900 + (size_t)(y + 1) * 30 + (xx + 1)) * 32;
        uint4* o4 = (uint4*)outp;
#pragma unroll
        for (int j = 0; j < 4; j++) {
            unsigned wv[4];
#pragma unroll
            for (int h = 0; h < 4; h++) {
                int oc = j * 8 + h * 2;
                float r0 = fmaxf(acc[oc], 0.f) * c1p[oc] + c1p[32 + oc];
                float r1 = fmaxf(acc[oc + 1], 0.f) * c1p[oc + 1] + c1p[32 + oc + 1];
                wv[h] = (unsigned)f2bf(r0) | ((unsigned)f2bf(r1) << 16);
            }
            o4[j] = make_uint4(wv[0], wv[1], wv[2], wv[3]);
        }
    }
}

static __device__ __forceinline__ unsigned bilerp2(unsigned e00, unsigned e11, unsigned e01, unsigned e10,
                                                   float glt, float grb, float glb, float grt)
{
    float f0 = glt * __uint_as_float(e00 << 16) + grb * __uint_as_float(e11 << 16)
             + glb * __uint_as_float(e01 << 16) + grt * __uint_as_float(e10 << 16);
    float f1 = glt * __uint_as_float(e00 & 0xffff0000u) + grb * __uint_as_float(e11 & 0xffff0000u)
             + glb * __uint_as_float(e01 & 0xffff0000u) + grt * __uint_as_float(e10 & 0xffff0000u);
    return (unsigned)f2bf(f0) | ((unsigned)f2bf(f1) << 16);
}

// swizzled LDS pixel address: 64 B/pixel, slot XOR-swizzled by pixel index
static __device__ __forceinline__ int sw_addr(int px, int slot) {
    return px * 64 + ((slot ^ (px & 3)) << 4);
}

// ------- fused: p_conv (MFMA) -> offsets (per-wave LDS) -> bilinear A-frags -> conv2 MFMA -> bn -> h2p -------
__global__ __launch_bounds__(512, 2) void deform_fused(
    const unsigned short* __restrict__ h1p, const unsigned short* __restrict__ wpbf,
    const float* __restrict__ bp, const unsigned short* __restrict__ w2bf,
    const float* __restrict__ g2, const float* __restrict__ b2,
    const float* __restrict__ m2, const float* __restrict__ v2,
    unsigned short* __restrict__ h2p)
{
    __shared__ __align__(16) unsigned short img[785 * 32];   // interior 784 px + 1 zero slot, swizzled
    __shared__ float offtile[8 * 288];                       // per-wave [16 px][18 ch]
    int t = threadIdx.x, b = blockIdx.x;
    {
        const uint4* src = (const uint4*)(h1p + (size_t)b * 28800);
        char* ib = (char*)img;
        for (int i = t; i < 3136; i += 512) {
            int px = i >> 2, j = i & 3;
            int y = px / 28, xx = px % 28;
            uint4 v = src[((y + 1) * 30 + xx + 1) * 4 + j];
            *(uint4*)(ib + sw_addr(px, j)) = v;
        }
        if (t < 4) *(uint4*)(ib + 784 * 64 + t * 16) = make_uint4(0u, 0u, 0u, 0u);
    }
    int w = t >> 6, l = t & 63, col = l & 15, q = l >> 4;

    short8 bpf[18], b2f[18];
#pragma unroll
    for (int n = 0; n < 9; n++) {
        bpf[n]     = *(const short8*)(wpbf + col * 288 + n * 32 + q * 8);
        bpf[9 + n] = *(const short8*)(wpbf + (16 + col) * 288 + n * 32 + q * 8);
        b2f[n]     = *(const short8*)(w2bf + col * 288 + n * 32 + q * 8);
        b2f[9 + n] = *(const short8*)(w2bf + (16 + col) * 288 + n * 32 + q * 8);
    }
    float bias0 = bp[col];
    float bias1 = (col < 2) ? bp[16 + col] : 0.f;
    float inv0 = g2[col] * rsqrtf(v2[col] + 1e-5f);
    float sh0 = b2[col] - m2[col] * inv0;
    float inv1 = g2[16 + col] * rsqrtf(v2[16 + col] + 1e-5f);
    float sh1 = b2[16 + col] - m2[16 + col] * inv1;

    __syncthreads();
    const char* ib = (const char*)img;
    float* otw = offtile + w * 288;
    unsigned short* h2b = h2p + (size_t)b * 28800;

    for (int mt = w; mt < 49; mt += 8) {
        int p = mt * 16 + col;
        int y = p / 28, xx = p % 28;

        // ---- p_conv for this 16-pixel tile (A rows = pixels, oc in 2 tiles) ----
        floatx4 a0 = {0.f, 0.f, 0.f, 0.f}, a1 = {0.f, 0.f, 0.f, 0.f};
#pragma unroll
        for (int n = 0; n < 9; n++) {
            int yy = y + n / 3 - 1, xc = xx + n % 3 - 1;
            bool ok = ((unsigned)yy < 28u) && ((unsigned)xc < 28u);
            int tp = ok ? (yy * 28 + xc) : 784;      // 784 = zero slot
            short8 a = *(const short8*)(ib + sw_addr(tp, q));
            a0 = __builtin_amdgcn_mfma_f32_16x16x32_bf16(a, bpf[n], a0, 0, 0, 0);
            a1 = __builtin_amdgcn_mfma_f32_16x16x32_bf16(a, bpf[9 + n], a1, 0, 0, 0);
        }
#pragma unroll
        for (int r = 0; r < 4; r++)
            otw[(q * 4 + r) * 18 + col] = a0[r] + bias0;
        if (col < 2) {
#pragma unroll
            for (int r = 0; r < 4; r++)
                otw[(q * 4 + r) * 18 + 16 + col] = a1[r] + bias1;
        }
        __asm__ volatile("s_waitcnt lgkmcnt(0)" ::: "memory");

        // ---- bilinear A-frags + conv2 MFMA ----
        floatx4 d0 = {0.f, 0.f, 0.f, 0.f}, d1 = {0.f, 0.f, 0.f, 0.f};
#pragma unroll
        for (int n = 0; n < 9; n++) {
            float offy = otw[col * 18 + n];
            float offx = otw[col * 18 + 9 + n];
            float py = (float)(y + n / 3) + offy;       // padded coords
            float px = (float)(xx + n % 3) + offx;
            float fy = floorf(py), fx = floorf(px);
            float qy0 = fminf(fmaxf(fy, 0.f), 29.f);
            float qy1 = fminf(fmaxf(fy + 1.f, 0.f), 29.f);
            float qx0 = fminf(fmaxf(fx, 0.f), 29.f);
            float qx1 = fminf(fmaxf(fx + 1.f, 0.f), 29.f);
            float pyc = fminf(fmaxf(py, 0.f), 29.f);
            float pxc = fminf(fmaxf(px, 0.f), 29.f);
            float glt = (1.f + (qy0 - pyc)) * (1.f + (qx0 - pxc));
            float grb = (1.f - (qy1 - pyc)) * (1.f - (qx1 - pxc));
            float glb = (1.f + (qy0 - pyc)) * (1.f - (qx1 - pxc));
            float grt = (1.f - (qy1 - pyc)) * (1.f + (qx0 - pxc));
            int iy0 = (int)qy0, iy1 = (int)qy1, ix0 = (int)qx0, ix1 = (int)qx1;
            // padded -> interior coords with zero-slot fallback
            int ly0 = iy0 - 1, ly1 = iy1 - 1, lx0 = ix0 - 1, lx1 = ix1 - 1;
            bool v00 = ((unsigned)ly0 < 28u) && ((unsigned)lx0 < 28u);
            bool v11 = ((unsigned)ly1 < 28u) && ((unsigned)lx1 < 28u);
            bool v01 = ((unsigned)ly0 < 28u) && ((unsigned)lx1 < 28u);
            bool v10 = ((unsigned)ly1 < 28u) && ((unsigned)lx0 < 28u);
            int p00 = v00 ? (ly0 * 28 + lx0) : 784;
            int p11 = v11 ? (ly1 * 28 + lx1) : 784;
            int p01 = v01 ? (ly0 * 28 + lx1) : 784;
            int p10 = v10 ? (ly1 * 28 + lx0) : 784;
            uint4 u00 = *(const uint4*)(ib + sw_addr(p00, q));
            uint4 u11 = *(const uint4*)(ib + sw_addr(p11, q));
            uint4 u01 = *(const uint4*)(ib + sw_addr(p01, q));
            uint4 u10 = *(const uint4*)(ib + sw_addr(p10, q));
            unsigned o0 = bilerp2(u00.x, u11.x, u01.x, u10.x, glt, grb, glb, grt);
            unsigned o1 = bilerp2(u00.y, u11.y, u01.y, u10.y, glt, grb, glb, grt);
            unsigned o2 = bilerp2(u00.z, u11.z, u01.z, u10.z, glt, grb, glb, grt);
            unsigned o3 = bilerp2(u00.w, u11.w, u01.w, u10.w, glt, grb, glb, grt);
            uint4 af4 = make_uint4(o0, o1, o2, o3);
            short8 af = *(short8*)&af4;
            d0 = __builtin_amdgcn_mfma_f32_16x16x32_bf16(af, b2f[n], d0, 0, 0, 0);
            d1 = __builtin_amdgcn_mfma_f32_16x16x32_bf16(af, b2f[9 + n], d1, 0, 0, 0);
        }
        // ---- bn2 + store ----
#pragma unroll
        for (int r = 0; r < 4; r++) {
            int pout = mt * 16 + q * 4 + r;
            int yo = pout / 28, xo = pout % 28;
            int base = ((yo + 1) * 30 + xo + 1) * 32;
            h2b[base + col]      = f2bf(fmaxf(d0[r], 0.f) * inv0 + sh0);
            h2b[base + 16 + col] = f2bf(fmaxf(d1[r], 0.f) * inv1 + sh1);
        }
    }
}

// ------- conv3 MFMA + relu + partial global-sum -> pooled2[bi][64] (2 blocks/image) -------
__global__ __launch_bounds__(512, 4) void conv3_mfma(
    const unsigned short* __restrict__ h2p, const unsigned short* __restrict__ w3bf,
    float* __restrict__ pooled2)
{
    __shared__ __align__(16) unsigned short img2[17 * 30 * 32];   // swizzled, max 17 padded rows
    __shared__ float part[8][32];
    int t = threadIdx.x, bi = blockIdx.x;
    int b = bi >> 1, half = bi & 1;
    int row0 = half ? 14 : 0;          // padded row range [row0, row0+nrows)
    int nrows = half ? 16 : 17;
    int start = half ? 25 : 0, end = half ? 49 : 25;
    {
        const uint4* src = (const uint4*)(h2p + (size_t)b * 28800 + (size_t)row0 * 30 * 32);
        char* ib = (char*)img2;
        int ntot = nrows * 30 * 4;
        for (int i = t; i < ntot; i += 512) {
            int px = i >> 2, j = i & 3;
            *(uint4*)(ib + sw_addr(px, j)) = src[i];
        }
    }
    int w = t >> 6, l = t & 63, col = l & 15, q = l >> 4;
    int ocp = w & 1;                         // oc half: tiles {2p, 2p+1}
    short8 bA[9], bB[9];
#pragma unroll
    for (int n = 0; n < 9; n++) {
        bA[n] = *(const short8*)(w3bf + (ocp * 32 + col) * 288 + n * 32 + q * 8);
        bB[n] = *(const short8*)(w3bf + (ocp * 32 + 16 + col) * 288 + n * 32 + q * 8);
    }
    __syncthreads();

    const char* ib = (const char*)img2;
    float psA = 0.f, psB = 0.f;
    for (int mt = start + (w >> 1); mt < end; mt += 4) {
        int p = mt * 16 + col;
        int y = p / 28, xx = p % 28;
        int lp0 = (y + 1 - row0) * 30 + (xx + 1);
        floatx4 cA = {0.f, 0.f, 0.f, 0.f}, cB = {0.f, 0.f, 0.f, 0.f};
#pragma unroll
        for (int n = 0; n < 9; n++) {
            int lp = lp0 + (n / 3 - 1) * 30 + (n % 3 - 1);
            short8 a = *(const short8*)(ib + sw_addr(lp, q));
            cA = __builtin_amdgcn_mfma_f32_16x16x32_bf16(a, bA[n], cA, 0, 0, 0);
            cB = __builtin_amdgcn_mfma_f32_16x16x32_bf16(a, bB[n], cB, 0, 0, 0);
        }
        psA += fmaxf(cA[0], 0.f) + fmaxf(cA[1], 0.f) + fmaxf(cA[2], 0.f) + fmaxf(cA[3], 0.f);
        psB += fmaxf(cB[0], 0.f) + fmaxf(cB[1], 0.f) + fmaxf(cB[2], 0.f) + fmaxf(cB[3], 0.f);
    }
    psA += __shfl_xor(psA, 16, 64); psA += __shfl_xor(psA, 32, 64);
    psB += __shfl_xor(psB, 16, 64); psB += __shfl_xor(psB, 32, 64);
    if (l < 16) { part[w][l] = psA; part[w][16 + l] = psB; }
    __syncthreads();
    if (t < 64) {
        int hi = t >> 5;                     // which oc half
        float s = part[hi][t & 31] + part[hi + 2][t & 31] + part[hi + 4][t & 31] + part[hi + 6][t & 31];
        pooled2[(size_t)bi * 64 + t] = s;    // relu-sum partial; BN applied in cls via c3p
    }
}

// -------- classifier: combine halves, bn3, mean, linear 64->10, log_softmax --------
__global__ __launch_bounds__(256) void cls_kernel(
    const float* __restrict__ pooled2, const float* __restrict__ c3p,
    const float* __restrict__ wc, const float* __restrict__ bc,
    float* __restrict__ outp)
{
    int b = threadIdx.x;
    float feat[64];
#pragma unroll
    for (int k = 0; k < 64; k++) {
        float s = pooled2[(size_t)(2 * b) * 64 + k] + pooled2[(size_t)(2 * b + 1) * 64 + k];
        feat[k] = s * c3p[k] * (1.f / 784.f) + c3p[64 + k];
    }
    float lg[10];
    float mx = -1e30f;
#pragma unroll
    for (int j = 0; j < 10; j++) {
        float s = bc[j];
#pragma unroll
        for (int k = 0; k < 64; k++) s += feat[k] * wc[j * 64 + k];
        lg[j] = s;
        mx = fmaxf(mx, s);
    }
    float se = 0.f;
#pragma unroll
    for (int j = 0; j < 10; j++) se += expf(lg[j] - mx);
    float lse = logf(se);
#pragma unroll
    for (int j = 0; j < 10; j++) outp[b * 10 + j] = lg[j] - mx - lse;
}

extern "C" void kernel_launch(void* const* d_in, const int* in_sizes, int n_in,
                              void* d_out, int out_size, void* d_ws, size_t ws_size,
                              hipStream_t stream)
{
    (void)in_sizes; (void)n_in; (void)out_size; (void)ws_size;
    const float* x  = (const float*)d_in[0];
    const float* w1 = (const float*)d_in[1];
    const float* g1 = (const float*)d_in[2];
    const float* b1 = (const float*)d_in[3];
    const float* m1 = (const float*)d_in[4];
    const float* v1 = (const float*)d_in[5];
    const float* wp = (const float*)d_in[6];
    const float* bp = (const float*)d_in[7];
    const float* w2 = (const float*)d_in[8];
    const float* g2 = (const float*)d_in[9];
    const float* b2 = (const float*)d_in[10];
    const float* m2 = (const float*)d_in[11];
    const float* v2 = (const float*)d_in[12];
    const float* w3 = (const float*)d_in[13];
    const float* g3 = (const float*)d_in[14];
    const float* b3 = (const float*)d_in[15];
    const float* m3 = (const float*)d_in[16];
    const float* v3 = (const float*)d_in[17];
    const float* wc = (const float*)d_in[18];
    const float* bc = (const float*)d_in[19];
    float* outp = (float*)d_out;

    unsigned char* ws = (unsigned char*)d_ws;
    unsigned short* h1p  = (unsigned short*)(ws + H1P_OFF);
    unsigned short* h2p  = (unsigned short*)(ws + H2P_OFF);
    unsigned short* wpbf = (unsigned short*)(ws + WPBF_OFF);
    unsigned short* w2bf = (unsigned short*)(ws + W2BF_OFF);
    unsigned short* w3bf = (unsigned short*)(ws + W3BF_OFF);
    float*          pooled2 = (float*)(ws + POOL2_OFF);
    float*          w1t  = (float*)(ws + W1T_OFF);
    float*          c1p  = (float*)(ws + C1P_OFF);
    float*          c3p  = (float*)(ws + C3P_OFF);

    border_zero<<<NB, 256, 0, stream>>>(h1p, h2p);
    wcvt<<<149, 256, 0, stream>>>(wp, w2, w3, w1, g1, b1, m1, v1, g3, b3, m3, v3,
                                  wpbf, w2bf, w3bf, w1t, c1p, c3p);
    conv1_kernel<<<NB, 256, 0, stream>>>(x, w1t, c1p, h1p);
    deform_fused<<<NB, 512, 0, stream>>>(h1p, wpbf, bp, w2bf, g2, b2, m2, v2, h2p);
    conv3_mfma<<<2 * NB, 512, 0, stream>>>(h2p, w3bf, pooled2);
    cls_kernel<<<1, 256, 0, stream>>>(pooled2, c3p, wc, bc, outp);
}

// Round 5
// 183.794 us; speedup vs baseline: 4.3162x; 1.1108x over previous
//
#include <hip/hip_runtime.h>
#include <hip/hip_bf16.h>
#include <math.h>

typedef __attribute__((ext_vector_type(8))) short short8;   // 8 bf16 = 4 VGPRs (MFMA A/B frag)
typedef __attribute__((ext_vector_type(4))) float floatx4;  // MFMA C/D frag
typedef __attribute__((ext_vector_type(2))) float floatx2;

#define NB  256
#define HH  28
#define WW  28
#define HWP 784

// ---------------- workspace layout (bytes) ----------------
#define H1P_OFF   0u           // 256*900*32 bf16 (padded 30x30, [b][p30][c])
#define H2P_OFF   14745600u    // same
#define WPBF_OFF  29491200u    // 32*288 bf16 (rows>=18 zero)
#define W2BF_OFF  29509632u    // 32*288 bf16
#define W3BF_OFF  29528064u    // 64*288 bf16
#define POOL2_OFF 29564928u    // 512*64 f32
#define C1P_OFF   29696000u    // 64 f32
#define C3P_OFF   29696256u    // 128 f32
#define W1BF_OFF  29696768u    // 32*32 bf16 ([oc][k=n*3+ic], k>=27 zero)

static __device__ __forceinline__ unsigned short f2bf(float f) {
    unsigned u = __float_as_uint(f);
    u = (u + 0x7fffu + ((u >> 16) & 1u)) >> 16;   // RNE
    return (unsigned short)u;
}

static __device__ __forceinline__ unsigned pk2bf(float a, float b) {
    __hip_bfloat162 h = __float22bfloat162_rn(make_float2(a, b));
    unsigned r;
    __builtin_memcpy(&r, &h, 4);
    return r;
}

static __device__ __forceinline__ floatx2 up2(unsigned u) {
    floatx2 r;
    r.x = __uint_as_float(u << 16);
    r.y = __uint_as_float(u & 0xffff0000u);
    return r;
}

// 80-byte pixel stride in LDS: bank-group = (5*px + s) mod 8 (period 8 in px)
static __device__ __forceinline__ int sw80(int px, int s) {
    return px * 80 + s * 16;
}

// ---------------- zero the padded borders of h2p ----------------
__global__ __launch_bounds__(128) void border_zero(unsigned short* __restrict__ h2p)
{
    int b = blockIdx.x, t = threadIdx.x;
    if (t < 116) {
        int y, xx;
        if (t < 30)      { y = 0;      xx = t; }
        else if (t < 60) { y = 29;     xx = t - 30; }
        else if (t < 88) { y = t - 59; xx = 0; }
        else             { y = t - 87; xx = 29; }
        uint4* p4 = (uint4*)(h2p + ((size_t)b * 900 + y * 30 + xx) * 32);
        uint4 z = make_uint4(0u, 0u, 0u, 0u);
        p4[0] = z; p4[1] = z; p4[2] = z; p4[3] = z;
    }
}

// ------- weight prep -------
__global__ void wcvt(const float* __restrict__ wp, const float* __restrict__ w2,
                     const float* __restrict__ w3, const float* __restrict__ w1,
                     const float* __restrict__ g1, const float* __restrict__ b1,
                     const float* __restrict__ m1, const float* __restrict__ v1,
                     const float* __restrict__ g3, const float* __restrict__ b3,
                     const float* __restrict__ m3, const float* __restrict__ v3,
                     unsigned short* __restrict__ wpbf, unsigned short* __restrict__ w2bf,
                     unsigned short* __restrict__ w3bf, unsigned short* __restrict__ w1bf,
                     float* __restrict__ c1p, float* __restrict__ c3p)
{
    int t = blockIdx.x * 256 + threadIdx.x;
    if (t < 9216) {
        int oc = t / 288, k = t % 288;
        int n = k >> 5, ic = k & 31;
        wpbf[t] = (oc < 18) ? f2bf(wp[oc * 288 + ic * 9 + n]) : (unsigned short)0;
    } else if (t < 18432) {
        int i = t - 9216;
        int oc = i / 288, k = i % 288;
        int n = k >> 5, ic = k & 31;
        w2bf[i] = f2bf(w2[oc * 288 + ic * 9 + n]);
    } else if (t < 36864) {
        int i = t - 18432;
        int oc = i / 288, k = i % 288;
        int n = k >> 5, ic = k & 31;
        w3bf[i] = f2bf(w3[oc * 288 + ic * 9 + n]);
    } else if (t < 36928) {
        int oc = t - 36864;       // 0..63
        int c = oc & 31;
        float inv = g1[c] * rsqrtf(v1[c] + 1e-5f);
        c1p[oc] = (oc < 32) ? inv : (b1[c] - m1[c] * inv);
    } else if (t < 37056) {
        int i = t - 36928;        // 0..127
        int k = i & 63;
        float inv = g3[k] * rsqrtf(v3[k] + 1e-5f);
        c3p[i] = (i < 64) ? inv : (b3[k] - m3[k] * inv);
    } else if (t < 38080) {
        int i = t - 37056;        // i = oc*32 + k, k = n*3+ic
        int oc = i >> 5, k = i & 31;
        int n = k / 3, ic = k - n * 3;
        w1bf[i] = (k < 27) ? f2bf(w1[oc * 27 + ic * 9 + n]) : (unsigned short)0;
    }
}

// ---------------- conv1 as MFMA: 3->32 pad1, relu, bn -> h1p (bf16 padded) ----------------
__global__ __launch_bounds__(256) void conv1_mfma(
    const float* __restrict__ x, const unsigned short* __restrict__ w1bf,
    const float* __restrict__ c1p, unsigned short* __restrict__ h1p)
{
    __shared__ float xs[2356];     // [3][784] + zero slot at 2352
    int t = threadIdx.x, b = blockIdx.x;
    {
        const float4* xg = (const float4*)(x + (size_t)b * 2352);
        float4* xl = (float4*)xs;
        for (int i = t; i < 588; i += 256) xl[i] = xg[i];
        if (t == 0) xs[2352] = 0.f;
    }
    int w = t >> 6, l = t & 63, col = l & 15, q = l >> 4;
    short8 bf0 = *(const short8*)(w1bf + col * 32 + q * 8);
    short8 bf1 = *(const short8*)(w1bf + (16 + col) * 32 + q * 8);
    float sc0 = c1p[col],      sh0 = c1p[32 + col];
    float sc1 = c1p[16 + col], sh1 = c1p[48 + col];
    __syncthreads();

    unsigned short* h1b = h1p + (size_t)b * 28800;
    for (int mt = w; mt < 49; mt += 4) {
        int p = mt * 16 + col;
        int y = p / 28, xx = p % 28;
        unsigned au[4];
#pragma unroll
        for (int jp = 0; jp < 4; jp++) {
            float vv[2];
#pragma unroll
            for (int h = 0; h < 2; h++) {
                int k = q * 8 + jp * 2 + h;
                int n = k / 3, ic = k - n * 3;
                int yy = y + n / 3 - 1, xc = xx + n % 3 - 1;
                bool ok = (k < 27) && ((unsigned)yy < 28u) && ((unsigned)xc < 28u);
                int idx = ok ? (ic * 784 + yy * 28 + xc) : 2352;
                vv[h] = xs[idx];
            }
            au[jp] = pk2bf(vv[0], vv[1]);
        }
        uint4 a4 = make_uint4(au[0], au[1], au[2], au[3]);
        short8 a = *(short8*)&a4;
        floatx4 d0 = {0.f, 0.f, 0.f, 0.f}, d1 = {0.f, 0.f, 0.f, 0.f};
        d0 = __builtin_amdgcn_mfma_f32_16x16x32_bf16(a, bf0, d0, 0, 0, 0);
        d1 = __builtin_amdgcn_mfma_f32_16x16x32_bf16(a, bf1, d1, 0, 0, 0);
#pragma unroll
        for (int r = 0; r < 4; r++) {
            int pout = mt * 16 + q * 4 + r;
            int yo = pout / 28, xo = pout % 28;
            int base = ((yo + 1) * 30 + xo + 1) * 32;
            h1b[base + col]      = f2bf(fmaxf(d0[r], 0.f) * sc0 + sh0);
            h1b[base + 16 + col] = f2bf(fmaxf(d1[r], 0.f) * sc1 + sh1);
        }
    }
}

// ------- fused: p_conv (MFMA) -> offsets (per-wave LDS) -> bilinear A-frags -> conv2 MFMA -> bn -> h2p -------
__global__ __launch_bounds__(512, 2) void deform_fused(
    const unsigned short* __restrict__ h1p, const unsigned short* __restrict__ wpbf,
    const float* __restrict__ bp, const unsigned short* __restrict__ w2bf,
    const float* __restrict__ g2, const float* __restrict__ b2,
    const float* __restrict__ m2, const float* __restrict__ v2,
    unsigned short* __restrict__ h2p)
{
    __shared__ __align__(16) unsigned char imgb_s[785 * 80];  // interior 784 px + zero slot, 80B stride
    __shared__ float offtile[8 * 288];                        // per-wave [16 px][18 ch]
    int t = threadIdx.x, bi = blockIdx.x;
    int b = bi >> 1, half = bi & 1;
    int start = half ? 25 : 0, end = half ? 49 : 25;
    {
        const uint4* src = (const uint4*)(h1p + (size_t)b * 28800);
        for (int i = t; i < 3136; i += 512) {
            int px = i >> 2, j = i & 3;
            int y = px / 28, xx = px % 28;
            uint4 v = src[((y + 1) * 30 + xx + 1) * 4 + j];
            *(uint4*)(imgb_s + sw80(px, j)) = v;
        }
        if (t < 4) *(uint4*)(imgb_s + sw80(784, t)) = make_uint4(0u, 0u, 0u, 0u);
    }
    int w = t >> 6, l = t & 63, col = l & 15, q = l >> 4;

    short8 bpf[18], b2f[18];
#pragma unroll
    for (int n = 0; n < 9; n++) {
        bpf[n]     = *(const short8*)(wpbf + col * 288 + n * 32 + q * 8);
        bpf[9 + n] = *(const short8*)(wpbf + (16 + col) * 288 + n * 32 + q * 8);
        b2f[n]     = *(const short8*)(w2bf + col * 288 + n * 32 + q * 8);
        b2f[9 + n] = *(const short8*)(w2bf + (16 + col) * 288 + n * 32 + q * 8);
    }
    float bias0 = bp[col];
    float bias1 = (col < 2) ? bp[16 + col] : 0.f;
    float inv0 = g2[col] * rsqrtf(v2[col] + 1e-5f);
    float sh0 = b2[col] - m2[col] * inv0;
    float inv1 = g2[16 + col] * rsqrtf(v2[16 + col] + 1e-5f);
    float sh1 = b2[16 + col] - m2[16 + col] * inv1;

    __syncthreads();
    const unsigned char* ib = imgb_s;
    float* otw = offtile + w * 288;
    unsigned short* h2b = h2p + (size_t)b * 28800;

    for (int mt = start + w; mt < end; mt += 8) {
        int p = mt * 16 + col;
        int y = p / 28, xx = p % 28;

        // ---- p_conv for this 16-pixel tile ----
        floatx4 a0 = {0.f, 0.f, 0.f, 0.f}, a1 = {0.f, 0.f, 0.f, 0.f};
#pragma unroll
        for (int n = 0; n < 9; n++) {
            int yy = y + n / 3 - 1, xc = xx + n % 3 - 1;
            bool ok = ((unsigned)yy < 28u) && ((unsigned)xc < 28u);
            int tp = ok ? (yy * 28 + xc) : 784;      // 784 = zero slot
            short8 a = *(const short8*)(ib + sw80(tp, q));
            a0 = __builtin_amdgcn_mfma_f32_16x16x32_bf16(a, bpf[n], a0, 0, 0, 0);
            a1 = __builtin_amdgcn_mfma_f32_16x16x32_bf16(a, bpf[9 + n], a1, 0, 0, 0);
        }
#pragma unroll
        for (int r = 0; r < 4; r++)
            otw[(q * 4 + r) * 18 + col] = a0[r] + bias0;
        if (col < 2) {
#pragma unroll
            for (int r = 0; r < 4; r++)
                otw[(q * 4 + r) * 18 + 16 + col] = a1[r] + bias1;
        }
        __asm__ volatile("s_waitcnt lgkmcnt(0)" ::: "memory");

        // ---- bilinear A-frags + conv2 MFMA ----
        floatx4 d0 = {0.f, 0.f, 0.f, 0.f}, d1 = {0.f, 0.f, 0.f, 0.f};
#pragma unroll
        for (int n = 0; n < 9; n++) {
            float offy = otw[col * 18 + n];
            float offx = otw[col * 18 + 9 + n];
            float py = (float)(y + n / 3) + offy;       // padded coords
            float px = (float)(xx + n % 3) + offx;
            float fy = floorf(py), fx = floorf(px);
            float qy0 = fminf(fmaxf(fy, 0.f), 29.f);
            float qy1 = fminf(fmaxf(fy + 1.f, 0.f), 29.f);
            float qx0 = fminf(fmaxf(fx, 0.f), 29.f);
            float qx1 = fminf(fmaxf(fx + 1.f, 0.f), 29.f);
            float pyc = fminf(fmaxf(py, 0.f), 29.f);
            float pxc = fminf(fmaxf(px, 0.f), 29.f);
            float glt = (1.f + (qy0 - pyc)) * (1.f + (qx0 - pxc));
            float grb = (1.f - (qy1 - pyc)) * (1.f - (qx1 - pxc));
            float glb = (1.f + (qy0 - pyc)) * (1.f - (qx1 - pxc));
            float grt = (1.f - (qy1 - pyc)) * (1.f + (qx0 - pxc));
            int iy0 = (int)qy0, iy1 = (int)qy1, ix0 = (int)qx0, ix1 = (int)qx1;
            int ly0 = iy0 - 1, ly1 = iy1 - 1, lx0 = ix0 - 1, lx1 = ix1 - 1;
            bool v00 = ((unsigned)ly0 < 28u) && ((unsigned)lx0 < 28u);
            bool v11 = ((unsigned)ly1 < 28u) && ((unsigned)lx1 < 28u);
            bool v01 = ((unsigned)ly0 < 28u) && ((unsigned)lx1 < 28u);
            bool v10 = ((unsigned)ly1 < 28u) && ((unsigned)lx0 < 28u);
            int p00 = v00 ? (ly0 * 28 + lx0) : 784;
            int p11 = v11 ? (ly1 * 28 + lx1) : 784;
            int p01 = v01 ? (ly0 * 28 + lx1) : 784;
            int p10 = v10 ? (ly1 * 28 + lx0) : 784;
            uint4 u00 = *(const uint4*)(ib + sw80(p00, q));
            uint4 u11 = *(const uint4*)(ib + sw80(p11, q));
            uint4 u01 = *(const uint4*)(ib + sw80(p01, q));
            uint4 u10 = *(const uint4*)(ib + sw80(p10, q));
            floatx2 f0 = up2(u00.x) * glt + up2(u11.x) * grb + up2(u01.x) * glb + up2(u10.x) * grt;
            floatx2 f1 = up2(u00.y) * glt + up2(u11.y) * grb + up2(u01.y) * glb + up2(u10.y) * grt;
            floatx2 f2 = up2(u00.z) * glt + up2(u11.z) * grb + up2(u01.z) * glb + up2(u10.z) * grt;
            floatx2 f3 = up2(u00.w) * glt + up2(u11.w) * grb + up2(u01.w) * glb + up2(u10.w) * grt;
            uint4 af4 = make_uint4(pk2bf(f0.x, f0.y), pk2bf(f1.x, f1.y),
                                   pk2bf(f2.x, f2.y), pk2bf(f3.x, f3.y));
            short8 af = *(short8*)&af4;
            d0 = __builtin_amdgcn_mfma_f32_16x16x32_bf16(af, b2f[n], d0, 0, 0, 0);
            d1 = __builtin_amdgcn_mfma_f32_16x16x32_bf16(af, b2f[9 + n], d1, 0, 0, 0);
        }
        // ---- bn2 + store ----
#pragma unroll
        for (int r = 0; r < 4; r++) {
            int pout = mt * 16 + q * 4 + r;
            int yo = pout / 28, xo = pout % 28;
            int base = ((yo + 1) * 30 + xo + 1) * 32;
            h2b[base + col]      = f2bf(fmaxf(d0[r], 0.f) * inv0 + sh0);
            h2b[base + 16 + col] = f2bf(fmaxf(d1[r], 0.f) * inv1 + sh1);
        }
    }
}

// ------- conv3 MFMA + relu + partial global-sum -> pooled2[bi][64] (2 blocks/image) -------
__global__ __launch_bounds__(512, 4) void conv3_mfma(
    const unsigned short* __restrict__ h2p, const unsigned short* __restrict__ w3bf,
    float* __restrict__ pooled2)
{
    __shared__ __align__(16) unsigned char img2b[510 * 80];   // 80B stride, max 17 padded rows
    __shared__ float part[8][32];
    int t = threadIdx.x, bi = blockIdx.x;
    int b = bi >> 1, half = bi & 1;
    int row0 = half ? 14 : 0;          // padded row range [row0, row0+nrows)
    int nrows = half ? 16 : 17;
    int start = half ? 25 : 0, end = half ? 49 : 25;
    {
        const uint4* src = (const uint4*)(h2p + (size_t)b * 28800 + (size_t)row0 * 30 * 32);
        int ntot = nrows * 30 * 4;
        for (int i = t; i < ntot; i += 512) {
            int px = i >> 2, j = i & 3;
            *(uint4*)(img2b + sw80(px, j)) = src[i];
        }
    }
    int w = t >> 6, l = t & 63, col = l & 15, q = l >> 4;
    int ocp = w & 1;
    short8 bA[9], bB[9];
#pragma unroll
    for (int n = 0; n < 9; n++) {
        bA[n] = *(const short8*)(w3bf + (ocp * 32 + col) * 288 + n * 32 + q * 8);
        bB[n] = *(const short8*)(w3bf + (ocp * 32 + 16 + col) * 288 + n * 32 + q * 8);
    }
    __syncthreads();

    const unsigned char* ib = img2b;
    float psA = 0.f, psB = 0.f;
    for (int mt = start + (w >> 1); mt < end; mt += 4) {
        int p = mt * 16 + col;
        int y = p / 28, xx = p % 28;
        int lp0 = (y + 1 - row0) * 30 + (xx + 1);
        floatx4 cA = {0.f, 0.f, 0.f, 0.f}, cB = {0.f, 0.f, 0.f, 0.f};
#pragma unroll
        for (int n = 0; n < 9; n++) {
            int lp = lp0 + (n / 3 - 1) * 30 + (n % 3 - 1);
            short8 a = *(const short8*)(ib + sw80(lp, q));
            cA = __builtin_amdgcn_mfma_f32_16x16x32_bf16(a, bA[n], cA, 0, 0, 0);
            cB = __builtin_amdgcn_mfma_f32_16x16x32_bf16(a, bB[n], cB, 0, 0, 0);
        }
        psA += fmaxf(cA[0], 0.f) + fmaxf(cA[1], 0.f) + fmaxf(cA[2], 0.f) + fmaxf(cA[3], 0.f);
        psB += fmaxf(cB[0], 0.f) + fmaxf(cB[1], 0.f) + fmaxf(cB[2], 0.f) + fmaxf(cB[3], 0.f);
    }
    psA += __shfl_xor(psA, 16, 64); psA += __shfl_xor(psA, 32, 64);
    psB += __shfl_xor(psB, 16, 64); psB += __shfl_xor(psB, 32, 64);
    if (l < 16) { part[w][l] = psA; part[w][16 + l] = psB; }
    __syncthreads();
    if (t < 64) {
        int hi = t >> 5;
        float s = part[hi][t & 31] + part[hi + 2][t & 31] + part[hi + 4][t & 31] + part[hi + 6][t & 31];
        pooled2[(size_t)bi * 64 + t] = s;
    }
}

// -------- classifier: combine halves, bn3, mean, linear 64->10, log_softmax --------
__global__ __launch_bounds__(256) void cls_kernel(
    const float* __restrict__ pooled2, const float* __restrict__ c3p,
    const float* __restrict__ wc, const float* __restrict__ bc,
    float* __restrict__ outp)
{
    int b = threadIdx.x;
    float feat[64];
#pragma unroll
    for (int k = 0; k < 64; k++) {
        float s = pooled2[(size_t)(2 * b) * 64 + k] + pooled2[(size_t)(2 * b + 1) * 64 + k];
        feat[k] = s * c3p[k] * (1.f / 784.f) + c3p[64 + k];
    }
    float lg[10];
    float mx = -1e30f;
#pragma unroll
    for (int j = 0; j < 10; j++) {
        float s = bc[j];
#pragma unroll
        for (int k = 0; k < 64; k++) s += feat[k] * wc[j * 64 + k];
        lg[j] = s;
        mx = fmaxf(mx, s);
    }
    float se = 0.f;
#pragma unroll
    for (int j = 0; j < 10; j++) se += expf(lg[j] - mx);
    float lse = logf(se);
#pragma unroll
    for (int j = 0; j < 10; j++) outp[b * 10 + j] = lg[j] - mx - lse;
}

extern "C" void kernel_launch(void* const* d_in, const int* in_sizes, int n_in,
                              void* d_out, int out_size, void* d_ws, size_t ws_size,
                              hipStream_t stream)
{
    (void)in_sizes; (void)n_in; (void)out_size; (void)ws_size;
    const float* x  = (const float*)d_in[0];
    const float* w1 = (const float*)d_in[1];
    const float* g1 = (const float*)d_in[2];
    const float* b1 = (const float*)d_in[3];
    const float* m1 = (const float*)d_in[4];
    const float* v1 = (const float*)d_in[5];
    const float* wp = (const float*)d_in[6];
    const float* bp = (const float*)d_in[7];
    const float* w2 = (const float*)d_in[8];
    const float* g2 = (const float*)d_in[9];
    const float* b2 = (const float*)d_in[10];
    const float* m2 = (const float*)d_in[11];
    const float* v2 = (const float*)d_in[12];
    const float* w3 = (const float*)d_in[13];
    const float* g3 = (const float*)d_in[14];
    const float* b3 = (const float*)d_in[15];
    const float* m3 = (const float*)d_in[16];
    const float* v3 = (const float*)d_in[17];
    const float* wc = (const float*)d_in[18];
    const float* bc = (const float*)d_in[19];
    float* outp = (float*)d_out;

    unsigned char* ws = (unsigned char*)d_ws;
    unsigned short* h1p  = (unsigned short*)(ws + H1P_OFF);
    unsigned short* h2p  = (unsigned short*)(ws + H2P_OFF);
    unsigned short* wpbf = (unsigned short*)(ws + WPBF_OFF);
    unsigned short* w2bf = (unsigned short*)(ws + W2BF_OFF);
    unsigned short* w3bf = (unsigned short*)(ws + W3BF_OFF);
    float*          pooled2 = (float*)(ws + POOL2_OFF);
    float*          c1p  = (float*)(ws + C1P_OFF);
    float*          c3p  = (float*)(ws + C3P_OFF);
    unsigned short* w1bf = (unsigned short*)(ws + W1BF_OFF);

    border_zero<<<NB, 128, 0, stream>>>(h2p);
    wcvt<<<149, 256, 0, stream>>>(wp, w2, w3, w1, g1, b1, m1, v1, g3, b3, m3, v3,
                                  wpbf, w2bf, w3bf, w1bf, c1p, c3p);
    conv1_mfma<<<NB, 256, 0, stream>>>(x, w1bf, c1p, h1p);
    deform_fused<<<2 * NB, 512, 0, stream>>>(h1p, wpbf, bp, w2bf, g2, b2, m2, v2, h2p);
    conv3_mfma<<<2 * NB, 512, 0, stream>>>(h2p, w3bf, pooled2);
    cls_kernel<<<1, 256, 0, stream>>>(pooled2, c3p, wc, bc, outp);
}

// Round 6
// 174.624 us; speedup vs baseline: 4.5429x; 1.0525x over previous
//
#include <hip/hip_runtime.h>
#include <hip/hip_bf16.h>
#include <math.h>

typedef __attribute__((ext_vector_type(8))) short short8;   // 8 bf16 = 4 VGPRs (MFMA A/B frag)
typedef __attribute__((ext_vector_type(4))) float floatx4;  // MFMA C/D frag
typedef __attribute__((ext_vector_type(2))) float floatx2;

#define NB  256
#define HWP 784

// ---------------- workspace layout (bytes) ----------------
#define H2P_OFF   0u           // 256*900*32 bf16 (padded 30x30, [b][p30][c])
#define WPBF_OFF  14745600u    // 32*288 bf16 (rows>=18 zero)
#define W2BF_OFF  14764032u    // 32*288 bf16
#define W3BF_OFF  14782464u    // 64*288 bf16
#define POOL_OFF  14819328u    // 256*64 f32
#define C1P_OFF   14884864u    // 64 f32
#define C3P_OFF   14885120u    // 128 f32
#define W1BF_OFF  14885632u    // 32*32 bf16 ([oc][k=n*3+ic], k>=27 zero)

static __device__ __forceinline__ unsigned short f2bf(float f) {
    unsigned u = __float_as_uint(f);
    u = (u + 0x7fffu + ((u >> 16) & 1u)) >> 16;   // RNE
    return (unsigned short)u;
}

static __device__ __forceinline__ unsigned pk2bf(float a, float b) {
    __hip_bfloat162 h = __float22bfloat162_rn(make_float2(a, b));
    unsigned r;
    __builtin_memcpy(&r, &h, 4);
    return r;
}

static __device__ __forceinline__ floatx2 up2(unsigned u) {
    floatx2 r;
    r.x = __uint_as_float(u << 16);
    r.y = __uint_as_float(u & 0xffff0000u);
    return r;
}

// 80-byte pixel stride in LDS, slot s = 16B channel-group (ch>>3)
static __device__ __forceinline__ int sw80(int px, int s) {
    return px * 80 + s * 16;
}

// ---------------- zero the padded borders of h2p ----------------
__global__ __launch_bounds__(128) void border_zero(unsigned short* __restrict__ h2p)
{
    int b = blockIdx.x, t = threadIdx.x;
    if (t < 116) {
        int y, xx;
        if (t < 30)      { y = 0;      xx = t; }
        else if (t < 60) { y = 29;     xx = t - 30; }
        else if (t < 88) { y = t - 59; xx = 0; }
        else             { y = t - 87; xx = 29; }
        uint4* p4 = (uint4*)(h2p + ((size_t)b * 900 + y * 30 + xx) * 32);
        uint4 z = make_uint4(0u, 0u, 0u, 0u);
        p4[0] = z; p4[1] = z; p4[2] = z; p4[3] = z;
    }
}

// ------- weight prep -------
__global__ void wcvt(const float* __restrict__ wp, const float* __restrict__ w2,
                     const float* __restrict__ w3, const float* __restrict__ w1,
                     const float* __restrict__ g1, const float* __restrict__ b1,
                     const float* __restrict__ m1, const float* __restrict__ v1,
                     const float* __restrict__ g3, const float* __restrict__ b3,
                     const float* __restrict__ m3, const float* __restrict__ v3,
                     unsigned short* __restrict__ wpbf, unsigned short* __restrict__ w2bf,
                     unsigned short* __restrict__ w3bf, unsigned short* __restrict__ w1bf,
                     float* __restrict__ c1p, float* __restrict__ c3p)
{
    int t = blockIdx.x * 256 + threadIdx.x;
    if (t < 9216) {
        int oc = t / 288, k = t % 288;
        int n = k >> 5, ic = k & 31;
        wpbf[t] = (oc < 18) ? f2bf(wp[oc * 288 + ic * 9 + n]) : (unsigned short)0;
    } else if (t < 18432) {
        int i = t - 9216;
        int oc = i / 288, k = i % 288;
        int n = k >> 5, ic = k & 31;
        w2bf[i] = f2bf(w2[oc * 288 + ic * 9 + n]);
    } else if (t < 36864) {
        int i = t - 18432;
        int oc = i / 288, k = i % 288;
        int n = k >> 5, ic = k & 31;
        w3bf[i] = f2bf(w3[oc * 288 + ic * 9 + n]);
    } else if (t < 36928) {
        int oc = t - 36864;       // 0..63
        int c = oc & 31;
        float inv = g1[c] * rsqrtf(v1[c] + 1e-5f);
        c1p[oc] = (oc < 32) ? inv : (b1[c] - m1[c] * inv);
    } else if (t < 37056) {
        int i = t - 36928;        // 0..127
        int k = i & 63;
        float inv = g3[k] * rsqrtf(v3[k] + 1e-5f);
        c3p[i] = (i < 64) ? inv : (b3[k] - m3[k] * inv);
    } else if (t < 38080) {
        int i = t - 37056;        // i = oc*32 + k, k = n*3+ic
        int oc = i >> 5, k = i & 31;
        int n = k / 3, ic = k - n * 3;
        w1bf[i] = (k < 27) ? f2bf(w1[oc * 27 + ic * 9 + n]) : (unsigned short)0;
    }
}

// ======= fused: conv1 (MFMA -> LDS image) -> p_conv (MFMA) -> bilinear -> conv2 MFMA -> bn -> h2p =======
__global__ __launch_bounds__(768) void fused_front(
    const float* __restrict__ x, const unsigned short* __restrict__ w1bf,
    const float* __restrict__ c1p,
    const unsigned short* __restrict__ wpbf, const float* __restrict__ bp,
    const unsigned short* __restrict__ w2bf,
    const float* __restrict__ g2, const float* __restrict__ b2,
    const float* __restrict__ m2, const float* __restrict__ v2,
    unsigned short* __restrict__ h2p)
{
    __shared__ __align__(16) unsigned char imgb_s[785 * 80];  // 784 interior px + zero slot
    __shared__ __align__(16) float scratch[3456];             // xs(2353) then offtile[12][288]
    int t = threadIdx.x, b = blockIdx.x;
    int w = t >> 6, l = t & 63, col = l & 15, q = l >> 4;

    // stage x (fp32) into scratch
    {
        const float4* xg = (const float4*)(x + (size_t)b * 2352);
        float4* xl = (float4*)scratch;
        for (int i = t; i < 588; i += 768) xl[i] = xg[i];
    }
    if (t == 767) scratch[2352] = 0.f;
    if (t < 5) *(uint4*)(imgb_s + 784 * 80 + t * 16) = make_uint4(0u, 0u, 0u, 0u);

    // weight frags (global loads, L1/L2-served)
    short8 bpf[18], b2f[18];
#pragma unroll
    for (int n = 0; n < 9; n++) {
        bpf[n]     = *(const short8*)(wpbf + col * 288 + n * 32 + q * 8);
        bpf[9 + n] = *(const short8*)(wpbf + (16 + col) * 288 + n * 32 + q * 8);
        b2f[n]     = *(const short8*)(w2bf + col * 288 + n * 32 + q * 8);
        b2f[9 + n] = *(const short8*)(w2bf + (16 + col) * 288 + n * 32 + q * 8);
    }
    float bias0 = bp[col];
    float bias1 = (col < 2) ? bp[16 + col] : 0.f;
    float inv0 = g2[col] * rsqrtf(v2[col] + 1e-5f);
    float sh0 = b2[col] - m2[col] * inv0;
    float inv1 = g2[16 + col] * rsqrtf(v2[16 + col] + 1e-5f);
    float sh1 = b2[16 + col] - m2[16 + col] * inv1;

    __syncthreads();

    // ---- conv1 phase: 3->32 pad1, relu, bn -> LDS image (bf16, 80B stride) ----
    {
        short8 bf0 = *(const short8*)(w1bf + col * 32 + q * 8);
        short8 bf1 = *(const short8*)(w1bf + (16 + col) * 32 + q * 8);
        float sc0 = c1p[col],      s0 = c1p[32 + col];
        float sc1 = c1p[16 + col], s1 = c1p[48 + col];
        const float* xs = scratch;
        for (int mt = w; mt < 49; mt += 12) {
            int p = mt * 16 + col;
            int y = p / 28, xx = p % 28;
            unsigned au[4];
#pragma unroll
            for (int jp = 0; jp < 4; jp++) {
                float vv[2];
#pragma unroll
                for (int h = 0; h < 2; h++) {
                    int k = q * 8 + jp * 2 + h;
                    int n = k / 3, ic = k - n * 3;
                    int yy = y + n / 3 - 1, xc = xx + n % 3 - 1;
                    bool ok = (k < 27) && ((unsigned)yy < 28u) && ((unsigned)xc < 28u);
                    int idx = ok ? (ic * 784 + yy * 28 + xc) : 2352;
                    vv[h] = xs[idx];
                }
                au[jp] = pk2bf(vv[0], vv[1]);
            }
            uint4 a4 = make_uint4(au[0], au[1], au[2], au[3]);
            short8 a = *(short8*)&a4;
            floatx4 d0 = {0.f, 0.f, 0.f, 0.f}, d1 = {0.f, 0.f, 0.f, 0.f};
            d0 = __builtin_amdgcn_mfma_f32_16x16x32_bf16(a, bf0, d0, 0, 0, 0);
            d1 = __builtin_amdgcn_mfma_f32_16x16x32_bf16(a, bf1, d1, 0, 0, 0);
            int g0 = (col >> 3) * 16 + (col & 7) * 2;
#pragma unroll
            for (int r = 0; r < 4; r++) {
                int pout = mt * 16 + q * 4 + r;
                *(unsigned short*)(imgb_s + pout * 80 + g0) =
                    f2bf(fmaxf(d0[r], 0.f) * sc0 + s0);
                *(unsigned short*)(imgb_s + pout * 80 + 32 + g0) =
                    f2bf(fmaxf(d1[r], 0.f) * sc1 + s1);
            }
        }
    }
    __syncthreads();

    // ---- deform phase ----
    const unsigned char* ib = imgb_s;
    float* otw = scratch + w * 288;
    unsigned short* h2b = h2p + (size_t)b * 28800;

    for (int mt = w; mt < 49; mt += 12) {
        int p = mt * 16 + col;
        int y = p / 28, xx = p % 28;

        // p_conv for this 16-pixel tile
        floatx4 a0 = {0.f, 0.f, 0.f, 0.f}, a1 = {0.f, 0.f, 0.f, 0.f};
#pragma unroll
        for (int n = 0; n < 9; n++) {
            int yy = y + n / 3 - 1, xc = xx + n % 3 - 1;
            bool ok = ((unsigned)yy < 28u) && ((unsigned)xc < 28u);
            int tp = ok ? (yy * 28 + xc) : 784;      // 784 = zero slot
            short8 a = *(const short8*)(ib + sw80(tp, q));
            a0 = __builtin_amdgcn_mfma_f32_16x16x32_bf16(a, bpf[n], a0, 0, 0, 0);
            a1 = __builtin_amdgcn_mfma_f32_16x16x32_bf16(a, bpf[9 + n], a1, 0, 0, 0);
        }
#pragma unroll
        for (int r = 0; r < 4; r++)
            otw[(q * 4 + r) * 18 + col] = a0[r] + bias0;
        if (col < 2) {
#pragma unroll
            for (int r = 0; r < 4; r++)
                otw[(q * 4 + r) * 18 + 16 + col] = a1[r] + bias1;
        }
        __asm__ volatile("s_waitcnt lgkmcnt(0)" ::: "memory");

        // bilinear A-frags + conv2 MFMA
        floatx4 d0 = {0.f, 0.f, 0.f, 0.f}, d1 = {0.f, 0.f, 0.f, 0.f};
#pragma unroll
        for (int n = 0; n < 9; n++) {
            float offy = otw[col * 18 + n];
            float offx = otw[col * 18 + 9 + n];
            float py = (float)(y + n / 3) + offy;       // padded coords
            float px = (float)(xx + n % 3) + offx;
            float fy = floorf(py), fx = floorf(px);
            float qy0 = fminf(fmaxf(fy, 0.f), 29.f);
            float qy1 = fminf(fmaxf(fy + 1.f, 0.f), 29.f);
            float qx0 = fminf(fmaxf(fx, 0.f), 29.f);
            float qx1 = fminf(fmaxf(fx + 1.f, 0.f), 29.f);
            float pyc = fminf(fmaxf(py, 0.f), 29.f);
            float pxc = fminf(fmaxf(px, 0.f), 29.f);
            float glt = (1.f + (qy0 - pyc)) * (1.f + (qx0 - pxc));
            float grb = (1.f - (qy1 - pyc)) * (1.f - (qx1 - pxc));
            float glb = (1.f + (qy0 - pyc)) * (1.f - (qx1 - pxc));
            float grt = (1.f - (qy1 - pyc)) * (1.f + (qx0 - pxc));
            int iy0 = (int)qy0, iy1 = (int)qy1, ix0 = (int)qx0, ix1 = (int)qx1;
            int ly0 = iy0 - 1, ly1 = iy1 - 1, lx0 = ix0 - 1, lx1 = ix1 - 1;
            bool v00 = ((unsigned)ly0 < 28u) && ((unsigned)lx0 < 28u);
            bool v11 = ((unsigned)ly1 < 28u) && ((unsigned)lx1 < 28u);
            bool v01 = ((unsigned)ly0 < 28u) && ((unsigned)lx1 < 28u);
            bool v10 = ((unsigned)ly1 < 28u) && ((unsigned)lx0 < 28u);
            int p00 = v00 ? (ly0 * 28 + lx0) : 784;
            int p11 = v11 ? (ly1 * 28 + lx1) : 784;
            int p01 = v01 ? (ly0 * 28 + lx1) : 784;
            int p10 = v10 ? (ly1 * 28 + lx0) : 784;
            uint4 u00 = *(const uint4*)(ib + sw80(p00, q));
            uint4 u11 = *(const uint4*)(ib + sw80(p11, q));
            uint4 u01 = *(const uint4*)(ib + sw80(p01, q));
            uint4 u10 = *(const uint4*)(ib + sw80(p10, q));
            floatx2 f0 = up2(u00.x) * glt + up2(u11.x) * grb + up2(u01.x) * glb + up2(u10.x) * grt;
            floatx2 f1 = up2(u00.y) * glt + up2(u11.y) * grb + up2(u01.y) * glb + up2(u10.y) * grt;
            floatx2 f2 = up2(u00.z) * glt + up2(u11.z) * grb + up2(u01.z) * glb + up2(u10.z) * grt;
            floatx2 f3 = up2(u00.w) * glt + up2(u11.w) * grb + up2(u01.w) * glb + up2(u10.w) * grt;
            uint4 af4 = make_uint4(pk2bf(f0.x, f0.y), pk2bf(f1.x, f1.y),
                                   pk2bf(f2.x, f2.y), pk2bf(f3.x, f3.y));
            short8 af = *(short8*)&af4;
            d0 = __builtin_amdgcn_mfma_f32_16x16x32_bf16(af, b2f[n], d0, 0, 0, 0);
            d1 = __builtin_amdgcn_mfma_f32_16x16x32_bf16(af, b2f[9 + n], d1, 0, 0, 0);
        }
        // bn2 + store to global padded h2p
#pragma unroll
        for (int r = 0; r < 4; r++) {
            int pout = mt * 16 + q * 4 + r;
            int yo = pout / 28, xo = pout % 28;
            int base = ((yo + 1) * 30 + xo + 1) * 32;
            h2b[base + col]      = f2bf(fmaxf(d0[r], 0.f) * inv0 + sh0);
            h2b[base + 16 + col] = f2bf(fmaxf(d1[r], 0.f) * inv1 + sh1);
        }
    }
}

// ------- conv3 MFMA + relu + global-sum -> pooled[b][64] (1 block/image, 12 waves) -------
__global__ __launch_bounds__(768) void conv3_full(
    const unsigned short* __restrict__ h2p, const unsigned short* __restrict__ w3bf,
    float* __restrict__ pooled)
{
    __shared__ __align__(16) unsigned char img2b[900 * 80];   // all 900 padded px
    __shared__ float part[12][32];
    int t = threadIdx.x, b = blockIdx.x;
    {
        const uint4* src = (const uint4*)(h2p + (size_t)b * 28800);
        for (int i = t; i < 3600; i += 768) {
            int px = i >> 2, j = i & 3;
            *(uint4*)(img2b + sw80(px, j)) = src[i];
        }
    }
    int w = t >> 6, l = t & 63, col = l & 15, q = l >> 4;
    int ocp = w & 1;
    short8 bA[9], bB[9];
#pragma unroll
    for (int n = 0; n < 9; n++) {
        bA[n] = *(const short8*)(w3bf + (ocp * 32 + col) * 288 + n * 32 + q * 8);
        bB[n] = *(const short8*)(w3bf + (ocp * 32 + 16 + col) * 288 + n * 32 + q * 8);
    }
    __syncthreads();

    const unsigned char* ib = img2b;
    float psA = 0.f, psB = 0.f;
    for (int mt = (w >> 1); mt < 49; mt += 6) {
        int p = mt * 16 + col;
        int y = p / 28, xx = p % 28;
        int lp0 = (y + 1) * 30 + (xx + 1);
        floatx4 cA = {0.f, 0.f, 0.f, 0.f}, cB = {0.f, 0.f, 0.f, 0.f};
#pragma unroll
        for (int n = 0; n < 9; n++) {
            int lp = lp0 + (n / 3 - 1) * 30 + (n % 3 - 1);
            short8 a = *(const short8*)(ib + sw80(lp, q));
            cA = __builtin_amdgcn_mfma_f32_16x16x32_bf16(a, bA[n], cA, 0, 0, 0);
            cB = __builtin_amdgcn_mfma_f32_16x16x32_bf16(a, bB[n], cB, 0, 0, 0);
        }
        psA += fmaxf(cA[0], 0.f) + fmaxf(cA[1], 0.f) + fmaxf(cA[2], 0.f) + fmaxf(cA[3], 0.f);
        psB += fmaxf(cB[0], 0.f) + fmaxf(cB[1], 0.f) + fmaxf(cB[2], 0.f) + fmaxf(cB[3], 0.f);
    }
    psA += __shfl_xor(psA, 16, 64); psA += __shfl_xor(psA, 32, 64);
    psB += __shfl_xor(psB, 16, 64); psB += __shfl_xor(psB, 32, 64);
    if (l < 16) { part[w][l] = psA; part[w][16 + l] = psB; }
    __syncthreads();
    if (t < 64) {
        int hi = t >> 5, c = t & 31;
        float s = 0.f;
#pragma unroll
        for (int j = 0; j < 6; j++) s += part[2 * j + hi][c];
        pooled[(size_t)b * 64 + t] = s;     // relu-sum; BN+mean in cls
    }
}

// -------- classifier: bn3, mean, linear 64->10, log_softmax --------
__global__ __launch_bounds__(256) void cls_kernel(
    const float* __restrict__ pooled, const float* __restrict__ c3p,
    const float* __restrict__ wc, const float* __restrict__ bc,
    float* __restrict__ outp)
{
    int b = threadIdx.x;
    float feat[64];
#pragma unroll
    for (int k = 0; k < 64; k++)
        feat[k] = pooled[(size_t)b * 64 + k] * c3p[k] * (1.f / 784.f) + c3p[64 + k];
    float lg[10];
    float mx = -1e30f;
#pragma unroll
    for (int j = 0; j < 10; j++) {
        float s = bc[j];
#pragma unroll
        for (int k = 0; k < 64; k++) s += feat[k] * wc[j * 64 + k];
        lg[j] = s;
        mx = fmaxf(mx, s);
    }
    float se = 0.f;
#pragma unroll
    for (int j = 0; j < 10; j++) se += expf(lg[j] - mx);
    float lse = logf(se);
#pragma unroll
    for (int j = 0; j < 10; j++) outp[b * 10 + j] = lg[j] - mx - lse;
}

extern "C" void kernel_launch(void* const* d_in, const int* in_sizes, int n_in,
                              void* d_out, int out_size, void* d_ws, size_t ws_size,
                              hipStream_t stream)
{
    (void)in_sizes; (void)n_in; (void)out_size; (void)ws_size;
    const float* x  = (const float*)d_in[0];
    const float* w1 = (const float*)d_in[1];
    const float* g1 = (const float*)d_in[2];
    const float* b1 = (const float*)d_in[3];
    const float* m1 = (const float*)d_in[4];
    const float* v1 = (const float*)d_in[5];
    const float* wp = (const float*)d_in[6];
    const float* bp = (const float*)d_in[7];
    const float* w2 = (const float*)d_in[8];
    const float* g2 = (const float*)d_in[9];
    const float* b2 = (const float*)d_in[10];
    const float* m2 = (const float*)d_in[11];
    const float* v2 = (const float*)d_in[12];
    const float* w3 = (const float*)d_in[13];
    const float* g3 = (const float*)d_in[14];
    const float* b3 = (const float*)d_in[15];
    const float* m3 = (const float*)d_in[16];
    const float* v3 = (const float*)d_in[17];
    const float* wc = (const float*)d_in[18];
    const float* bc = (const float*)d_in[19];
    float* outp = (float*)d_out;

    unsigned char* ws = (unsigned char*)d_ws;
    unsigned short* h2p  = (unsigned short*)(ws + H2P_OFF);
    unsigned short* wpbf = (unsigned short*)(ws + WPBF_OFF);
    unsigned short* w2bf = (unsigned short*)(ws + W2BF_OFF);
    unsigned short* w3bf = (unsigned short*)(ws + W3BF_OFF);
    float*          pooled = (float*)(ws + POOL_OFF);
    float*          c1p  = (float*)(ws + C1P_OFF);
    float*          c3p  = (float*)(ws + C3P_OFF);
    unsigned short* w1bf = (unsigned short*)(ws + W1BF_OFF);

    border_zero<<<NB, 128, 0, stream>>>(h2p);
    wcvt<<<149, 256, 0, stream>>>(wp, w2, w3, w1, g1, b1, m1, v1, g3, b3, m3, v3,
                                  wpbf, w2bf, w3bf, w1bf, c1p, c3p);
    fused_front<<<NB, 768, 0, stream>>>(x, w1bf, c1p, wpbf, bp, w2bf,
                                        g2, b2, m2, v2, h2p);
    conv3_full<<<NB, 768, 0, stream>>>(h2p, w3bf, pooled);
    cls_kernel<<<1, 256, 0, stream>>>(pooled, c3p, wc, bc, outp);
}

// Round 7
// 167.391 us; speedup vs baseline: 4.7392x; 1.0432x over previous
//
#include <hip/hip_runtime.h>
#include <hip/hip_bf16.h>
#include <math.h>

typedef __attribute__((ext_vector_type(8))) short short8;   // 8 bf16 = 4 VGPRs (MFMA A/B frag)
typedef __attribute__((ext_vector_type(4))) float floatx4;  // MFMA C/D frag
typedef __attribute__((ext_vector_type(2))) float floatx2;

#define NB  256
#define HWP 784

// ---------------- workspace layout (bytes) ----------------
#define WPBF_OFF  0u           // 32*288 bf16 (rows>=18 zero)
#define W2BF_OFF  18432u       // 32*288 bf16
#define W3BF_OFF  36864u       // 64*288 bf16
#define POOL_OFF  73728u       // 256*64 f32
#define C1P_OFF   139264u      // 64 f32
#define C3P_OFF   139520u      // 128 f32
#define W1BF_OFF  140032u      // 32*32 bf16 ([oc][k=n*3+ic], k>=27 zero)

static __device__ __forceinline__ unsigned short f2bf(float f) {
    unsigned u = __float_as_uint(f);
    u = (u + 0x7fffu + ((u >> 16) & 1u)) >> 16;   // RNE
    return (unsigned short)u;
}

static __device__ __forceinline__ unsigned pk2bf(float a, float b) {
    __hip_bfloat162 h = __float22bfloat162_rn(make_float2(a, b));
    unsigned r;
    __builtin_memcpy(&r, &h, 4);
    return r;
}

static __device__ __forceinline__ floatx2 up2(unsigned u) {
    floatx2 r;
    r.x = __uint_as_float(u << 16);
    r.y = __uint_as_float(u & 0xffff0000u);
    return r;
}

// 80-byte pixel stride in LDS, slot s = 16B channel-group (ch>>3)
static __device__ __forceinline__ int sw80(int px, int s) {
    return px * 80 + s * 16;
}

// ------- weight prep -------
__global__ void wcvt(const float* __restrict__ wp, const float* __restrict__ w2,
                     const float* __restrict__ w3, const float* __restrict__ w1,
                     const float* __restrict__ g1, const float* __restrict__ b1,
                     const float* __restrict__ m1, const float* __restrict__ v1,
                     const float* __restrict__ g3, const float* __restrict__ b3,
                     const float* __restrict__ m3, const float* __restrict__ v3,
                     unsigned short* __restrict__ wpbf, unsigned short* __restrict__ w2bf,
                     unsigned short* __restrict__ w3bf, unsigned short* __restrict__ w1bf,
                     float* __restrict__ c1p, float* __restrict__ c3p)
{
    int t = blockIdx.x * 256 + threadIdx.x;
    if (t < 9216) {
        int oc = t / 288, k = t % 288;
        int n = k >> 5, ic = k & 31;
        wpbf[t] = (oc < 18) ? f2bf(wp[oc * 288 + ic * 9 + n]) : (unsigned short)0;
    } else if (t < 18432) {
        int i = t - 9216;
        int oc = i / 288, k = i % 288;
        int n = k >> 5, ic = k & 31;
        w2bf[i] = f2bf(w2[oc * 288 + ic * 9 + n]);
    } else if (t < 36864) {
        int i = t - 18432;
        int oc = i / 288, k = i % 288;
        int n = k >> 5, ic = k & 31;
        w3bf[i] = f2bf(w3[oc * 288 + ic * 9 + n]);
    } else if (t < 36928) {
        int oc = t - 36864;       // 0..63
        int c = oc & 31;
        float inv = g1[c] * rsqrtf(v1[c] + 1e-5f);
        c1p[oc] = (oc < 32) ? inv : (b1[c] - m1[c] * inv);
    } else if (t < 37056) {
        int i = t - 36928;        // 0..127
        int k = i & 63;
        float inv = g3[k] * rsqrtf(v3[k] + 1e-5f);
        c3p[i] = (i < 64) ? inv : (b3[k] - m3[k] * inv);
    } else if (t < 38080) {
        int i = t - 37056;        // i = oc*32 + k, k = n*3+ic
        int oc = i >> 5, k = i & 31;
        int n = k / 3, ic = k - n * 3;
        w1bf[i] = (k < 27) ? f2bf(w1[oc * 27 + ic * 9 + n]) : (unsigned short)0;
    }
}

// ======= mega-kernel: conv1 -> LDS img1 -> p_conv+bilinear+conv2 -> LDS img2 -> conv3+pool =======
__global__ __launch_bounds__(768) void fused_all(
    const float* __restrict__ x, const unsigned short* __restrict__ w1bf,
    const float* __restrict__ c1p,
    const unsigned short* __restrict__ wpbf, const float* __restrict__ bp,
    const unsigned short* __restrict__ w2bf,
    const float* __restrict__ g2, const float* __restrict__ b2,
    const float* __restrict__ m2, const float* __restrict__ v2,
    const unsigned short* __restrict__ w3bf,
    float* __restrict__ pooled)
{
    __shared__ __align__(16) unsigned char img1[785 * 80];   // h1: 784 interior px + zero slot
    __shared__ __align__(16) unsigned char img2[900 * 80];   // h2: padded 30x30
    __shared__ __align__(16) float scratch[3456];            // x staging, then offtile[12][288]
    int t = threadIdx.x, b = blockIdx.x;
    int w = t >> 6, l = t & 63, col = l & 15, q = l >> 4;
    int g0 = (col >> 3) * 16 + (col & 7) * 2;    // byte offset of channel `col` in 80B pixel

    // stage x (fp32) into scratch
    {
        const float4* xg = (const float4*)(x + (size_t)b * 2352);
        float4* xl = (float4*)scratch;
        for (int i = t; i < 588; i += 768) xl[i] = xg[i];
    }
    if (t == 767) scratch[2352] = 0.f;
    // zero img2 borders (116 px * 5 uint4) and img1 zero-slot (5 uint4)
    if (t < 580) {
        int i = t / 5, s = t - 5 * (t / 5);
        int y, xx;
        if (i < 30)      { y = 0;      xx = i; }
        else if (i < 60) { y = 29;     xx = i - 30; }
        else if (i < 88) { y = i - 59; xx = 0; }
        else             { y = i - 87; xx = 29; }
        *(uint4*)(img2 + sw80(y * 30 + xx, s)) = make_uint4(0u, 0u, 0u, 0u);
    } else if (t < 585) {
        *(uint4*)(img1 + sw80(784, t - 580)) = make_uint4(0u, 0u, 0u, 0u);
    }

    // deform-phase weight frags + constants
    short8 bpf[18], b2f[18];
#pragma unroll
    for (int n = 0; n < 9; n++) {
        bpf[n]     = *(const short8*)(wpbf + col * 288 + n * 32 + q * 8);
        bpf[9 + n] = *(const short8*)(wpbf + (16 + col) * 288 + n * 32 + q * 8);
        b2f[n]     = *(const short8*)(w2bf + col * 288 + n * 32 + q * 8);
        b2f[9 + n] = *(const short8*)(w2bf + (16 + col) * 288 + n * 32 + q * 8);
    }
    float bias0 = bp[col];
    float bias1 = (col < 2) ? bp[16 + col] : 0.f;
    float inv0 = g2[col] * rsqrtf(v2[col] + 1e-5f);
    float sh0 = b2[col] - m2[col] * inv0;
    float inv1 = g2[16 + col] * rsqrtf(v2[16 + col] + 1e-5f);
    float sh1 = b2[16 + col] - m2[16 + col] * inv1;

    __syncthreads();

    // ---- conv1 phase: 3->32 pad1, relu, bn -> img1 (bf16, 80B stride) ----
    {
        short8 bf0 = *(const short8*)(w1bf + col * 32 + q * 8);
        short8 bf1 = *(const short8*)(w1bf + (16 + col) * 32 + q * 8);
        float sc0 = c1p[col],      s0 = c1p[32 + col];
        float sc1 = c1p[16 + col], s1 = c1p[48 + col];
        const float* xs = scratch;
        for (int mt = w; mt < 49; mt += 12) {
            int p = mt * 16 + col;
            int y = p / 28, xx = p % 28;
            unsigned au[4];
#pragma unroll
            for (int jp = 0; jp < 4; jp++) {
                float vv[2];
#pragma unroll
                for (int h = 0; h < 2; h++) {
                    int k = q * 8 + jp * 2 + h;
                    int n = k / 3, ic = k - n * 3;
                    int yy = y + n / 3 - 1, xc = xx + n % 3 - 1;
                    bool ok = (k < 27) && ((unsigned)yy < 28u) && ((unsigned)xc < 28u);
                    int idx = ok ? (ic * 784 + yy * 28 + xc) : 2352;
                    vv[h] = xs[idx];
                }
                au[jp] = pk2bf(vv[0], vv[1]);
            }
            uint4 a4 = make_uint4(au[0], au[1], au[2], au[3]);
            short8 a = *(short8*)&a4;
            floatx4 d0 = {0.f, 0.f, 0.f, 0.f}, d1 = {0.f, 0.f, 0.f, 0.f};
            d0 = __builtin_amdgcn_mfma_f32_16x16x32_bf16(a, bf0, d0, 0, 0, 0);
            d1 = __builtin_amdgcn_mfma_f32_16x16x32_bf16(a, bf1, d1, 0, 0, 0);
#pragma unroll
            for (int r = 0; r < 4; r++) {
                int pout = mt * 16 + q * 4 + r;
                *(unsigned short*)(img1 + pout * 80 + g0) =
                    f2bf(fmaxf(d0[r], 0.f) * sc0 + s0);
                *(unsigned short*)(img1 + pout * 80 + 32 + g0) =
                    f2bf(fmaxf(d1[r], 0.f) * sc1 + s1);
            }
        }
    }
    __syncthreads();

    // ---- deform phase: p_conv MFMA -> offsets -> bilinear -> conv2 MFMA -> bn -> img2 ----
    {
        const unsigned char* ib = img1;
        float* otw = scratch + w * 288;

        for (int mt = w; mt < 49; mt += 12) {
            int p = mt * 16 + col;
            int y = p / 28, xx = p % 28;

            // p_conv for this 16-pixel tile
            floatx4 a0 = {0.f, 0.f, 0.f, 0.f}, a1 = {0.f, 0.f, 0.f, 0.f};
#pragma unroll
            for (int n = 0; n < 9; n++) {
                int yy = y + n / 3 - 1, xc = xx + n % 3 - 1;
                bool ok = ((unsigned)yy < 28u) && ((unsigned)xc < 28u);
                int tp = ok ? (yy * 28 + xc) : 784;      // 784 = zero slot
                short8 a = *(const short8*)(ib + sw80(tp, q));
                a0 = __builtin_amdgcn_mfma_f32_16x16x32_bf16(a, bpf[n], a0, 0, 0, 0);
                a1 = __builtin_amdgcn_mfma_f32_16x16x32_bf16(a, bpf[9 + n], a1, 0, 0, 0);
            }
#pragma unroll
            for (int r = 0; r < 4; r++)
                otw[(q * 4 + r) * 18 + col] = a0[r] + bias0;
            if (col < 2) {
#pragma unroll
                for (int r = 0; r < 4; r++)
                    otw[(q * 4 + r) * 18 + 16 + col] = a1[r] + bias1;
            }
            __asm__ volatile("s_waitcnt lgkmcnt(0)" ::: "memory");

            // bilinear A-frags + conv2 MFMA
            floatx4 d0 = {0.f, 0.f, 0.f, 0.f}, d1 = {0.f, 0.f, 0.f, 0.f};
#pragma unroll
            for (int n = 0; n < 9; n++) {
                float offy = otw[col * 18 + n];
                float offx = otw[col * 18 + 9 + n];
                float py = (float)(y + n / 3) + offy;       // padded coords
                float px = (float)(xx + n % 3) + offx;
                float fy = floorf(py), fx = floorf(px);
                float qy0 = fminf(fmaxf(fy, 0.f), 29.f);
                float qy1 = fminf(fmaxf(fy + 1.f, 0.f), 29.f);
                float qx0 = fminf(fmaxf(fx, 0.f), 29.f);
                float qx1 = fminf(fmaxf(fx + 1.f, 0.f), 29.f);
                float pyc = fminf(fmaxf(py, 0.f), 29.f);
                float pxc = fminf(fmaxf(px, 0.f), 29.f);
                float glt = (1.f + (qy0 - pyc)) * (1.f + (qx0 - pxc));
                float grb = (1.f - (qy1 - pyc)) * (1.f - (qx1 - pxc));
                float glb = (1.f + (qy0 - pyc)) * (1.f - (qx1 - pxc));
                float grt = (1.f - (qy1 - pyc)) * (1.f + (qx0 - pxc));
                int iy0 = (int)qy0, iy1 = (int)qy1, ix0 = (int)qx0, ix1 = (int)qx1;
                int ly0 = iy0 - 1, ly1 = iy1 - 1, lx0 = ix0 - 1, lx1 = ix1 - 1;
                bool v00 = ((unsigned)ly0 < 28u) && ((unsigned)lx0 < 28u);
                bool v11 = ((unsigned)ly1 < 28u) && ((unsigned)lx1 < 28u);
                bool v01 = ((unsigned)ly0 < 28u) && ((unsigned)lx1 < 28u);
                bool v10 = ((unsigned)ly1 < 28u) && ((unsigned)lx0 < 28u);
                int p00 = v00 ? (ly0 * 28 + lx0) : 784;
                int p11 = v11 ? (ly1 * 28 + lx1) : 784;
                int p01 = v01 ? (ly0 * 28 + lx1) : 784;
                int p10 = v10 ? (ly1 * 28 + lx0) : 784;
                uint4 u00 = *(const uint4*)(ib + sw80(p00, q));
                uint4 u11 = *(const uint4*)(ib + sw80(p11, q));
                uint4 u01 = *(const uint4*)(ib + sw80(p01, q));
                uint4 u10 = *(const uint4*)(ib + sw80(p10, q));
                floatx2 f0 = up2(u00.x) * glt + up2(u11.x) * grb + up2(u01.x) * glb + up2(u10.x) * grt;
                floatx2 f1 = up2(u00.y) * glt + up2(u11.y) * grb + up2(u01.y) * glb + up2(u10.y) * grt;
                floatx2 f2 = up2(u00.z) * glt + up2(u11.z) * grb + up2(u01.z) * glb + up2(u10.z) * grt;
                floatx2 f3 = up2(u00.w) * glt + up2(u11.w) * grb + up2(u01.w) * glb + up2(u10.w) * grt;
                uint4 af4 = make_uint4(pk2bf(f0.x, f0.y), pk2bf(f1.x, f1.y),
                                       pk2bf(f2.x, f2.y), pk2bf(f3.x, f3.y));
                short8 af = *(short8*)&af4;
                d0 = __builtin_amdgcn_mfma_f32_16x16x32_bf16(af, b2f[n], d0, 0, 0, 0);
                d1 = __builtin_amdgcn_mfma_f32_16x16x32_bf16(af, b2f[9 + n], d1, 0, 0, 0);
            }
            // bn2 + store to LDS img2 (padded layout)
#pragma unroll
            for (int r = 0; r < 4; r++) {
                int pout = mt * 16 + q * 4 + r;
                int yo = pout / 28, xo = pout % 28;
                int ppad = (yo + 1) * 30 + xo + 1;
                *(unsigned short*)(img2 + ppad * 80 + g0) =
                    f2bf(fmaxf(d0[r], 0.f) * inv0 + sh0);
                *(unsigned short*)(img2 + ppad * 80 + 32 + g0) =
                    f2bf(fmaxf(d1[r], 0.f) * inv1 + sh1);
            }
        }
    }
    __syncthreads();

    // ---- conv3 phase: MFMA + relu + global-sum -> pooled[b][64] ----
    {
        __shared__ float part[12][32];
        int ocp = w & 1;
        short8 bA[9], bB[9];
#pragma unroll
        for (int n = 0; n < 9; n++) {
            bA[n] = *(const short8*)(w3bf + (ocp * 32 + col) * 288 + n * 32 + q * 8);
            bB[n] = *(const short8*)(w3bf + (ocp * 32 + 16 + col) * 288 + n * 32 + q * 8);
        }
        const unsigned char* ib = img2;
        float psA = 0.f, psB = 0.f;
        for (int mt = (w >> 1); mt < 49; mt += 6) {
            int p = mt * 16 + col;
            int y = p / 28, xx = p % 28;
            int lp0 = (y + 1) * 30 + (xx + 1);
            floatx4 cA = {0.f, 0.f, 0.f, 0.f}, cB = {0.f, 0.f, 0.f, 0.f};
#pragma unroll
            for (int n = 0; n < 9; n++) {
                int lp = lp0 + (n / 3 - 1) * 30 + (n % 3 - 1);
                short8 a = *(const short8*)(ib + sw80(lp, q));
                cA = __builtin_amdgcn_mfma_f32_16x16x32_bf16(a, bA[n], cA, 0, 0, 0);
                cB = __builtin_amdgcn_mfma_f32_16x16x32_bf16(a, bB[n], cB, 0, 0, 0);
            }
            psA += fmaxf(cA[0], 0.f) + fmaxf(cA[1], 0.f) + fmaxf(cA[2], 0.f) + fmaxf(cA[3], 0.f);
            psB += fmaxf(cB[0], 0.f) + fmaxf(cB[1], 0.f) + fmaxf(cB[2], 0.f) + fmaxf(cB[3], 0.f);
        }
        psA += __shfl_xor(psA, 16, 64); psA += __shfl_xor(psA, 32, 64);
        psB += __shfl_xor(psB, 16, 64); psB += __shfl_xor(psB, 32, 64);
        if (l < 16) { part[w][l] = psA; part[w][16 + l] = psB; }
        __syncthreads();
        if (t < 64) {
            int hi = t >> 5, c = t & 31;
            float s = 0.f;
#pragma unroll
            for (int j = 0; j < 6; j++) s += part[2 * j + hi][c];
            pooled[(size_t)b * 64 + t] = s;     // relu-sum; BN+mean in cls
        }
    }
}

// -------- classifier: bn3, mean, linear 64->10, log_softmax --------
__global__ __launch_bounds__(256) void cls_kernel(
    const float* __restrict__ pooled, const float* __restrict__ c3p,
    const float* __restrict__ wc, const float* __restrict__ bc,
    float* __restrict__ outp)
{
    int b = threadIdx.x;
    float feat[64];
#pragma unroll
    for (int k = 0; k < 64; k++)
        feat[k] = pooled[(size_t)b * 64 + k] * c3p[k] * (1.f / 784.f) + c3p[64 + k];
    float lg[10];
    float mx = -1e30f;
#pragma unroll
    for (int j = 0; j < 10; j++) {
        float s = bc[j];
#pragma unroll
        for (int k = 0; k < 64; k++) s += feat[k] * wc[j * 64 + k];
        lg[j] = s;
        mx = fmaxf(mx, s);
    }
    float se = 0.f;
#pragma unroll
    for (int j = 0; j < 10; j++) se += expf(lg[j] - mx);
    float lse = logf(se);
#pragma unroll
    for (int j = 0; j < 10; j++) outp[b * 10 + j] = lg[j] - mx - lse;
}

extern "C" void kernel_launch(void* const* d_in, const int* in_sizes, int n_in,
                              void* d_out, int out_size, void* d_ws, size_t ws_size,
                              hipStream_t stream)
{
    (void)in_sizes; (void)n_in; (void)out_size; (void)ws_size;
    const float* x  = (const float*)d_in[0];
    const float* w1 = (const float*)d_in[1];
    const float* g1 = (const float*)d_in[2];
    const float* b1 = (const float*)d_in[3];
    const float* m1 = (const float*)d_in[4];
    const float* v1 = (const float*)d_in[5];
    const float* wp = (const float*)d_in[6];
    const float* bp = (const float*)d_in[7];
    const float* w2 = (const float*)d_in[8];
    const float* g2 = (const float*)d_in[9];
    const float* b2 = (const float*)d_in[10];
    const float* m2 = (const float*)d_in[11];
    const float* v2 = (const float*)d_in[12];
    const float* w3 = (const float*)d_in[13];
    const float* g3 = (const float*)d_in[14];
    const float* b3 = (const float*)d_in[15];
    const float* m3 = (const float*)d_in[16];
    const float* v3 = (const float*)d_in[17];
    const float* wc = (const float*)d_in[18];
    const float* bc = (const float*)d_in[19];
    float* outp = (float*)d_out;

    unsigned char* ws = (unsigned char*)d_ws;
    unsigned short* wpbf = (unsigned short*)(ws + WPBF_OFF);
    unsigned short* w2bf = (unsigned short*)(ws + W2BF_OFF);
    unsigned short* w3bf = (unsigned short*)(ws + W3BF_OFF);
    float*          pooled = (float*)(ws + POOL_OFF);
    float*          c1p  = (float*)(ws + C1P_OFF);
    float*          c3p  = (float*)(ws + C3P_OFF);
    unsigned short* w1bf = (unsigned short*)(ws + W1BF_OFF);

    wcvt<<<149, 256, 0, stream>>>(wp, w2, w3, w1, g1, b1, m1, v1, g3, b3, m3, v3,
                                  wpbf, w2bf, w3bf, w1bf, c1p, c3p);
    fused_all<<<NB, 768, 0, stream>>>(x, w1bf, c1p, wpbf, bp, w2bf,
                                      g2, b2, m2, v2, w3bf, pooled);
    cls_kernel<<<1, 256, 0, stream>>>(pooled, c3p, wc, bc, outp);
}

// Round 8
// 146.308 us; speedup vs baseline: 5.4221x; 1.1441x over previous
//
#include <hip/hip_runtime.h>
#include <hip/hip_bf16.h>
#include <math.h>

typedef __attribute__((ext_vector_type(8))) short short8;   // 8 bf16 = 4 VGPRs (MFMA A/B frag)
typedef __attribute__((ext_vector_type(4))) float floatx4;  // MFMA C/D frag
typedef __attribute__((ext_vector_type(2))) float floatx2;

#define NB  256

// ---------------- workspace layout (bytes) ----------------
#define WPBF_OFF  0u           // 32*288 bf16 (rows>=18 zero)
#define W2BF_OFF  18432u       // 32*288 bf16
#define W3BF_OFF  36864u       // 64*288 bf16
#define POOL_OFF  73728u       // 256*64 f32
#define C1P_OFF   139264u      // 64 f32
#define C3P_OFF   139520u      // 128 f32
#define W1BF_OFF  140032u      // 32*32 bf16 ([oc][k=n*3+ic], k>=27 zero)

// ---------------- LDS layout inside fused_all (bytes) ----------------
#define L_IMG1  0            // 785*64 = 50240  (h1: 784 px + zero slot)
#define L_U     50240        // 785*64 = 50240  (x staging, then h2 interior + zero slot)
#define L_OFFT  100480       // 12*288*4 = 13824 (offsets; later part[12][32])
#define L_WL    114304       // 64 rows * 592 = 37888 (wp rows then w3 rows, padded stride)
#define L_TOT   152192

static __device__ __forceinline__ unsigned short f2bf(float f) {
    unsigned u = __float_as_uint(f);
    u = (u + 0x7fffu + ((u >> 16) & 1u)) >> 16;   // RNE
    return (unsigned short)u;
}

static __device__ __forceinline__ unsigned pk2bf(float a, float b) {
    __hip_bfloat162 h = __float22bfloat162_rn(make_float2(a, b));
    unsigned r;
    __builtin_memcpy(&r, &h, 4);
    return r;
}

static __device__ __forceinline__ floatx2 up2(unsigned u) {
    floatx2 r;
    r.x = __uint_as_float(u << 16);
    r.y = __uint_as_float(u & 0xffff0000u);
    return r;
}

// ------- weight prep -------
__global__ void wcvt(const float* __restrict__ wp, const float* __restrict__ w2,
                     const float* __restrict__ w3, const float* __restrict__ w1,
                     const float* __restrict__ g1, const float* __restrict__ b1,
                     const float* __restrict__ m1, const float* __restrict__ v1,
                     const float* __restrict__ g3, const float* __restrict__ b3,
                     const float* __restrict__ m3, const float* __restrict__ v3,
                     unsigned short* __restrict__ wpbf, unsigned short* __restrict__ w2bf,
                     unsigned short* __restrict__ w3bf, unsigned short* __restrict__ w1bf,
                     float* __restrict__ c1p, float* __restrict__ c3p)
{
    int t = blockIdx.x * 256 + threadIdx.x;
    if (t < 9216) {
        int oc = t / 288, k = t % 288;
        int n = k >> 5, ic = k & 31;
        wpbf[t] = (oc < 18) ? f2bf(wp[oc * 288 + ic * 9 + n]) : (unsigned short)0;
    } else if (t < 18432) {
        int i = t - 9216;
        int oc = i / 288, k = i % 288;
        int n = k >> 5, ic = k & 31;
        w2bf[i] = f2bf(w2[oc * 288 + ic * 9 + n]);
    } else if (t < 36864) {
        int i = t - 18432;
        int oc = i / 288, k = i % 288;
        int n = k >> 5, ic = k & 31;
        w3bf[i] = f2bf(w3[oc * 288 + ic * 9 + n]);
    } else if (t < 36928) {
        int oc = t - 36864;       // 0..63
        int c = oc & 31;
        float inv = g1[c] * rsqrtf(v1[c] + 1e-5f);
        c1p[oc] = (oc < 32) ? inv : (b1[c] - m1[c] * inv);
    } else if (t < 37056) {
        int i = t - 36928;        // 0..127
        int k = i & 63;
        float inv = g3[k] * rsqrtf(v3[k] + 1e-5f);
        c3p[i] = (i < 64) ? inv : (b3[k] - m3[k] * inv);
    } else if (t < 38080) {
        int i = t - 37056;        // i = oc*32 + k, k = n*3+ic
        int oc = i >> 5, k = i & 31;
        int n = k / 3, ic = k - n * 3;
        w1bf[i] = (k < 27) ? f2bf(w1[oc * 27 + ic * 9 + n]) : (unsigned short)0;
    }
}

// ======= mega-kernel: conv1 -> LDS img1 -> p_conv+bilinear+conv2 -> LDS img2 -> conv3+pool =======
__global__ __launch_bounds__(768, 3) void fused_all(
    const float* __restrict__ x, const unsigned short* __restrict__ w1bf,
    const float* __restrict__ c1p,
    const unsigned short* __restrict__ wpbf, const float* __restrict__ bp,
    const unsigned short* __restrict__ w2bf,
    const float* __restrict__ g2, const float* __restrict__ b2,
    const float* __restrict__ m2, const float* __restrict__ v2,
    const unsigned short* __restrict__ w3bf,
    float* __restrict__ pooled)
{
    __shared__ __align__(16) unsigned char ALL[L_TOT];
    int t = threadIdx.x, b = blockIdx.x;
    int w = t >> 6, l = t & 63, col = l & 15, q = l >> 4;

    unsigned char* img1 = ALL + L_IMG1;
    unsigned char* uimg = ALL + L_U;          // x staging then h2
    float* xs = (float*)uimg;

    // stage x (fp32) into U region
    {
        const float4* xg = (const float4*)(x + (size_t)b * 2352);
        float4* xl = (float4*)uimg;
        for (int i = t; i < 588; i += 768) xl[i] = xg[i];
    }
    // wp weights -> LDS pool (rows 0..31, padded stride 592 B)
    {
        const uint4* src = (const uint4*)wpbf;
        for (int i = t; i < 1152; i += 768) {
            int row = i / 36, g = i - row * 36;
            *(uint4*)(ALL + L_WL + row * 592 + g * 16) = src[i];
        }
    }
    if (t == 700) xs[2352] = 0.f;                           // conv1 zero slot
    if (t < 4)  *(uint4*)(img1 + 784 * 64 + t * 16) = make_uint4(0u, 0u, 0u, 0u);
    if (t >= 4 && t < 8) *(uint4*)(uimg + 784 * 64 + (t - 4) * 16) = make_uint4(0u, 0u, 0u, 0u);

    // conv2 B-frags stay in VGPRs (innermost chain)
    short8 b2f[18];
#pragma unroll
    for (int n = 0; n < 9; n++) {
        b2f[n]     = *(const short8*)(w2bf + col * 288 + n * 32 + q * 8);
        b2f[9 + n] = *(const short8*)(w2bf + (16 + col) * 288 + n * 32 + q * 8);
    }
    float bias0 = bp[col];
    float bias1 = (col < 2) ? bp[16 + col] : 0.f;
    float inv0 = g2[col] * rsqrtf(v2[col] + 1e-5f);
    float sh0 = b2[col] - m2[col] * inv0;
    float inv1 = g2[16 + col] * rsqrtf(v2[16 + col] + 1e-5f);
    float sh1 = b2[16 + col] - m2[16 + col] * inv1;

    __syncthreads();

    // ---- conv1 phase: 3->32 pad1, relu, bn -> img1 (bf16, 64B/px) ----
    {
        short8 bf0 = *(const short8*)(w1bf + col * 32 + q * 8);
        short8 bf1 = *(const short8*)(w1bf + (16 + col) * 32 + q * 8);
        float sc0 = c1p[col],      s0 = c1p[32 + col];
        float sc1 = c1p[16 + col], s1 = c1p[48 + col];
        for (int mt = w; mt < 49; mt += 12) {
            int p = mt * 16 + col;
            int y = p / 28, xx = p % 28;
            unsigned au[4];
#pragma unroll
            for (int jp = 0; jp < 4; jp++) {
                float vv[2];
#pragma unroll
                for (int h = 0; h < 2; h++) {
                    int k = q * 8 + jp * 2 + h;
                    int n = k / 3, ic = k - n * 3;
                    int yy = y + n / 3 - 1, xc = xx + n % 3 - 1;
                    bool ok = (k < 27) && ((unsigned)yy < 28u) && ((unsigned)xc < 28u);
                    int idx = ok ? (ic * 784 + yy * 28 + xc) : 2352;
                    vv[h] = xs[idx];
                }
                au[jp] = pk2bf(vv[0], vv[1]);
            }
            uint4 a4 = make_uint4(au[0], au[1], au[2], au[3]);
            short8 a = *(short8*)&a4;
            floatx4 d0 = {0.f, 0.f, 0.f, 0.f}, d1 = {0.f, 0.f, 0.f, 0.f};
            d0 = __builtin_amdgcn_mfma_f32_16x16x32_bf16(a, bf0, d0, 0, 0, 0);
            d1 = __builtin_amdgcn_mfma_f32_16x16x32_bf16(a, bf1, d1, 0, 0, 0);
#pragma unroll
            for (int r = 0; r < 4; r++) {
                int pout = mt * 16 + q * 4 + r;
                *(unsigned short*)(img1 + pout * 64 + col * 2) =
                    f2bf(fmaxf(d0[r], 0.f) * sc0 + s0);
                *(unsigned short*)(img1 + pout * 64 + 32 + col * 2) =
                    f2bf(fmaxf(d1[r], 0.f) * sc1 + s1);
            }
        }
    }
    __syncthreads();

    // ---- deform phase: p_conv MFMA (B from LDS pool) -> offsets -> bilinear -> conv2 MFMA -> img2 ----
    {
        const unsigned char* ib = img1;
        float* otw = (float*)(ALL + L_OFFT) + w * 288;

        for (int mt = w; mt < 49; mt += 12) {
            int p = mt * 16 + col;
            int y = p / 28, xx = p % 28;

            // p_conv for this 16-pixel tile
            floatx4 a0 = {0.f, 0.f, 0.f, 0.f}, a1 = {0.f, 0.f, 0.f, 0.f};
#pragma unroll
            for (int n = 0; n < 9; n++) {
                int yy = y + n / 3 - 1, xc = xx + n % 3 - 1;
                bool ok = ((unsigned)yy < 28u) && ((unsigned)xc < 28u);
                int tp = ok ? (yy * 28 + xc) : 784;      // 784 = zero slot
                short8 a  = *(const short8*)(ib + tp * 64 + q * 16);
                short8 p0 = *(const short8*)(ALL + L_WL + col * 592 + n * 64 + q * 16);
                short8 p1 = *(const short8*)(ALL + L_WL + (16 + col) * 592 + n * 64 + q * 16);
                a0 = __builtin_amdgcn_mfma_f32_16x16x32_bf16(a, p0, a0, 0, 0, 0);
                a1 = __builtin_amdgcn_mfma_f32_16x16x32_bf16(a, p1, a1, 0, 0, 0);
            }
#pragma unroll
            for (int r = 0; r < 4; r++)
                otw[(q * 4 + r) * 18 + col] = a0[r] + bias0;
            if (col < 2) {
#pragma unroll
                for (int r = 0; r < 4; r++)
                    otw[(q * 4 + r) * 18 + 16 + col] = a1[r] + bias1;
            }
            __asm__ volatile("s_waitcnt lgkmcnt(0)" ::: "memory");

            // bilinear A-frags + conv2 MFMA
            floatx4 d0 = {0.f, 0.f, 0.f, 0.f}, d1 = {0.f, 0.f, 0.f, 0.f};
#pragma unroll
            for (int n = 0; n < 9; n++) {
                float offy = otw[col * 18 + n];
                float offx = otw[col * 18 + 9 + n];
                float py = (float)(y + n / 3) + offy;       // padded coords
                float px = (float)(xx + n % 3) + offx;
                float fy = floorf(py), fx = floorf(px);
                float qy0 = fminf(fmaxf(fy, 0.f), 29.f);
                float qy1 = fminf(fmaxf(fy + 1.f, 0.f), 29.f);
                float qx0 = fminf(fmaxf(fx, 0.f), 29.f);
                float qx1 = fminf(fmaxf(fx + 1.f, 0.f), 29.f);
                float pyc = fminf(fmaxf(py, 0.f), 29.f);
                float pxc = fminf(fmaxf(px, 0.f), 29.f);
                float glt = (1.f + (qy0 - pyc)) * (1.f + (qx0 - pxc));
                float grb = (1.f - (qy1 - pyc)) * (1.f - (qx1 - pxc));
                float glb = (1.f + (qy0 - pyc)) * (1.f - (qx1 - pxc));
                float grt = (1.f - (qy1 - pyc)) * (1.f + (qx0 - pxc));
                int iy0 = (int)qy0, iy1 = (int)qy1, ix0 = (int)qx0, ix1 = (int)qx1;
                int ly0 = iy0 - 1, ly1 = iy1 - 1, lx0 = ix0 - 1, lx1 = ix1 - 1;
                bool v00 = ((unsigned)ly0 < 28u) && ((unsigned)lx0 < 28u);
                bool v11 = ((unsigned)ly1 < 28u) && ((unsigned)lx1 < 28u);
                bool v01 = ((unsigned)ly0 < 28u) && ((unsigned)lx1 < 28u);
                bool v10 = ((unsigned)ly1 < 28u) && ((unsigned)lx0 < 28u);
                int p00 = v00 ? (ly0 * 28 + lx0) : 784;
                int p11 = v11 ? (ly1 * 28 + lx1) : 784;
                int p01 = v01 ? (ly0 * 28 + lx1) : 784;
                int p10 = v10 ? (ly1 * 28 + lx0) : 784;
                uint4 u00 = *(const uint4*)(ib + p00 * 64 + q * 16);
                uint4 u11 = *(const uint4*)(ib + p11 * 64 + q * 16);
                uint4 u01 = *(const uint4*)(ib + p01 * 64 + q * 16);
                uint4 u10 = *(const uint4*)(ib + p10 * 64 + q * 16);
                floatx2 f0 = up2(u00.x) * glt + up2(u11.x) * grb + up2(u01.x) * glb + up2(u10.x) * grt;
                floatx2 f1 = up2(u00.y) * glt + up2(u11.y) * grb + up2(u01.y) * glb + up2(u10.y) * grt;
                floatx2 f2 = up2(u00.z) * glt + up2(u11.z) * grb + up2(u01.z) * glb + up2(u10.z) * grt;
                floatx2 f3 = up2(u00.w) * glt + up2(u11.w) * grb + up2(u01.w) * glb + up2(u10.w) * grt;
                uint4 af4 = make_uint4(pk2bf(f0.x, f0.y), pk2bf(f1.x, f1.y),
                                       pk2bf(f2.x, f2.y), pk2bf(f3.x, f3.y));
                short8 af = *(short8*)&af4;
                d0 = __builtin_amdgcn_mfma_f32_16x16x32_bf16(af, b2f[n], d0, 0, 0, 0);
                d1 = __builtin_amdgcn_mfma_f32_16x16x32_bf16(af, b2f[9 + n], d1, 0, 0, 0);
            }
            // bn2 + store to LDS img2 (interior layout, 64B/px)
#pragma unroll
            for (int r = 0; r < 4; r++) {
                int pout = mt * 16 + q * 4 + r;
                *(unsigned short*)(uimg + pout * 64 + col * 2) =
                    f2bf(fmaxf(d0[r], 0.f) * inv0 + sh0);
                *(unsigned short*)(uimg + pout * 64 + 32 + col * 2) =
                    f2bf(fmaxf(d1[r], 0.f) * inv1 + sh1);
            }
        }
    }
    __syncthreads();

    // load w3 into the LDS weight pool (overwrites wp rows)
    {
        const uint4* src = (const uint4*)w3bf;
        for (int i = t; i < 2304; i += 768) {
            int row = i / 36, g = i - row * 36;
            *(uint4*)(ALL + L_WL + row * 592 + g * 16) = src[i];
        }
    }
    __syncthreads();

    // ---- conv3 phase: MFMA (B from LDS pool) + relu + global-sum -> pooled[b][64] ----
    {
        float* part = (float*)(ALL + L_OFFT);   // [12][32], overlaps dead offtile
        int ocp = w & 1;
        const unsigned char* ib = uimg;
        float psA = 0.f, psB = 0.f;
        for (int mt = (w >> 1); mt < 49; mt += 6) {
            int p = mt * 16 + col;
            int y = p / 28, xx = p % 28;
            floatx4 cA = {0.f, 0.f, 0.f, 0.f}, cB = {0.f, 0.f, 0.f, 0.f};
#pragma unroll
            for (int n = 0; n < 9; n++) {
                int yy = y + n / 3 - 1, xc = xx + n % 3 - 1;
                bool ok = ((unsigned)yy < 28u) && ((unsigned)xc < 28u);
                int tp = ok ? (yy * 28 + xc) : 784;
                short8 a  = *(const short8*)(ib + tp * 64 + q * 16);
                short8 wA = *(const short8*)(ALL + L_WL + (ocp * 32 + col) * 592 + n * 64 + q * 16);
                short8 wB = *(const short8*)(ALL + L_WL + (ocp * 32 + 16 + col) * 592 + n * 64 + q * 16);
                cA = __builtin_amdgcn_mfma_f32_16x16x32_bf16(a, wA, cA, 0, 0, 0);
                cB = __builtin_amdgcn_mfma_f32_16x16x32_bf16(a, wB, cB, 0, 0, 0);
            }
            psA += fmaxf(cA[0], 0.f) + fmaxf(cA[1], 0.f) + fmaxf(cA[2], 0.f) + fmaxf(cA[3], 0.f);
            psB += fmaxf(cB[0], 0.f) + fmaxf(cB[1], 0.f) + fmaxf(cB[2], 0.f) + fmaxf(cB[3], 0.f);
        }
        psA += __shfl_xor(psA, 16, 64); psA += __shfl_xor(psA, 32, 64);
        psB += __shfl_xor(psB, 16, 64); psB += __shfl_xor(psB, 32, 64);
        if (l < 16) { part[w * 32 + l] = psA; part[w * 32 + 16 + l] = psB; }
        __syncthreads();
        if (t < 64) {
            int hi = t >> 5, c = t & 31;
            float s = 0.f;
#pragma unroll
            for (int j = 0; j < 6; j++) s += part[(2 * j + hi) * 32 + c];
            pooled[(size_t)b * 64 + t] = s;     // relu-sum; BN+mean in cls
        }
    }
}

// -------- classifier: bn3, mean, linear 64->10, log_softmax --------
__global__ __launch_bounds__(64) void cls_kernel(
    const float* __restrict__ pooled, const float* __restrict__ c3p,
    const float* __restrict__ wc, const float* __restrict__ bc,
    float* __restrict__ outp)
{
    int b = blockIdx.x * 64 + threadIdx.x;
    float feat[64];
#pragma unroll
    for (int k = 0; k < 64; k++)
        feat[k] = pooled[(size_t)b * 64 + k] * c3p[k] * (1.f / 784.f) + c3p[64 + k];
    float lg[10];
    float mx = -1e30f;
#pragma unroll
    for (int j = 0; j < 10; j++) {
        float s = bc[j];
#pragma unroll
        for (int k = 0; k < 64; k++) s += feat[k] * wc[j * 64 + k];
        lg[j] = s;
        mx = fmaxf(mx, s);
    }
    float se = 0.f;
#pragma unroll
    for (int j = 0; j < 10; j++) se += expf(lg[j] - mx);
    float lse = logf(se);
#pragma unroll
    for (int j = 0; j < 10; j++) outp[b * 10 + j] = lg[j] - mx - lse;
}

extern "C" void kernel_launch(void* const* d_in, const int* in_sizes, int n_in,
                              void* d_out, int out_size, void* d_ws, size_t ws_size,
                              hipStream_t stream)
{
    (void)in_sizes; (void)n_in; (void)out_size; (void)ws_size;
    const float* x  = (const float*)d_in[0];
    const float* w1 = (const float*)d_in[1];
    const float* g1 = (const float*)d_in[2];
    const float* b1 = (const float*)d_in[3];
    const float* m1 = (const float*)d_in[4];
    const float* v1 = (const float*)d_in[5];
    const float* wp = (const float*)d_in[6];
    const float* bp = (const float*)d_in[7];
    const float* w2 = (const float*)d_in[8];
    const float* g2 = (const float*)d_in[9];
    const float* b2 = (const float*)d_in[10];
    const float* m2 = (const float*)d_in[11];
    const float* v2 = (const float*)d_in[12];
    const float* w3 = (const float*)d_in[13];
    const float* g3 = (const float*)d_in[14];
    const float* b3 = (const float*)d_in[15];
    const float* m3 = (const float*)d_in[16];
    const float* v3 = (const float*)d_in[17];
    const float* wc = (const float*)d_in[18];
    const float* bc = (const float*)d_in[19];
    float* outp = (float*)d_out;

    unsigned char* ws = (unsigned char*)d_ws;
    unsigned short* wpbf = (unsigned short*)(ws + WPBF_OFF);
    unsigned short* w2bf = (unsigned short*)(ws + W2BF_OFF);
    unsigned short* w3bf = (unsigned short*)(ws + W3BF_OFF);
    float*          pooled = (float*)(ws + POOL_OFF);
    float*          c1p  = (float*)(ws + C1P_OFF);
    float*          c3p  = (float*)(ws + C3P_OFF);
    unsigned short* w1bf = (unsigned short*)(ws + W1BF_OFF);

    wcvt<<<149, 256, 0, stream>>>(wp, w2, w3, w1, g1, b1, m1, v1, g3, b3, m3, v3,
                                  wpbf, w2bf, w3bf, w1bf, c1p, c3p);
    fused_all<<<NB, 768, 0, stream>>>(x, w1bf, c1p, wpbf, bp, w2bf,
                                      g2, b2, m2, v2, w3bf, pooled);
    cls_kernel<<<4, 64, 0, stream>>>(pooled, c3p, wc, bc, outp);
}

// Round 9
// 143.753 us; speedup vs baseline: 5.5184x; 1.0178x over previous
//
#include <hip/hip_runtime.h>
#include <hip/hip_bf16.h>
#include <math.h>

typedef __attribute__((ext_vector_type(8))) short short8;   // 8 bf16 = 4 VGPRs (MFMA A/B frag)
typedef __attribute__((ext_vector_type(4))) float floatx4;  // MFMA C/D frag
typedef __attribute__((ext_vector_type(2))) float floatx2;

#define NB 256

// ---------------- LDS layout (bytes) ----------------
#define L_IMG1 0            // 785*64 = 50240  (h1: 784 px + zero slot)
#define L_U    50240        // 785*64 = 50240  (x staging, then h2 interior + zero slot)
#define L_OFFT 100480       // 13824: w1 stash (2KB), then per-wave offsets, then part[12][32]
#define L_WL   114304       // 64 rows * 592 B (wp+w2 rows, later w3 rows)
#define L_TOT  152192

static __device__ __forceinline__ unsigned short f2bf(float f) {
    unsigned u = __float_as_uint(f);
    u = (u + 0x7fffu + ((u >> 16) & 1u)) >> 16;   // RNE
    return (unsigned short)u;
}

static __device__ __forceinline__ unsigned pk2bf(float a, float b) {
    __hip_bfloat162 h = __float22bfloat162_rn(make_float2(a, b));
    unsigned r;
    __builtin_memcpy(&r, &h, 4);
    return r;
}

static __device__ __forceinline__ floatx2 up2(unsigned u) {
    floatx2 r;
    r.x = __uint_as_float(u << 16);
    r.y = __uint_as_float(u & 0xffff0000u);
    return r;
}

// ======= single mega-kernel: weights-cvt -> conv1 -> deform(conv2) -> conv3+pool -> cls =======
__global__ __launch_bounds__(768, 3) void meganet(
    const float* __restrict__ x,  const float* __restrict__ w1,
    const float* __restrict__ g1, const float* __restrict__ b1,
    const float* __restrict__ m1, const float* __restrict__ v1,
    const float* __restrict__ wp, const float* __restrict__ bp,
    const float* __restrict__ w2,
    const float* __restrict__ g2, const float* __restrict__ b2,
    const float* __restrict__ m2, const float* __restrict__ v2,
    const float* __restrict__ w3,
    const float* __restrict__ g3, const float* __restrict__ b3,
    const float* __restrict__ m3, const float* __restrict__ v3,
    const float* __restrict__ wc, const float* __restrict__ bc,
    float* __restrict__ outp)
{
    __shared__ __align__(16) unsigned char ALL[L_TOT];
    int t = threadIdx.x, b = blockIdx.x;
    int w = t >> 6, l = t & 63, col = l & 15, q = l >> 4;

    unsigned char* img1 = ALL + L_IMG1;
    unsigned char* uimg = ALL + L_U;          // x staging then h2

    // ---- phase 0: stage x, convert weights into LDS, per-lane BN consts ----
    {
        const float4* xg = (const float4*)(x + (size_t)b * 2352);
        float4* xl = (float4*)uimg;
        for (int i = t; i < 588; i += 768) xl[i] = xg[i];
    }
    for (int i = t; i < 9216; i += 768) {      // wp -> pool rows 0..31 (>=18 zero), w2 -> rows 32..63
        int row = i / 288, k = i - row * 288;
        int src = row * 288 + (k & 31) * 9 + (k >> 5);
        float vp = (row < 18) ? wp[src] : 0.f;
        *(unsigned short*)(ALL + L_WL + row * 592 + k * 2) = f2bf(vp);
        *(unsigned short*)(ALL + L_WL + (32 + row) * 592 + k * 2) = f2bf(w2[src]);
    }
    for (int i = t; i < 1024; i += 768) {      // w1 -> stash at L_OFFT ([oc][k=n*3+ic], k>=27 zero)
        int oc = i >> 5, k = i & 31;
        int n = k / 3, ic = k - n * 3;
        float v = (k < 27) ? w1[oc * 27 + ic * 9 + n] : 0.f;
        *(unsigned short*)(ALL + L_OFFT + i * 2) = f2bf(v);
    }
    if (t == 700) ((float*)uimg)[2352] = 0.f;                       // conv1 zero slot
    if (t < 4)  *(uint4*)(img1 + 784 * 64 + t * 16) = make_uint4(0u, 0u, 0u, 0u);
    if (t >= 4 && t < 8) *(uint4*)(uimg + 784 * 64 + (t - 4) * 16) = make_uint4(0u, 0u, 0u, 0u);

    // per-lane constants (global scalar loads)
    float i1a = g1[col] * rsqrtf(v1[col] + 1e-5f);
    float sc0 = i1a, s0 = b1[col] - m1[col] * i1a;
    float i1b = g1[16 + col] * rsqrtf(v1[16 + col] + 1e-5f);
    float sc1 = i1b, s1 = b1[16 + col] - m1[16 + col] * i1b;
    float bias0 = bp[col];
    float bias1 = (col < 2) ? bp[16 + col] : 0.f;
    float inv0 = g2[col] * rsqrtf(v2[col] + 1e-5f);
    float sh0 = b2[col] - m2[col] * inv0;
    float inv1 = g2[16 + col] * rsqrtf(v2[16 + col] + 1e-5f);
    float sh1 = b2[16 + col] - m2[16 + col] * inv1;

    __syncthreads();

    // ---- phase 1: conv1 (3->32, pad1, relu, bn) -> img1 ----
    {
        short8 bf0 = *(const short8*)(ALL + L_OFFT + col * 64 + q * 16);
        short8 bf1 = *(const short8*)(ALL + L_OFFT + (16 + col) * 64 + q * 16);
        const float* xs = (const float*)uimg;
        for (int mt = w; mt < 49; mt += 12) {
            int p = mt * 16 + col;
            int y = p / 28, xx = p % 28;
            unsigned au[4];
#pragma unroll
            for (int jp = 0; jp < 4; jp++) {
                float vv[2];
#pragma unroll
                for (int h = 0; h < 2; h++) {
                    int k = q * 8 + jp * 2 + h;
                    int n = k / 3, ic = k - n * 3;
                    int yy = y + n / 3 - 1, xc = xx + n % 3 - 1;
                    bool ok = (k < 27) && ((unsigned)yy < 28u) && ((unsigned)xc < 28u);
                    int idx = ok ? (ic * 784 + yy * 28 + xc) : 2352;
                    vv[h] = xs[idx];
                }
                au[jp] = pk2bf(vv[0], vv[1]);
            }
            uint4 a4 = make_uint4(au[0], au[1], au[2], au[3]);
            short8 a = *(short8*)&a4;
            floatx4 d0 = {0.f, 0.f, 0.f, 0.f}, d1 = {0.f, 0.f, 0.f, 0.f};
            d0 = __builtin_amdgcn_mfma_f32_16x16x32_bf16(a, bf0, d0, 0, 0, 0);
            d1 = __builtin_amdgcn_mfma_f32_16x16x32_bf16(a, bf1, d1, 0, 0, 0);
#pragma unroll
            for (int r = 0; r < 4; r++) {
                int pout = mt * 16 + q * 4 + r;
                *(unsigned short*)(img1 + pout * 64 + col * 2) =
                    f2bf(fmaxf(d0[r], 0.f) * sc0 + s0);
                *(unsigned short*)(img1 + pout * 64 + 32 + col * 2) =
                    f2bf(fmaxf(d1[r], 0.f) * sc1 + s1);
            }
        }
    }
    __syncthreads();

    // ---- phase 2: p_conv MFMA -> offsets -> bilinear -> conv2 MFMA -> bn2 -> uimg ----
    {
        const unsigned char* ib = img1;
        float* otw = (float*)(ALL + L_OFFT) + w * 288;

        for (int mt = w; mt < 49; mt += 12) {
            int p = mt * 16 + col;
            int y = p / 28, xx = p % 28;

            // p_conv for this 16-pixel tile (B from LDS pool rows 0..31)
            floatx4 a0 = {0.f, 0.f, 0.f, 0.f}, a1 = {0.f, 0.f, 0.f, 0.f};
#pragma unroll
            for (int n = 0; n < 9; n++) {
                int yy = y + n / 3 - 1, xc = xx + n % 3 - 1;
                bool ok = ((unsigned)yy < 28u) && ((unsigned)xc < 28u);
                int tp = ok ? (yy * 28 + xc) : 784;      // 784 = zero slot
                short8 a  = *(const short8*)(ib + tp * 64 + q * 16);
                short8 p0 = *(const short8*)(ALL + L_WL + col * 592 + n * 64 + q * 16);
                short8 p1 = *(const short8*)(ALL + L_WL + (16 + col) * 592 + n * 64 + q * 16);
                a0 = __builtin_amdgcn_mfma_f32_16x16x32_bf16(a, p0, a0, 0, 0, 0);
                a1 = __builtin_amdgcn_mfma_f32_16x16x32_bf16(a, p1, a1, 0, 0, 0);
            }
#pragma unroll
            for (int r = 0; r < 4; r++)
                otw[(q * 4 + r) * 18 + col] = a0[r] + bias0;
            if (col < 2) {
#pragma unroll
                for (int r = 0; r < 4; r++)
                    otw[(q * 4 + r) * 18 + 16 + col] = a1[r] + bias1;
            }
            __asm__ volatile("s_waitcnt lgkmcnt(0)" ::: "memory");

            // bilinear A-frags + conv2 MFMA (B from LDS pool rows 32..63)
            floatx4 d0 = {0.f, 0.f, 0.f, 0.f}, d1 = {0.f, 0.f, 0.f, 0.f};
#pragma unroll
            for (int n = 0; n < 9; n++) {
                float offy = otw[col * 18 + n];
                float offx = otw[col * 18 + 9 + n];
                float py = (float)(y + n / 3) + offy;       // padded coords
                float px = (float)(xx + n % 3) + offx;
                float fy = floorf(py), fx = floorf(px);
                float qy0 = fminf(fmaxf(fy, 0.f), 29.f);
                float qy1 = fminf(fmaxf(fy + 1.f, 0.f), 29.f);
                float qx0 = fminf(fmaxf(fx, 0.f), 29.f);
                float qx1 = fminf(fmaxf(fx + 1.f, 0.f), 29.f);
                float pyc = fminf(fmaxf(py, 0.f), 29.f);
                float pxc = fminf(fmaxf(px, 0.f), 29.f);
                float glt = (1.f + (qy0 - pyc)) * (1.f + (qx0 - pxc));
                float grb = (1.f - (qy1 - pyc)) * (1.f - (qx1 - pxc));
                float glb = (1.f + (qy0 - pyc)) * (1.f - (qx1 - pxc));
                float grt = (1.f - (qy1 - pyc)) * (1.f + (qx0 - pxc));
                int iy0 = (int)qy0, iy1 = (int)qy1, ix0 = (int)qx0, ix1 = (int)qx1;
                int ly0 = iy0 - 1, ly1 = iy1 - 1, lx0 = ix0 - 1, lx1 = ix1 - 1;
                bool v00 = ((unsigned)ly0 < 28u) && ((unsigned)lx0 < 28u);
                bool v11 = ((unsigned)ly1 < 28u) && ((unsigned)lx1 < 28u);
                bool v01 = ((unsigned)ly0 < 28u) && ((unsigned)lx1 < 28u);
                bool v10 = ((unsigned)ly1 < 28u) && ((unsigned)lx0 < 28u);
                int p00 = v00 ? (ly0 * 28 + lx0) : 784;
                int p11 = v11 ? (ly1 * 28 + lx1) : 784;
                int p01 = v01 ? (ly0 * 28 + lx1) : 784;
                int p10 = v10 ? (ly1 * 28 + lx0) : 784;
                uint4 u00 = *(const uint4*)(ib + p00 * 64 + q * 16);
                uint4 u11 = *(const uint4*)(ib + p11 * 64 + q * 16);
                uint4 u01 = *(const uint4*)(ib + p01 * 64 + q * 16);
                uint4 u10 = *(const uint4*)(ib + p10 * 64 + q * 16);
                floatx2 f0 = up2(u00.x) * glt + up2(u11.x) * grb + up2(u01.x) * glb + up2(u10.x) * grt;
                floatx2 f1 = up2(u00.y) * glt + up2(u11.y) * grb + up2(u01.y) * glb + up2(u10.y) * grt;
                floatx2 f2 = up2(u00.z) * glt + up2(u11.z) * grb + up2(u01.z) * glb + up2(u10.z) * grt;
                floatx2 f3 = up2(u00.w) * glt + up2(u11.w) * grb + up2(u01.w) * glb + up2(u10.w) * grt;
                uint4 af4 = make_uint4(pk2bf(f0.x, f0.y), pk2bf(f1.x, f1.y),
                                       pk2bf(f2.x, f2.y), pk2bf(f3.x, f3.y));
                short8 af = *(short8*)&af4;
                short8 wb0 = *(const short8*)(ALL + L_WL + (32 + col) * 592 + n * 64 + q * 16);
                short8 wb1 = *(const short8*)(ALL + L_WL + (48 + col) * 592 + n * 64 + q * 16);
                d0 = __builtin_amdgcn_mfma_f32_16x16x32_bf16(af, wb0, d0, 0, 0, 0);
                d1 = __builtin_amdgcn_mfma_f32_16x16x32_bf16(af, wb1, d1, 0, 0, 0);
            }
            // bn2 + store to LDS uimg (interior layout, 64B/px)
#pragma unroll
            for (int r = 0; r < 4; r++) {
                int pout = mt * 16 + q * 4 + r;
                *(unsigned short*)(uimg + pout * 64 + col * 2) =
                    f2bf(fmaxf(d0[r], 0.f) * inv0 + sh0);
                *(unsigned short*)(uimg + pout * 64 + 32 + col * 2) =
                    f2bf(fmaxf(d1[r], 0.f) * inv1 + sh1);
            }
        }
    }
    __syncthreads();

    // ---- phase 3: convert w3 -> pool rows 0..63 ----
    for (int i = t; i < 18432; i += 768) {
        int row = i / 288, k = i - row * 288;
        *(unsigned short*)(ALL + L_WL + row * 592 + k * 2) =
            f2bf(w3[row * 288 + (k & 31) * 9 + (k >> 5)]);
    }
    __syncthreads();

    // ---- phase 4: conv3 MFMA + relu + global-sum partials ----
    {
        float* part = (float*)(ALL + L_OFFT);   // [12][32]
        int ocp = w & 1;
        const unsigned char* ib = uimg;
        float psA = 0.f, psB = 0.f;
        for (int mt = (w >> 1); mt < 49; mt += 6) {
            int p = mt * 16 + col;
            int y = p / 28, xx = p % 28;
            floatx4 cA = {0.f, 0.f, 0.f, 0.f}, cB = {0.f, 0.f, 0.f, 0.f};
#pragma unroll
            for (int n = 0; n < 9; n++) {
                int yy = y + n / 3 - 1, xc = xx + n % 3 - 1;
                bool ok = ((unsigned)yy < 28u) && ((unsigned)xc < 28u);
                int tp = ok ? (yy * 28 + xc) : 784;
                short8 a  = *(const short8*)(ib + tp * 64 + q * 16);
                short8 wA = *(const short8*)(ALL + L_WL + (ocp * 32 + col) * 592 + n * 64 + q * 16);
                short8 wB = *(const short8*)(ALL + L_WL + (ocp * 32 + 16 + col) * 592 + n * 64 + q * 16);
                cA = __builtin_amdgcn_mfma_f32_16x16x32_bf16(a, wA, cA, 0, 0, 0);
                cB = __builtin_amdgcn_mfma_f32_16x16x32_bf16(a, wB, cB, 0, 0, 0);
            }
            psA += fmaxf(cA[0], 0.f) + fmaxf(cA[1], 0.f) + fmaxf(cA[2], 0.f) + fmaxf(cA[3], 0.f);
            psB += fmaxf(cB[0], 0.f) + fmaxf(cB[1], 0.f) + fmaxf(cB[2], 0.f) + fmaxf(cB[3], 0.f);
        }
        psA += __shfl_xor(psA, 16, 64); psA += __shfl_xor(psA, 32, 64);
        psB += __shfl_xor(psB, 16, 64); psB += __shfl_xor(psB, 32, 64);
        if (l < 16) { part[w * 32 + l] = psA; part[w * 32 + 16 + l] = psB; }
    }
    __syncthreads();

    // ---- phase 5: classifier (one wave): bn3, mean, linear 64->10, log_softmax ----
    if (t < 64) {
        const float* part = (const float*)(ALL + L_OFFT);
        int hi = t >> 5, c = t & 31;
        float s = 0.f;
#pragma unroll
        for (int j = 0; j < 6; j++) s += part[(2 * j + hi) * 32 + c];   // oc = t
        float inv3 = g3[t] * rsqrtf(v3[t] + 1e-5f);
        float feat = s * inv3 * (1.f / 784.f) + (b3[t] - m3[t] * inv3);
        float lg[10];
        float mx = -1e30f;
#pragma unroll
        for (int j = 0; j < 10; j++) {
            float v = feat * wc[j * 64 + t];
            v += __shfl_xor(v, 1, 64);  v += __shfl_xor(v, 2, 64);
            v += __shfl_xor(v, 4, 64);  v += __shfl_xor(v, 8, 64);
            v += __shfl_xor(v, 16, 64); v += __shfl_xor(v, 32, 64);
            lg[j] = v + bc[j];
            mx = fmaxf(mx, lg[j]);
        }
        float se = 0.f;
#pragma unroll
        for (int j = 0; j < 10; j++) se += expf(lg[j] - mx);
        float lse = logf(se);
#pragma unroll
        for (int j = 0; j < 10; j++)
            if (t == j) outp[(size_t)b * 10 + j] = lg[j] - mx - lse;
    }
}

extern "C" void kernel_launch(void* const* d_in, const int* in_sizes, int n_in,
                              void* d_out, int out_size, void* d_ws, size_t ws_size,
                              hipStream_t stream)
{
    (void)in_sizes; (void)n_in; (void)out_size; (void)d_ws; (void)ws_size;
    const float* x  = (const float*)d_in[0];
    const float* w1 = (const float*)d_in[1];
    const float* g1 = (const float*)d_in[2];
    const float* b1 = (const float*)d_in[3];
    const float* m1 = (const float*)d_in[4];
    const float* v1 = (const float*)d_in[5];
    const float* wp = (const float*)d_in[6];
    const float* bp = (const float*)d_in[7];
    const float* w2 = (const float*)d_in[8];
    const float* g2 = (const float*)d_in[9];
    const float* b2 = (const float*)d_in[10];
    const float* m2 = (const float*)d_in[11];
    const float* v2 = (const float*)d_in[12];
    const float* w3 = (const float*)d_in[13];
    const float* g3 = (const float*)d_in[14];
    const float* b3 = (const float*)d_in[15];
    const float* m3 = (const float*)d_in[16];
    const float* v3 = (const float*)d_in[17];
    const float* wc = (const float*)d_in[18];
    const float* bc = (const float*)d_in[19];
    float* outp = (float*)d_out;

    meganet<<<NB, 768, 0, stream>>>(x, w1, g1, b1, m1, v1, wp, bp, w2,
                                    g2, b2, m2, v2, w3, g3, b3, m3, v3,
                                    wc, bc, outp);
}

// Round 11
// 138.473 us; speedup vs baseline: 5.7289x; 1.0381x over previous
//
#include <hip/hip_runtime.h>
#include <hip/hip_bf16.h>
#include <math.h>

typedef __attribute__((ext_vector_type(8))) short short8;   // 8 bf16 = 4 VGPRs (MFMA A/B frag)
typedef __attribute__((ext_vector_type(4))) float floatx4;  // MFMA C/D frag
typedef __attribute__((ext_vector_type(2))) float floatx2;

#define NB 256

// ---------------- workspace layout (bytes) ----------------
#define WPB_OFF 0u        // 32*288 bf16 [oc][k=n*32+ic], rows>=18 zero (p_conv, unscaled)
#define W2B_OFF 18432u    // 32*288 bf16, scaled by inv2[oc]
#define W3B_OFF 36864u    // 64*288 bf16, scaled by inv3[oc]
#define W1B_OFF 73728u    // 32*32 bf16 [oc][k=n*3+ic], k>=27 zero, scaled by inv1[oc]
#define C1S_OFF 75776u    // 32 f32 shift1
#define C2S_OFF 75904u    // 32 f32 shift2
#define C3S_OFF 76032u    // 64 f32 shift3

// ---------------- LDS layout (bytes) ----------------
#define L_IMG1 0            // 785*64 = 50240  (h1: 784 px + zero slot)
#define L_U    50240        // 785*64 = 50240  (x staging, then h2 interior + zero slot)
#define L_OFFT 100480       // w1 stash (2KB), then per-wave offsets [12][288]f32, then part[12][32]
#define L_WL   114304       // 64 rows * 592 B (wp+w2 rows, later w3 rows)
#define L_TOT  152192

static __device__ __forceinline__ unsigned short f2bf(float f) {
    unsigned u = __float_as_uint(f);
    u = (u + 0x7fffu + ((u >> 16) & 1u)) >> 16;   // RNE
    return (unsigned short)u;
}

static __device__ __forceinline__ unsigned pk2bf(float a, float b) {
    __hip_bfloat162 h = __float22bfloat162_rn(make_float2(a, b));
    unsigned r;
    __builtin_memcpy(&r, &h, 4);
    return r;
}

static __device__ __forceinline__ floatx2 up2(unsigned u) {
    floatx2 r;
    r.x = __uint_as_float(u << 16);
    r.y = __uint_as_float(u & 0xffff0000u);
    return r;
}

// ------- weight prep: bf16, pre-transposed, BN-scale-folded -------
__global__ void wcvt(const float* __restrict__ wp, const float* __restrict__ w2,
                     const float* __restrict__ w3, const float* __restrict__ w1,
                     const float* __restrict__ g1, const float* __restrict__ b1,
                     const float* __restrict__ m1, const float* __restrict__ v1,
                     const float* __restrict__ g2, const float* __restrict__ b2,
                     const float* __restrict__ m2, const float* __restrict__ v2,
                     const float* __restrict__ g3, const float* __restrict__ b3,
                     const float* __restrict__ m3, const float* __restrict__ v3,
                     unsigned short* __restrict__ wpb, unsigned short* __restrict__ w2b,
                     unsigned short* __restrict__ w3b, unsigned short* __restrict__ w1b,
                     float* __restrict__ c1s, float* __restrict__ c2s,
                     float* __restrict__ c3s)
{
    int t = blockIdx.x * 256 + threadIdx.x;
    if (t < 9216) {
        int oc = t / 288, k = t % 288;
        int n = k >> 5, ic = k & 31;
        wpb[t] = (oc < 18) ? f2bf(wp[oc * 288 + ic * 9 + n]) : (unsigned short)0;
    } else if (t < 18432) {
        int i = t - 9216;
        int oc = i / 288, k = i % 288;
        int n = k >> 5, ic = k & 31;
        float inv = g2[oc] * rsqrtf(v2[oc] + 1e-5f);
        w2b[i] = f2bf(w2[oc * 288 + ic * 9 + n] * inv);
    } else if (t < 36864) {
        int i = t - 18432;
        int oc = i / 288, k = i % 288;
        int n = k >> 5, ic = k & 31;
        float inv = g3[oc] * rsqrtf(v3[oc] + 1e-5f);
        w3b[i] = f2bf(w3[oc * 288 + ic * 9 + n] * inv);
    } else if (t < 37888) {
        int i = t - 36864;        // i = oc*32 + k, k = n*3+ic
        int oc = i >> 5, k = i & 31;
        int n = k / 3, ic = k - n * 3;
        float inv = g1[oc] * rsqrtf(v1[oc] + 1e-5f);
        w1b[i] = (k < 27) ? f2bf(w1[oc * 27 + ic * 9 + n] * inv) : (unsigned short)0;
    } else if (t < 37920) {
        int c = t - 37888;        // 0..31
        float inv = g1[c] * rsqrtf(v1[c] + 1e-5f);
        c1s[c] = b1[c] - m1[c] * inv;
    } else if (t < 37952) {
        int c = t - 37920;
        float inv = g2[c] * rsqrtf(v2[c] + 1e-5f);
        c2s[c] = b2[c] - m2[c] * inv;
    } else if (t < 38016) {
        int c = t - 37952;        // 0..63
        float inv = g3[c] * rsqrtf(v3[c] + 1e-5f);
        c3s[c] = b3[c] - m3[c] * inv;
    }
}

// ======= mega-kernel: conv1 -> LDS img1 -> p_conv+bilinear+conv2 -> LDS img2 -> conv3+pool -> cls =======
__global__ __launch_bounds__(768, 3) void meganet(
    const float* __restrict__ x,
    const unsigned short* __restrict__ wpb, const unsigned short* __restrict__ w2b,
    const unsigned short* __restrict__ w3b, const unsigned short* __restrict__ w1b,
    const float* __restrict__ c1s, const float* __restrict__ c2s,
    const float* __restrict__ c3s, const float* __restrict__ bp,
    const float* __restrict__ wc, const float* __restrict__ bc,
    float* __restrict__ outp)
{
    __shared__ __align__(16) unsigned char ALL[L_TOT];
    int t = threadIdx.x, b = blockIdx.x;
    int w = t >> 6, l = t & 63, col = l & 15, q = l >> 4;

    unsigned char* img1 = ALL + L_IMG1;
    unsigned char* uimg = ALL + L_U;          // x staging then h2

    // ---- phase 0: stage x + weights into LDS (all coalesced) ----
    {
        const float4* xg = (const float4*)(x + (size_t)b * 2352);
        float4* xl = (float4*)uimg;
        for (int i = t; i < 588; i += 768) xl[i] = xg[i];
    }
    {
        const uint4* s1 = (const uint4*)wpb;
        const uint4* s2 = (const uint4*)w2b;
        for (int i = t; i < 2304; i += 768) {      // wp rows 0..31, w2 rows 32..63
            int row = i / 36, g = i - row * 36;
            uint4 v = (row < 32) ? s1[row * 36 + g] : s2[(row - 32) * 36 + g];
            *(uint4*)(ALL + L_WL + row * 592 + g * 16) = v;
        }
        if (t < 128) *(uint4*)(ALL + L_OFFT + t * 16) = ((const uint4*)w1b)[t];
    }
    if (t == 700) ((float*)uimg)[2352] = 0.f;                       // conv1 zero slot
    if (t < 4)  *(uint4*)(img1 + 784 * 64 + t * 16) = make_uint4(0u, 0u, 0u, 0u);
    if (t >= 4 && t < 8) *(uint4*)(uimg + 784 * 64 + (t - 4) * 16) = make_uint4(0u, 0u, 0u, 0u);

    float s0 = c1s[col], s1v = c1s[16 + col];
    float bias0 = bp[col];
    float bias1 = (col < 2) ? bp[16 + col] : 0.f;
    float sh0 = c2s[col], sh1 = c2s[16 + col];

    __syncthreads();

    // ---- phase 1: conv1 (3->32, pad1, relu, bn-folded) -> img1 ----
    {
        short8 bf0 = *(const short8*)(ALL + L_OFFT + col * 64 + q * 16);
        short8 bf1 = *(const short8*)(ALL + L_OFFT + (16 + col) * 64 + q * 16);
        const float* xs = (const float*)uimg;
        for (int mt = w; mt < 49; mt += 12) {
            int p = mt * 16 + col;
            int y = p / 28, xx = p % 28;
            unsigned au[4];
#pragma unroll
            for (int jp = 0; jp < 4; jp++) {
                float vv[2];
#pragma unroll
                for (int h = 0; h < 2; h++) {
                    int k = q * 8 + jp * 2 + h;
                    int n = k / 3, ic = k - n * 3;
                    int yy = y + n / 3 - 1, xc = xx + n % 3 - 1;
                    bool ok = (k < 27) && ((unsigned)yy < 28u) && ((unsigned)xc < 28u);
                    int idx = ok ? (ic * 784 + yy * 28 + xc) : 2352;
                    vv[h] = xs[idx];
                }
                au[jp] = pk2bf(vv[0], vv[1]);
            }
            uint4 a4 = make_uint4(au[0], au[1], au[2], au[3]);
            short8 a = *(short8*)&a4;
            floatx4 d0 = {0.f, 0.f, 0.f, 0.f}, d1 = {0.f, 0.f, 0.f, 0.f};
            d0 = __builtin_amdgcn_mfma_f32_16x16x32_bf16(a, bf0, d0, 0, 0, 0);
            d1 = __builtin_amdgcn_mfma_f32_16x16x32_bf16(a, bf1, d1, 0, 0, 0);
#pragma unroll
            for (int r = 0; r < 4; r++) {
                int pout = mt * 16 + q * 4 + r;
                *(unsigned short*)(img1 + pout * 64 + col * 2) = f2bf(fmaxf(d0[r], 0.f) + s0);
                *(unsigned short*)(img1 + pout * 64 + 32 + col * 2) = f2bf(fmaxf(d1[r], 0.f) + s1v);
            }
        }
    }
    __syncthreads();

    // ---- phase 2: p_conv MFMA -> offsets -> bilinear -> conv2 MFMA -> uimg ----
    {
        const unsigned char* ib = img1;
        float* otw = (float*)(ALL + L_OFFT) + w * 288;

        for (int mt = w; mt < 49; mt += 12) {
            int p = mt * 16 + col;
            int y = p / 28, xx = p % 28;

            // p_conv for this 16-pixel tile (B from LDS pool rows 0..31)
            floatx4 a0 = {0.f, 0.f, 0.f, 0.f}, a1 = {0.f, 0.f, 0.f, 0.f};
#pragma unroll
            for (int n = 0; n < 9; n++) {
                int yy = y + n / 3 - 1, xc = xx + n % 3 - 1;
                bool ok = ((unsigned)yy < 28u) && ((unsigned)xc < 28u);
                int tp = ok ? (yy * 28 + xc) : 784;      // 784 = zero slot
                short8 a  = *(const short8*)(ib + tp * 64 + q * 16);
                short8 p0 = *(const short8*)(ALL + L_WL + col * 592 + n * 64 + q * 16);
                short8 p1 = *(const short8*)(ALL + L_WL + (16 + col) * 592 + n * 64 + q * 16);
                a0 = __builtin_amdgcn_mfma_f32_16x16x32_bf16(a, p0, a0, 0, 0, 0);
                a1 = __builtin_amdgcn_mfma_f32_16x16x32_bf16(a, p1, a1, 0, 0, 0);
            }
#pragma unroll
            for (int r = 0; r < 4; r++)
                otw[(q * 4 + r) * 18 + col] = a0[r] + bias0;
            if (col < 2) {
#pragma unroll
                for (int r = 0; r < 4; r++)
                    otw[(q * 4 + r) * 18 + 16 + col] = a1[r] + bias1;
            }
            __asm__ volatile("s_waitcnt lgkmcnt(0)" ::: "memory");

            // bilinear A-frags + conv2 MFMA (B rows 32..63, scale-folded)
            floatx4 d0 = {0.f, 0.f, 0.f, 0.f}, d1 = {0.f, 0.f, 0.f, 0.f};
#pragma unroll
            for (int n = 0; n < 9; n++) {
                float offy = otw[col * 18 + n];
                float offx = otw[col * 18 + 9 + n];
                float py = (float)(y + n / 3) + offy;       // padded coords
                float px = (float)(xx + n % 3) + offx;
                float fy = floorf(py), fx = floorf(px);
                float qy0 = fminf(fmaxf(fy, 0.f), 29.f);
                float qy1 = fminf(fmaxf(fy + 1.f, 0.f), 29.f);
                float qx0 = fminf(fmaxf(fx, 0.f), 29.f);
                float qx1 = fminf(fmaxf(fx + 1.f, 0.f), 29.f);
                float pyc = fminf(fmaxf(py, 0.f), 29.f);
                float pxc = fminf(fmaxf(px, 0.f), 29.f);
                float glt = (1.f + (qy0 - pyc)) * (1.f + (qx0 - pxc));
                float grb = (1.f - (qy1 - pyc)) * (1.f - (qx1 - pxc));
                float glb = (1.f + (qy0 - pyc)) * (1.f - (qx1 - pxc));
                float grt = (1.f - (qy1 - pyc)) * (1.f + (qx0 - pxc));
                int iy0 = (int)qy0, iy1 = (int)qy1, ix0 = (int)qx0, ix1 = (int)qx1;
                int ly0 = iy0 - 1, ly1 = iy1 - 1, lx0 = ix0 - 1, lx1 = ix1 - 1;
                bool v00 = ((unsigned)ly0 < 28u) && ((unsigned)lx0 < 28u);
                bool v11 = ((unsigned)ly1 < 28u) && ((unsigned)lx1 < 28u);
                bool v01 = ((unsigned)ly0 < 28u) && ((unsigned)lx1 < 28u);
                bool v10 = ((unsigned)ly1 < 28u) && ((unsigned)lx0 < 28u);
                int p00 = v00 ? (ly0 * 28 + lx0) : 784;
                int p11 = v11 ? (ly1 * 28 + lx1) : 784;
                int p01 = v01 ? (ly0 * 28 + lx1) : 784;
                int p10 = v10 ? (ly1 * 28 + lx0) : 784;
                uint4 u00 = *(const uint4*)(ib + p00 * 64 + q * 16);
                uint4 u11 = *(const uint4*)(ib + p11 * 64 + q * 16);
                uint4 u01 = *(const uint4*)(ib + p01 * 64 + q * 16);
                uint4 u10 = *(const uint4*)(ib + p10 * 64 + q * 16);
                floatx2 f0 = up2(u00.x) * glt + up2(u11.x) * grb + up2(u01.x) * glb + up2(u10.x) * grt;
                floatx2 f1 = up2(u00.y) * glt + up2(u11.y) * grb + up2(u01.y) * glb + up2(u10.y) * grt;
                floatx2 f2 = up2(u00.z) * glt + up2(u11.z) * grb + up2(u01.z) * glb + up2(u10.z) * grt;
                floatx2 f3 = up2(u00.w) * glt + up2(u11.w) * grb + up2(u01.w) * glb + up2(u10.w) * grt;
                uint4 af4 = make_uint4(pk2bf(f0.x, f0.y), pk2bf(f1.x, f1.y),
                                       pk2bf(f2.x, f2.y), pk2bf(f3.x, f3.y));
                short8 af = *(short8*)&af4;
                short8 wb0 = *(const short8*)(ALL + L_WL + (32 + col) * 592 + n * 64 + q * 16);
                short8 wb1 = *(const short8*)(ALL + L_WL + (48 + col) * 592 + n * 64 + q * 16);
                d0 = __builtin_amdgcn_mfma_f32_16x16x32_bf16(af, wb0, d0, 0, 0, 0);
                d1 = __builtin_amdgcn_mfma_f32_16x16x32_bf16(af, wb1, d1, 0, 0, 0);
            }
            // relu + shift2 + store to LDS uimg (interior layout, 64B/px)
#pragma unroll
            for (int r = 0; r < 4; r++) {
                int pout = mt * 16 + q * 4 + r;
                *(unsigned short*)(uimg + pout * 64 + col * 2) = f2bf(fmaxf(d0[r], 0.f) + sh0);
                *(unsigned short*)(uimg + pout * 64 + 32 + col * 2) = f2bf(fmaxf(d1[r], 0.f) + sh1);
            }
        }
    }
    __syncthreads();

    // ---- phase 3: stage w3 (bf16, pre-scaled) -> pool rows 0..63 (coalesced) ----
    {
        const uint4* src = (const uint4*)w3b;
        for (int i = t; i < 2304; i += 768) {
            int row = i / 36, g = i - row * 36;
            *(uint4*)(ALL + L_WL + row * 592 + g * 16) = src[row * 36 + g];
        }
    }
    __syncthreads();

    // ---- phase 4: conv3 MFMA + relu + global-sum partials ----
    {
        float* part = (float*)(ALL + L_OFFT);   // [12][32]
        int ocp = w & 1;
        const unsigned char* ib = uimg;
        float psA = 0.f, psB = 0.f;
        for (int mt = (w >> 1); mt < 49; mt += 6) {
            int p = mt * 16 + col;
            int y = p / 28, xx = p % 28;
            floatx4 cA = {0.f, 0.f, 0.f, 0.f}, cB = {0.f, 0.f, 0.f, 0.f};
#pragma unroll
            for (int n = 0; n < 9; n++) {
                int yy = y + n / 3 - 1, xc = xx + n % 3 - 1;
                bool ok = ((unsigned)yy < 28u) && ((unsigned)xc < 28u);
                int tp = ok ? (yy * 28 + xc) : 784;
                short8 a  = *(const short8*)(ib + tp * 64 + q * 16);
                short8 wA = *(const short8*)(ALL + L_WL + (ocp * 32 + col) * 592 + n * 64 + q * 16);
                short8 wB = *(const short8*)(ALL + L_WL + (ocp * 32 + 16 + col) * 592 + n * 64 + q * 16);
                cA = __builtin_amdgcn_mfma_f32_16x16x32_bf16(a, wA, cA, 0, 0, 0);
                cB = __builtin_amdgcn_mfma_f32_16x16x32_bf16(a, wB, cB, 0, 0, 0);
            }
            psA += fmaxf(cA[0], 0.f) + fmaxf(cA[1], 0.f) + fmaxf(cA[2], 0.f) + fmaxf(cA[3], 0.f);
            psB += fmaxf(cB[0], 0.f) + fmaxf(cB[1], 0.f) + fmaxf(cB[2], 0.f) + fmaxf(cB[3], 0.f);
        }
        psA += __shfl_xor(psA, 16, 64); psA += __shfl_xor(psA, 32, 64);
        psB += __shfl_xor(psB, 16, 64); psB += __shfl_xor(psB, 32, 64);
        if (l < 16) { part[w * 32 + l] = psA; part[w * 32 + 16 + l] = psB; }
    }
    __syncthreads();

    // ---- phase 5: classifier (one wave): shift3, mean, linear 64->10, log_softmax ----
    if (t < 64) {
        const float* part = (const float*)(ALL + L_OFFT);
        int hi = t >> 5, c = t & 31;
        float s = 0.f;
#pragma unroll
        for (int j = 0; j < 6; j++) s += part[(2 * j + hi) * 32 + c];   // oc = t
        float feat = s * (1.f / 784.f) + c3s[t];
        float lg[10];
        float mx = -1e30f;
#pragma unroll
        for (int j = 0; j < 10; j++) {
            float v = feat * wc[j * 64 + t];
            v += __shfl_xor(v, 1, 64);  v += __shfl_xor(v, 2, 64);
            v += __shfl_xor(v, 4, 64);  v += __shfl_xor(v, 8, 64);
            v += __shfl_xor(v, 16, 64); v += __shfl_xor(v, 32, 64);
            lg[j] = v + bc[j];
            mx = fmaxf(mx, lg[j]);
        }
        float se = 0.f;
#pragma unroll
        for (int j = 0; j < 10; j++) se += expf(lg[j] - mx);
        float lse = logf(se);
#pragma unroll
        for (int j = 0; j < 10; j++)
            if (t == j) outp[(size_t)b * 10 + j] = lg[j] - mx - lse;
    }
}

extern "C" void kernel_launch(void* const* d_in, const int* in_sizes, int n_in,
                              void* d_out, int out_size, void* d_ws, size_t ws_size,
                              hipStream_t stream)
{
    (void)in_sizes; (void)n_in; (void)out_size; (void)ws_size;
    const float* x  = (const float*)d_in[0];
    const float* w1 = (const float*)d_in[1];
    const float* g1 = (const float*)d_in[2];
    const float* b1 = (const float*)d_in[3];
    const float* m1 = (const float*)d_in[4];
    const float* v1 = (const float*)d_in[5];
    const float* wp = (const float*)d_in[6];
    const float* bp = (const float*)d_in[7];
    const float* w2 = (const float*)d_in[8];
    const float* g2 = (const float*)d_in[9];
    const float* b2 = (const float*)d_in[10];
    const float* m2 = (const float*)d_in[11];
    const float* v2 = (const float*)d_in[12];
    const float* w3 = (const float*)d_in[13];
    const float* g3 = (const float*)d_in[14];
    const float* b3 = (const float*)d_in[15];
    const float* m3 = (const float*)d_in[16];
    const float* v3 = (const float*)d_in[17];
    const float* wc = (const float*)d_in[18];
    const float* bc = (const float*)d_in[19];
    float* outp = (float*)d_out;

    unsigned char* ws = (unsigned char*)d_ws;
    unsigned short* wpb = (unsigned short*)(ws + WPB_OFF);
    unsigned short* w2b = (unsigned short*)(ws + W2B_OFF);
    unsigned short* w3b = (unsigned short*)(ws + W3B_OFF);
    unsigned short* w1b = (unsigned short*)(ws + W1B_OFF);
    float* c1s = (float*)(ws + C1S_OFF);
    float* c2s = (float*)(ws + C2S_OFF);
    float* c3s = (float*)(ws + C3S_OFF);

    wcvt<<<149, 256, 0, stream>>>(wp, w2, w3, w1, g1, b1, m1, v1,
                                  g2, b2, m2, v2, g3, b3, m3, v3,
                                  wpb, w2b, w3b, w1b, c1s, c2s, c3s);
    meganet<<<NB, 768, 0, stream>>>(x, wpb, w2b, w3b, w1b, c1s, c2s, c3s,
                                    bp, wc, bc, outp);
}